// Round 7
// baseline (744.244 us; speedup 1.0000x reference)
//
#include <hip/hip_runtime.h>
#include <math.h>

// ---------------- problem constants ----------------
#define NDRUG 1000
#define NCELL 1000
#define NGENE 6000
#define NNODE 8000
#define H1 256
#define HD  512   // HEADS*H2 = HEADS*H3
#define E0  160000
#define ET  168000   // E0 + NNODE self loops
#define BSZ 10000
#define GKP 6016    // padded gene K
#define ZSPLIT 8    // gene split-K factor

typedef __attribute__((ext_vector_type(8))) short bf16x8;
typedef __attribute__((ext_vector_type(4))) float f32x4;

__device__ inline unsigned short f2bf(float f)
{
    unsigned u = __float_as_uint(f);
    u += 0x7fffu + ((u >> 16) & 1u);   // RNE
    return (unsigned short)(u >> 16);
}
__device__ inline float bf2f(unsigned short h)
{
    return __uint_as_float(((unsigned)h) << 16);
}

// async global->LDS, 16B per lane; LDS dest = base + lane*16 (wave-uniform base)
__device__ inline void gld16(const unsigned short* g, char* l)
{
    __builtin_amdgcn_global_load_lds(
        (const __attribute__((address_space(1))) unsigned int*)g,
        (__attribute__((address_space(3))) unsigned int*)l,
        16, 0, 0);
}

// ---------------- f32 -> (hi,lo) bf16 with [Mp][Kp] zero padding ----------------
__global__ void cvt_pad2_kernel(const float* __restrict__ in,
                                unsigned short* __restrict__ hi,
                                unsigned short* __restrict__ lo,
                                int M, int K, int Mp, int Kp)
{
    long total = (long)Mp * Kp / 8;
    int kp8 = Kp / 8;
    long stride = (long)gridDim.x * blockDim.x;
    for (long u = (long)blockIdx.x * blockDim.x + threadIdx.x; u < total; u += stride) {
        long row = u / kp8; int kc = (int)(u % kp8);
        unsigned short oh[8], ol[8];
        if (row < M && kc * 8 < K) {   // K%8==0
            const float* p = in + row * (long)K + kc * 8;
            float4 a = *(const float4*)p, b = *(const float4*)(p + 4);
            float v[8] = {a.x, a.y, a.z, a.w, b.x, b.y, b.z, b.w};
            #pragma unroll
            for (int i = 0; i < 8; ++i) {
                unsigned short h = f2bf(v[i]);
                oh[i] = h;
                ol[i] = f2bf(v[i] - bf2f(h));
            }
        } else {
            #pragma unroll
            for (int i = 0; i < 8; ++i) { oh[i] = 0; ol[i] = 0; }
        }
        *(uint4*)(hi + u * 8) = *(const uint4*)oh;
        *(uint4*)(lo + u * 8) = *(const uint4*)ol;
    }
}

// ---------------- W[K][N] f32 -> Wt_{hi,lo}[N][Kp] bf16 (transpose + split + K-pad) ----------------
__global__ __launch_bounds__(256) void transpose_cvt2_kernel(const float* __restrict__ W,
                                                             unsigned short* __restrict__ Wh,
                                                             unsigned short* __restrict__ Wl,
                                                             int K, int N, int Kp)
{
    __shared__ float t[32][33];
    int kb = blockIdx.x * 32, nb = blockIdx.y * 32;
    int tx = threadIdx.x & 31, ty = threadIdx.x >> 5;  // ty 0..7
    #pragma unroll
    for (int i = 0; i < 32; i += 8) {
        int k = kb + ty + i;
        t[ty + i][tx] = (k < K) ? W[(long)k * N + nb + tx] : 0.f;
    }
    __syncthreads();
    #pragma unroll
    for (int i = 0; i < 32; i += 8) {
        int n = nb + ty + i;
        float v = t[tx][ty + i];
        unsigned short h = f2bf(v);
        Wh[(long)n * Kp + kb + tx] = h;
        Wl[(long)n * Kp + kb + tx] = f2bf(v - bf2f(h));
    }
}

// ---------------- split-bf16 MFMA GEMM, 64x64 tile (drug/cell projections) ----------------
template<int OUTBF>
__global__ __launch_bounds__(256) void gemm_mfma2(const unsigned short* __restrict__ Ah,
                                                  const unsigned short* __restrict__ Al,
                                                  const unsigned short* __restrict__ Bh,
                                                  const unsigned short* __restrict__ Bl,
                                                  const float* __restrict__ bias,
                                                  float* __restrict__ Cf,
                                                  unsigned short* __restrict__ Cbh,
                                                  unsigned short* __restrict__ Cbl,
                                                  int M, int Kp, int N)
{
    __shared__ unsigned short AsH[64 * 64];
    __shared__ unsigned short AsL[64 * 64];
    __shared__ unsigned short BsH[64 * 64];
    __shared__ unsigned short BsL[64 * 64];
    char* AsH8 = (char*)AsH; char* AsL8 = (char*)AsL;
    char* BsH8 = (char*)BsH; char* BsL8 = (char*)BsL;
    int tid = threadIdx.x;
    int w = tid >> 6, l = tid & 63;
    int wr = w >> 1, wc = w & 1;
    int g = l >> 4, r16 = l & 15;
    int row0 = blockIdx.y * 64, col0 = blockIdx.x * 64;
    int srow = tid >> 3, skc = tid & 7;
    int B0 = srow * 128 + skc * 16;       int P0 = B0 ^ ((srow & 7) << 4);
    int r1 = srow + 32;                   int B1 = r1 * 128 + skc * 16;
    int P1 = B1 ^ ((r1 & 7) << 4);
    f32x4 acc[2][2] = {};
    for (int k0 = 0; k0 < Kp; k0 += 64) {
        long a0 = (long)(row0 + srow) * Kp + k0 + skc * 8;
        long a1 = (long)(row0 + srow + 32) * Kp + k0 + skc * 8;
        long b0 = (long)(col0 + srow) * Kp + k0 + skc * 8;
        long b1 = (long)(col0 + srow + 32) * Kp + k0 + skc * 8;
        uint4 ah0 = *(const uint4*)(Ah + a0); uint4 ah1 = *(const uint4*)(Ah + a1);
        uint4 al0 = *(const uint4*)(Al + a0); uint4 al1 = *(const uint4*)(Al + a1);
        uint4 bh0 = *(const uint4*)(Bh + b0); uint4 bh1 = *(const uint4*)(Bh + b1);
        uint4 bl0 = *(const uint4*)(Bl + b0); uint4 bl1 = *(const uint4*)(Bl + b1);
        __syncthreads();
        *(uint4*)(AsH8 + P0) = ah0; *(uint4*)(AsH8 + P1) = ah1;
        *(uint4*)(AsL8 + P0) = al0; *(uint4*)(AsL8 + P1) = al1;
        *(uint4*)(BsH8 + P0) = bh0; *(uint4*)(BsH8 + P1) = bh1;
        *(uint4*)(BsL8 + P0) = bl0; *(uint4*)(BsL8 + P1) = bl1;
        __syncthreads();
        #pragma unroll
        for (int kk = 0; kk < 2; ++kk) {
            bf16x8 afh[2], afl[2], bfh[2], bfl[2];
            #pragma unroll
            for (int m = 0; m < 2; ++m) {
                int row = wr * 32 + m * 16 + r16;
                int Bb = (row * 128 + kk * 64 + g * 16) ^ ((row & 7) << 4);
                afh[m] = *(const bf16x8*)(AsH8 + Bb);
                afl[m] = *(const bf16x8*)(AsL8 + Bb);
            }
            #pragma unroll
            for (int n = 0; n < 2; ++n) {
                int row = wc * 32 + n * 16 + r16;
                int Bb = (row * 128 + kk * 64 + g * 16) ^ ((row & 7) << 4);
                bfh[n] = *(const bf16x8*)(BsH8 + Bb);
                bfl[n] = *(const bf16x8*)(BsL8 + Bb);
            }
            #pragma unroll
            for (int m = 0; m < 2; ++m)
                #pragma unroll
                for (int n = 0; n < 2; ++n) {
                    acc[m][n] = __builtin_amdgcn_mfma_f32_16x16x32_bf16(afh[m], bfh[n], acc[m][n], 0, 0, 0);
                    acc[m][n] = __builtin_amdgcn_mfma_f32_16x16x32_bf16(afh[m], bfl[n], acc[m][n], 0, 0, 0);
                    acc[m][n] = __builtin_amdgcn_mfma_f32_16x16x32_bf16(afl[m], bfh[n], acc[m][n], 0, 0, 0);
                }
        }
    }
    #pragma unroll
    for (int m = 0; m < 2; ++m) {
        #pragma unroll
        for (int n = 0; n < 2; ++n) {
            #pragma unroll
            for (int r = 0; r < 4; ++r) {
                int rowg = row0 + wr * 32 + m * 16 + g * 4 + r;
                int colg = col0 + wc * 32 + n * 16 + r16;
                if (rowg < M) {
                    float v = acc[m][n][r] + bias[colg];
                    if (OUTBF) {
                        unsigned short h = f2bf(v);
                        Cbh[(long)rowg * N + colg] = h;
                        Cbl[(long)rowg * N + colg] = f2bf(v - bf2f(h));
                    } else {
                        Cf[(long)rowg * N + colg] = v;
                    }
                }
            }
        }
    }
}

// ---------------- 128x128 split-bf16 MFMA GEMM w/ global_load_lds (layer GEMMs) ----------------
// A rows may be read past M (guarded writes); Kp%64==0, N%128==0.
template<int OUTBF>
__global__ __launch_bounds__(256) void gemm_mfma128(const unsigned short* __restrict__ Ah,
                                                    const unsigned short* __restrict__ Al,
                                                    const unsigned short* __restrict__ Bh,
                                                    const unsigned short* __restrict__ Bl,
                                                    const float* __restrict__ bias,
                                                    float* __restrict__ Cf,
                                                    unsigned short* __restrict__ Cbh,
                                                    unsigned short* __restrict__ Cbl,
                                                    int M, int Kp, int N)
{
    __shared__ char lds[65536];
    char* AsH = lds;          char* AsL = lds + 16384;
    char* BsH = lds + 32768;  char* BsL = lds + 49152;
    int tid = threadIdx.x;
    int w = tid >> 6, l = tid & 63;
    int wr = w >> 1, wc = w & 1;
    int g = l >> 4, r16 = l & 15;
    int row0 = blockIdx.y * 128, col0 = blockIdx.x * 128;
    int rr = l >> 3, s = l & 7;
    int swz = s ^ rr;
    f32x4 acc[4][4] = {};
    for (int k0 = 0; k0 < Kp; k0 += 64) {
        __syncthreads();
        #pragma unroll
        for (int i = 0; i < 4; ++i) {
            int rt = w * 32 + i * 8;
            long koff = (long)k0 + swz * 8;
            const unsigned short* ga  = Ah + (long)(row0 + rt + rr) * Kp + koff;
            const unsigned short* gal = Al + (long)(row0 + rt + rr) * Kp + koff;
            const unsigned short* gb  = Bh + (long)(col0 + rt + rr) * Kp + koff;
            const unsigned short* gbl = Bl + (long)(col0 + rt + rr) * Kp + koff;
            int lbase = rt * 128;
            gld16(ga,  AsH + lbase);
            gld16(gal, AsL + lbase);
            gld16(gb,  BsH + lbase);
            gld16(gbl, BsL + lbase);
        }
        __syncthreads();
        #pragma unroll
        for (int kk = 0; kk < 2; ++kk) {
            bf16x8 afh[4], afl[4], bfh[4], bfl[4];
            #pragma unroll
            for (int m = 0; m < 4; ++m) {
                int row = wr * 64 + m * 16 + r16;
                int Bb = (row * 128 + kk * 64 + g * 16) ^ ((row & 7) << 4);
                afh[m] = *(const bf16x8*)(AsH + Bb);
                afl[m] = *(const bf16x8*)(AsL + Bb);
            }
            #pragma unroll
            for (int n = 0; n < 4; ++n) {
                int row = wc * 64 + n * 16 + r16;
                int Bb = (row * 128 + kk * 64 + g * 16) ^ ((row & 7) << 4);
                bfh[n] = *(const bf16x8*)(BsH + Bb);
                bfl[n] = *(const bf16x8*)(BsL + Bb);
            }
            #pragma unroll
            for (int m = 0; m < 4; ++m)
                #pragma unroll
                for (int n = 0; n < 4; ++n) {
                    acc[m][n] = __builtin_amdgcn_mfma_f32_16x16x32_bf16(afh[m], bfh[n], acc[m][n], 0, 0, 0);
                    acc[m][n] = __builtin_amdgcn_mfma_f32_16x16x32_bf16(afh[m], bfl[n], acc[m][n], 0, 0, 0);
                    acc[m][n] = __builtin_amdgcn_mfma_f32_16x16x32_bf16(afl[m], bfh[n], acc[m][n], 0, 0, 0);
                }
        }
    }
    #pragma unroll
    for (int m = 0; m < 4; ++m) {
        #pragma unroll
        for (int n = 0; n < 4; ++n) {
            #pragma unroll
            for (int r = 0; r < 4; ++r) {
                int rowg = row0 + wr * 64 + m * 16 + g * 4 + r;
                int colg = col0 + wc * 64 + n * 16 + r16;
                if (rowg < M) {
                    float v = acc[m][n][r] + bias[colg];
                    if (OUTBF) {
                        unsigned short h = f2bf(v);
                        Cbh[(long)rowg * N + colg] = h;
                        Cbl[(long)rowg * N + colg] = f2bf(v - bf2f(h));
                    } else {
                        Cf[(long)rowg * N + colg] = v;
                    }
                }
            }
        }
    }
}

// ---------------- gene GEMM: 128x128 tile, BK=64, global_load_lds, split-K z=ZSPLIT ----------------
__global__ __launch_bounds__(256) void gemm_gene_splitk(const unsigned short* __restrict__ Ah,
                                                        const unsigned short* __restrict__ Al,
                                                        const unsigned short* __restrict__ Bh,
                                                        const unsigned short* __restrict__ Bl,
                                                        float* __restrict__ part)
{
    __shared__ char lds[65536];
    char* AsH = lds;          char* AsL = lds + 16384;
    char* BsH = lds + 32768;  char* BsL = lds + 49152;
    int tid = threadIdx.x;
    int w = tid >> 6, l = tid & 63;
    int wr = w >> 1, wc = w & 1;
    int g = l >> 4, r16 = l & 15;
    int row0 = blockIdx.y * 128, col0 = blockIdx.x * 128;
    int z = blockIdx.z;
    int kbeg = z * 768;
    int kend = kbeg + 768; if (kend > GKP) kend = GKP;
    int rr = l >> 3, s = l & 7;
    int swz = s ^ rr;
    f32x4 acc[4][4] = {};
    for (int k0 = kbeg; k0 < kend; k0 += 64) {
        __syncthreads();
        #pragma unroll
        for (int i = 0; i < 4; ++i) {
            int rt = w * 32 + i * 8;
            long koff = (long)k0 + swz * 8;
            const unsigned short* ga  = Ah + (long)(row0 + rt + rr) * GKP + koff;
            const unsigned short* gal = Al + (long)(row0 + rt + rr) * GKP + koff;
            const unsigned short* gb  = Bh + (long)(col0 + rt + rr) * GKP + koff;
            const unsigned short* gbl = Bl + (long)(col0 + rt + rr) * GKP + koff;
            int lbase = rt * 128;
            gld16(ga,  AsH + lbase);
            gld16(gal, AsL + lbase);
            gld16(gb,  BsH + lbase);
            gld16(gbl, BsL + lbase);
        }
        __syncthreads();
        #pragma unroll
        for (int kk = 0; kk < 2; ++kk) {
            bf16x8 afh[4], afl[4], bfh[4], bfl[4];
            #pragma unroll
            for (int m = 0; m < 4; ++m) {
                int row = wr * 64 + m * 16 + r16;
                int Bb = (row * 128 + kk * 64 + g * 16) ^ ((row & 7) << 4);
                afh[m] = *(const bf16x8*)(AsH + Bb);
                afl[m] = *(const bf16x8*)(AsL + Bb);
            }
            #pragma unroll
            for (int n = 0; n < 4; ++n) {
                int row = wc * 64 + n * 16 + r16;
                int Bb = (row * 128 + kk * 64 + g * 16) ^ ((row & 7) << 4);
                bfh[n] = *(const bf16x8*)(BsH + Bb);
                bfl[n] = *(const bf16x8*)(BsL + Bb);
            }
            #pragma unroll
            for (int m = 0; m < 4; ++m)
                #pragma unroll
                for (int n = 0; n < 4; ++n) {
                    acc[m][n] = __builtin_amdgcn_mfma_f32_16x16x32_bf16(afh[m], bfh[n], acc[m][n], 0, 0, 0);
                    acc[m][n] = __builtin_amdgcn_mfma_f32_16x16x32_bf16(afh[m], bfl[n], acc[m][n], 0, 0, 0);
                    acc[m][n] = __builtin_amdgcn_mfma_f32_16x16x32_bf16(afl[m], bfh[n], acc[m][n], 0, 0, 0);
                }
        }
    }
    #pragma unroll
    for (int m = 0; m < 4; ++m) {
        #pragma unroll
        for (int n = 0; n < 4; ++n) {
            #pragma unroll
            for (int r = 0; r < 4; ++r) {
                int rowg = row0 + wr * 64 + m * 16 + g * 4 + r;
                int colg = col0 + wc * 64 + n * 16 + r16;
                if (rowg < NGENE)
                    part[((long)z * NGENE + rowg) * H1 + colg] = acc[m][n][r];
            }
        }
    }
}

// ---------------- split-K reduce: sum ZSPLIT partials + bias -> x0 hi/lo (gene rows) ----------------
__global__ __launch_bounds__(256) void reduce_splitk_kernel(const float* __restrict__ part,
                                                            const float* __restrict__ bias,
                                                            unsigned short* __restrict__ xh,
                                                            unsigned short* __restrict__ xl)
{
    const long NEL = (long)NGENE * H1;
    long stride = (long)gridDim.x * blockDim.x;
    for (long q = (long)blockIdx.x * blockDim.x + threadIdx.x; q * 4 < NEL; q += stride) {
        long e = q * 4;
        float4 sv = *(const float4*)(part + e);
        #pragma unroll
        for (int z = 1; z < ZSPLIT; ++z) {
            float4 t = *(const float4*)(part + (long)z * NEL + e);
            sv.x += t.x; sv.y += t.y; sv.z += t.z; sv.w += t.w;
        }
        int col = (int)(e & (H1 - 1));
        float4 b = *(const float4*)(bias + col);
        float v[4] = {sv.x + b.x, sv.y + b.y, sv.z + b.z, sv.w + b.w};
        unsigned short oh[4], ol[4];
        #pragma unroll
        for (int i = 0; i < 4; ++i) {
            oh[i] = f2bf(v[i]);
            ol[i] = f2bf(v[i] - bf2f(oh[i]));
        }
        long o = (long)(NDRUG + NCELL) * H1 + e;
        *(uint2*)(xh + o) = *(const uint2*)oh;
        *(uint2*)(xl + o) = *(const uint2*)ol;
    }
}

// ---------------- init kernels ----------------
__global__ void init1_kernel(float* m, int* deg, float* colsv, float* scal)
{
    int i = blockIdx.x * 256 + threadIdx.x;
    if (i < NNODE * 4) m[i] = -3.402823466e38f;
    if (i < NNODE) deg[i] = 0;
    if (i < 1024) colsv[i] = 0.f;
    if (i < 8) scal[i] = 0.f;
}

__global__ void init2_kernel(float* m, float* colsv)
{
    int i = blockIdx.x * 256 + threadIdx.x;
    if (i < NNODE * 4) m[i] = -3.402823466e38f;
    if (i < 1024) colsv[i] = 0.f;
}

// ---------------- sum(edge_attr) -> scal[0] ----------------
__global__ void reduce_sum_kernel(const float* __restrict__ x, int n, float* out)
{
    float s = 0.f;
    for (int i = blockIdx.x * blockDim.x + threadIdx.x; i < n; i += gridDim.x * blockDim.x)
        s += x[i];
    for (int off = 32; off; off >>= 1) s += __shfl_down(s, off);
    if ((threadIdx.x & 63) == 0) atomicAdd(out, s);
}

// ---------------- ce[h] = dot(We[h*128:...], att_e[h]) for both layers ----------------
__global__ __launch_bounds__(512) void ce_kernel(const float* We1, const float* ae1,
                                                 const float* We2, const float* ae2, float* ce)
{
    __shared__ float sm[512];
    int t = threadIdx.x;
    sm[t] = We1[t] * ae1[t];
    __syncthreads();
    if (t < 4) { float s = 0.f; for (int c = 0; c < 128; ++c) s += sm[t * 128 + c]; ce[t] = s; }
    __syncthreads();
    sm[t] = We2[t] * ae2[t];
    __syncthreads();
    if (t < 4) { float s = 0.f; for (int c = 0; c < 128; ++c) s += sm[t * 128 + c]; ce[4 + t] = s; }
}

// ---------------- per-node attention coefficients ----------------
__global__ __launch_bounds__(64) void attn_coef_kernel(const float* __restrict__ xw,
                                                       const float* __restrict__ as,
                                                       const float* __restrict__ ad,
                                                       float* __restrict__ a_src,
                                                       float* __restrict__ a_dst)
{
    int n = blockIdx.x;
    int l = threadIdx.x;
    #pragma unroll
    for (int h = 0; h < 4; ++h) {
        float x1 = xw[(long)n * HD + h * 128 + l];
        float x2 = xw[(long)n * HD + h * 128 + 64 + l];
        float s = x1 * as[h * 128 + l] + x2 * as[h * 128 + 64 + l];
        float d = x1 * ad[h * 128 + l] + x2 * ad[h * 128 + 64 + l];
        for (int off = 32; off; off >>= 1) { s += __shfl_down(s, off); d += __shfl_down(d, off); }
        if (l == 0) { a_src[n * 4 + h] = s; a_dst[n * 4 + h] = d; }
    }
}

// ---------------- atomic float max ----------------
__device__ inline void atomicMaxF(float* addr, float v)
{
    if (v >= 0.f) atomicMax((int*)addr, __float_as_int(v));
    else          atomicMin((unsigned int*)addr, __float_as_uint(v));
}

// ---------------- per-edge alpha + segment max (+ degree histogram) ----------------
__global__ void alpha_max_kernel(const int* __restrict__ ei, const float* __restrict__ eattr,
                                 const float* __restrict__ scal,
                                 const float* __restrict__ a_src, const float* __restrict__ a_dst,
                                 const float* __restrict__ ce,
                                 float* __restrict__ alpha, float* __restrict__ m,
                                 int* __restrict__ deg, int do_deg)
{
    int e = blockIdx.x * blockDim.x + threadIdx.x;
    if (e >= ET) return;
    int s, d; float a;
    if (e < E0) { s = ei[e]; d = ei[E0 + e]; a = eattr[e]; }
    else        { s = d = e - E0; a = scal[0] * (1.0f / E0); }
    #pragma unroll
    for (int h = 0; h < 4; ++h) {
        float v = a_src[s * 4 + h] + a_dst[d * 4 + h] + a * ce[h];
        v = v > 0.f ? v : 0.2f * v;
        alpha[e * 4 + h] = v;
        atomicMaxF(&m[d * 4 + h], v);
    }
    if (do_deg) atomicAdd(&deg[d], 1);
}

// ---------------- exclusive scan of deg -> row_start, cursor (single block) ----------------
__global__ __launch_bounds__(1024) void scan_kernel(const int* __restrict__ deg,
                                                    int* __restrict__ row_start,
                                                    int* __restrict__ cursor)
{
    __shared__ int sm[1024];
    int t = threadIdx.x;
    int base = t * 8;
    int loc[8];
    int sum = 0;
    #pragma unroll
    for (int j = 0; j < 8; ++j) {
        int v = (base + j < NNODE) ? deg[base + j] : 0;
        loc[j] = sum; sum += v;
    }
    sm[t] = sum;
    __syncthreads();
    for (int off = 1; off < 1024; off <<= 1) {
        int v = (t >= off) ? sm[t - off] : 0;
        __syncthreads();
        sm[t] += v;
        __syncthreads();
    }
    int excl = sm[t] - sum;
    #pragma unroll
    for (int j = 0; j < 8; ++j) {
        int idx = base + j;
        if (idx < NNODE) { int v = excl + loc[j]; row_start[idx] = v; cursor[idx] = v; }
    }
    if (t == 1023) row_start[NNODE] = sm[1023];
}

// ---------------- scatter edges into CSR (by dst) ----------------
__global__ void scatter_csr_kernel(const int* __restrict__ ei, int* __restrict__ cursor,
                                   int* __restrict__ csr_src, int* __restrict__ csr_eid)
{
    int e = blockIdx.x * blockDim.x + threadIdx.x;
    if (e >= ET) return;
    int s, d;
    if (e < E0) { s = ei[e]; d = ei[E0 + e]; }
    else        { s = d = e - E0; }
    int pos = atomicAdd(&cursor[d], 1);
    csr_src[pos] = s;
    csr_eid[pos] = e;
}

// ---------------- aggregation: one block (4 waves = 4 heads) per node ----------------
__global__ __launch_bounds__(256) void aggregate_kernel(const float* __restrict__ xw,
                                                        const float* __restrict__ alpha,
                                                        const float* __restrict__ m,
                                                        const int* __restrict__ rs,
                                                        const int* __restrict__ csr_src,
                                                        const int* __restrict__ csr_eid,
                                                        const float* __restrict__ bias,
                                                        float* __restrict__ out)
{
    int n = blockIdx.x;
    int h = threadIdx.x >> 6;   // wave index = head
    int l = threadIdx.x & 63;
    float mnh = m[n * 4 + h];
    int i0 = rs[n], i1 = rs[n + 1];
    float den = 0.f;
    for (int i = i0 + l; i < i1; i += 64)
        den += expf(alpha[csr_eid[i] * 4 + h] - mnh);
    for (int off = 32; off; off >>= 1) den += __shfl_down(den, off);
    den = __shfl(den, 0);
    float rden = 1.0f / (den + 1e-16f);
    float acc0 = 0.f, acc1 = 0.f;
    int i = i0;
    for (; i + 3 < i1; i += 4) {
        int s0 = csr_src[i],     s1 = csr_src[i + 1], s2 = csr_src[i + 2], s3 = csr_src[i + 3];
        int e0 = csr_eid[i],     e1 = csr_eid[i + 1], e2 = csr_eid[i + 2], e3 = csr_eid[i + 3];
        float al0 = alpha[e0 * 4 + h], al1 = alpha[e1 * 4 + h];
        float al2 = alpha[e2 * 4 + h], al3 = alpha[e3 * 4 + h];
        const float* r0 = xw + (long)s0 * HD + h * 128;
        const float* r1 = xw + (long)s1 * HD + h * 128;
        const float* r2 = xw + (long)s2 * HD + h * 128;
        const float* r3 = xw + (long)s3 * HD + h * 128;
        float x00 = r0[l], x01 = r0[64 + l];
        float x10 = r1[l], x11 = r1[64 + l];
        float x20 = r2[l], x21 = r2[64 + l];
        float x30 = r3[l], x31 = r3[64 + l];
        float w0 = expf(al0 - mnh), w1 = expf(al1 - mnh);
        float w2 = expf(al2 - mnh), w3 = expf(al3 - mnh);
        acc0 += w0 * x00 + w1 * x10 + w2 * x20 + w3 * x30;
        acc1 += w0 * x01 + w1 * x11 + w2 * x21 + w3 * x31;
    }
    for (; i < i1; ++i) {
        int s   = csr_src[i];
        int eid = csr_eid[i];
        float w = expf(alpha[eid * 4 + h] - mnh);
        const float* xr = xw + (long)s * HD + h * 128;
        acc0 += w * xr[l];
        acc1 += w * xr[64 + l];
    }
    out[(long)n * HD + h * 128 + l]      = acc0 * rden + bias[h * 128 + l];
    out[(long)n * HD + h * 128 + 64 + l] = acc1 * rden + bias[h * 128 + 64 + l];
}

// ---------------- graph norm: column sums ----------------
__global__ __launch_bounds__(256) void colsum_kernel(const float* __restrict__ x, float* __restrict__ colsum)
{
    int t = threadIdx.x, b = blockIdx.x;
    float s0 = 0.f, s1 = 0.f;
    for (int r = b * 125; r < (b + 1) * 125; ++r) {
        s0 += x[(long)r * HD + t];
        s1 += x[(long)r * HD + t + 256];
    }
    atomicAdd(&colsum[t], s0);
    atomicAdd(&colsum[t + 256], s1);
}

__global__ __launch_bounds__(256) void colvar_kernel(const float* __restrict__ x,
                                                     const float* __restrict__ colsum,
                                                     const float* __restrict__ ms,
                                                     float* __restrict__ colvar)
{
    int t = threadIdx.x, b = blockIdx.x;
    float c0 = ms[t] * colsum[t] * (1.0f / NNODE);
    float c1 = ms[t + 256] * colsum[t + 256] * (1.0f / NNODE);
    float s0 = 0.f, s1 = 0.f;
    for (int r = b * 125; r < (b + 1) * 125; ++r) {
        float v0 = x[(long)r * HD + t] - c0;       s0 += v0 * v0;
        float v1 = x[(long)r * HD + t + 256] - c1; s1 += v1 * v1;
    }
    atomicAdd(&colvar[t], s0);
    atomicAdd(&colvar[t + 256], s1);
}

// norm (+ReLU) in place; also writes (hi,lo) bf16 copies for the next GEMM's A input
__global__ void norm_kernel(float* __restrict__ x,
                            unsigned short* __restrict__ xbh, unsigned short* __restrict__ xbl,
                            const float* __restrict__ colsum,
                            const float* __restrict__ colvar,
                            const float* __restrict__ g, const float* __restrict__ be,
                            const float* __restrict__ ms)
{
    int stride = gridDim.x * blockDim.x;
    for (int idx = blockIdx.x * blockDim.x + threadIdx.x; idx < NNODE * HD; idx += stride) {
        int j = idx & 511;
        float mu  = colsum[j] * (1.0f / NNODE);
        float var = colvar[j] * (1.0f / NNODE);
        float v = x[idx] - ms[j] * mu;
        float y = g[j] * v / sqrtf(var + 1e-5f) + be[j];
        y = y > 0.f ? y : 0.f;
        x[idx] = y;
        unsigned short h = f2bf(y);
        xbh[idx] = h;
        xbl[idx] = f2bf(y - bf2f(h));
    }
}

// ---------------- prediction head ----------------
__global__ __launch_bounds__(256) void head_kernel(const float* __restrict__ x2,
                                                   const int* __restrict__ idd,
                                                   const int* __restrict__ idc,
                                                   const float* __restrict__ Wout,
                                                   const float* __restrict__ bout,
                                                   float* __restrict__ out0)
{
    int w = threadIdx.x >> 6, l = threadIdx.x & 63;
    int b = blockIdx.x * 4 + w;
    if (b >= BSZ) return;
    int rd = idd[b], rc = idc[b];
    float s = 0.f;
    #pragma unroll
    for (int k = l; k < HD; k += 64)
        s += x2[(long)rd * HD + k] * Wout[k] + x2[(long)rc * HD + k] * Wout[HD + k];
    for (int off = 32; off; off >>= 1) s += __shfl_down(s, off);
    if (l == 0) out0[b] = s + bout[0];
}

// ---------------- all_att: zero + scatter scalar ----------------
__global__ void zero_f4_kernel(float4* __restrict__ p, long n4)
{
    long stride = (long)gridDim.x * blockDim.x;
    for (long i = (long)blockIdx.x * blockDim.x + threadIdx.x; i < n4; i += stride)
        p[i] = make_float4(0.f, 0.f, 0.f, 0.f);
}

__global__ void scatter_att_kernel(const int* __restrict__ ei, float* __restrict__ attm)
{
    int e = blockIdx.x * blockDim.x + threadIdx.x;
    if (e >= ET) return;
    int s, d;
    if (e < E0) { s = ei[e]; d = ei[E0 + e]; }
    else        { s = d = e - E0; }
    const float val = 2.0f * (float)NNODE / (float)ET;
    attm[(long)s * NNODE + d] = val;
}

// ---------------- launch ----------------
extern "C" void kernel_launch(void* const* d_in, const int* in_sizes, int n_in,
                              void* d_out, int out_size, void* d_ws, size_t ws_size,
                              hipStream_t stream)
{
    const float* drug   = (const float*)d_in[0];
    const float* cell   = (const float*)d_in[1];
    const float* gene   = (const float*)d_in[2];
    const float* eattr  = (const float*)d_in[3];
    const int*   ei     = (const int*)d_in[4];
    const int*   idd    = (const int*)d_in[5];
    const int*   idc    = (const int*)d_in[6];
    const float* Wdrug  = (const float*)d_in[7];
    const float* bdrug  = (const float*)d_in[8];
    const float* Wcell  = (const float*)d_in[9];
    const float* bcell  = (const float*)d_in[10];
    const float* Wgene  = (const float*)d_in[11];
    const float* bgene  = (const float*)d_in[12];
    const float* W1     = (const float*)d_in[13];
    const float* b1     = (const float*)d_in[14];
    const float* as1    = (const float*)d_in[15];
    const float* ad1    = (const float*)d_in[16];
    const float* We1    = (const float*)d_in[17];
    const float* ae1    = (const float*)d_in[18];
    const float* bias1  = (const float*)d_in[19];
    const float* g1     = (const float*)d_in[20];
    const float* be1    = (const float*)d_in[21];
    const float* ms1    = (const float*)d_in[22];
    const float* W2     = (const float*)d_in[23];
    const float* b2     = (const float*)d_in[24];
    const float* as2    = (const float*)d_in[25];
    const float* ad2    = (const float*)d_in[26];
    const float* We2    = (const float*)d_in[27];
    const float* ae2    = (const float*)d_in[28];
    const float* bias2  = (const float*)d_in[29];
    const float* g2     = (const float*)d_in[30];
    const float* be2    = (const float*)d_in[31];
    const float* ms2    = (const float*)d_in[32];
    const float* Wout   = (const float*)d_in[33];
    const float* bout   = (const float*)d_in[34];

    float* out0 = (float*)d_out;                 // [10000]
    float* attm = (float*)d_out + BSZ;           // [8000*8000]

    // ---- workspace layout ----
    float* ws     = (float*)d_ws;
    float* xw     = ws;                          // 8000*512
    float* outb   = xw + (long)NNODE * HD;       // 8000*512
    float* alpha  = outb + (long)NNODE * HD;     // 168000*4
    float* a_src  = alpha + (long)ET * 4;        // 32000
    float* a_dst  = a_src + NNODE * 4;           // 32000
    float* mbuf   = a_dst + NNODE * 4;           // 32000
    float* colsum = mbuf + NNODE * 4;            // 512
    float* colvar = colsum + 512;                // 512
    float* ce     = colvar + 512;                // 8
    float* scal   = ce + 8;                      // 8
    int* deg      = (int*)(scal + 8);            // 8000
    int* rs       = deg + NNODE;                 // 8004 (padded)
    int* cursor   = rs + NNODE + 4;              // 8000
    int* csr_src  = cursor + NNODE;              // 168000
    int* csr_eid  = csr_src + ET;                // 168000
    unsigned short* p = (unsigned short*)(csr_eid + ET);
    unsigned short* gene_h = p; p += (long)6016 * GKP;
    unsigned short* gene_l = p; p += (long)6016 * GKP;
    unsigned short* drug_h = p; p += (long)1024 * 1024;
    unsigned short* drug_l = p; p += (long)1024 * 1024;
    unsigned short* cell_h = p; p += (long)1024 * 1024;
    unsigned short* cell_l = p; p += (long)1024 * 1024;
    unsigned short* x0_h   = p; p += (long)NNODE * H1;
    unsigned short* x0_l   = p; p += (long)NNODE * H1;
    unsigned short* xb_h   = p; p += (long)NNODE * HD;
    unsigned short* xb_l   = p; p += (long)NNODE * HD;
    unsigned short* Wd_h   = p; p += 256 * 1024;
    unsigned short* Wd_l   = p; p += 256 * 1024;
    unsigned short* Wc_h   = p; p += 256 * 1024;
    unsigned short* Wc_l   = p; p += 256 * 1024;
    unsigned short* Wg_h   = p; p += 256 * GKP;
    unsigned short* Wg_l   = p; p += 256 * GKP;
    unsigned short* W1_h   = p; p += 512 * 256;
    unsigned short* W1_l   = p; p += 512 * 256;
    unsigned short* W2_h   = p; p += 512 * 512;
    unsigned short* W2_l   = p; p += 512 * 512;
    // align to 16B and place split-K partials (ZSPLIT * NGENE * H1 f32 = 49.2 MB)
    float* partsk = (float*)((((unsigned long long)p) + 15) & ~15ULL);

    dim3 blk256(256);
    int gE = (ET + 255) / 256;

    // init + small precomputes
    init1_kernel<<<125, blk256, 0, stream>>>(mbuf, deg, colsum, scal);
    reduce_sum_kernel<<<64, blk256, 0, stream>>>(eattr, E0, &scal[0]);
    ce_kernel<<<1, 512, 0, stream>>>(We1, ae1, We2, ae2, ce);

    // ---- hi/lo split conversions ----
    cvt_pad2_kernel<<<512, blk256, 0, stream>>>(drug, drug_h, drug_l, NDRUG, NDRUG, 1024, 1024);
    cvt_pad2_kernel<<<512, blk256, 0, stream>>>(cell, cell_h, cell_l, NCELL, NCELL, 1024, 1024);
    cvt_pad2_kernel<<<2048, blk256, 0, stream>>>(gene, gene_h, gene_l, NGENE, NGENE, 6016, GKP);
    transpose_cvt2_kernel<<<dim3(32, 8),  blk256, 0, stream>>>(Wdrug, Wd_h, Wd_l, NDRUG, H1, 1024);
    transpose_cvt2_kernel<<<dim3(32, 8),  blk256, 0, stream>>>(Wcell, Wc_h, Wc_l, NCELL, H1, 1024);
    transpose_cvt2_kernel<<<dim3(188, 8), blk256, 0, stream>>>(Wgene, Wg_h, Wg_l, NGENE, H1, GKP);
    transpose_cvt2_kernel<<<dim3(8, 16),  blk256, 0, stream>>>(W1, W1_h, W1_l, H1, HD, H1);
    transpose_cvt2_kernel<<<dim3(16, 16), blk256, 0, stream>>>(W2, W2_h, W2_l, HD, HD, HD);

    // ---- input projections -> x0 (hi/lo bf16) ----
    gemm_mfma2<1><<<dim3(H1 / 64, 16), blk256, 0, stream>>>(drug_h, drug_l, Wd_h, Wd_l, bdrug,
        nullptr, x0_h, x0_l, NDRUG, 1024, H1);
    gemm_mfma2<1><<<dim3(H1 / 64, 16), blk256, 0, stream>>>(cell_h, cell_l, Wc_h, Wc_l, bcell,
        nullptr, x0_h + (long)NDRUG * H1, x0_l + (long)NDRUG * H1, NCELL, 1024, H1);
    // gene: 128x128 tile + gload_lds + split-K(ZSPLIT)
    gemm_gene_splitk<<<dim3(2, 47, ZSPLIT), blk256, 0, stream>>>(gene_h, gene_l, Wg_h, Wg_l, partsk);
    reduce_splitk_kernel<<<1500, blk256, 0, stream>>>(partsk, bgene, x0_h, x0_l);

    // ---- layer 1 ----
    gemm_mfma128<0><<<dim3(HD / 128, (NNODE + 127) / 128), blk256, 0, stream>>>(x0_h, x0_l, W1_h, W1_l, b1,
        xw, nullptr, nullptr, NNODE, H1, HD);
    attn_coef_kernel<<<NNODE, 64, 0, stream>>>(xw, as1, ad1, a_src, a_dst);
    alpha_max_kernel<<<gE, blk256, 0, stream>>>(ei, eattr, scal, a_src, a_dst, ce, alpha, mbuf, deg, 1);
    scan_kernel<<<1, 1024, 0, stream>>>(deg, rs, cursor);
    scatter_csr_kernel<<<gE, blk256, 0, stream>>>(ei, cursor, csr_src, csr_eid);
    aggregate_kernel<<<NNODE, blk256, 0, stream>>>(xw, alpha, mbuf, rs, csr_src, csr_eid, bias1, outb);
    colsum_kernel<<<64, blk256, 0, stream>>>(outb, colsum);
    colvar_kernel<<<64, blk256, 0, stream>>>(outb, colsum, ms1, colvar);
    norm_kernel<<<2048, blk256, 0, stream>>>(outb, xb_h, xb_l, colsum, colvar, g1, be1, ms1);

    // ---- layer 2 ----
    gemm_mfma128<0><<<dim3(HD / 128, (NNODE + 127) / 128), blk256, 0, stream>>>(xb_h, xb_l, W2_h, W2_l, b2,
        xw, nullptr, nullptr, NNODE, HD, HD);
    attn_coef_kernel<<<NNODE, 64, 0, stream>>>(xw, as2, ad2, a_src, a_dst);
    init2_kernel<<<125, blk256, 0, stream>>>(mbuf, colsum);
    alpha_max_kernel<<<gE, blk256, 0, stream>>>(ei, eattr, scal, a_src, a_dst, ce + 4, alpha, mbuf, deg, 0);
    aggregate_kernel<<<NNODE, blk256, 0, stream>>>(xw, alpha, mbuf, rs, csr_src, csr_eid, bias2, outb);
    colsum_kernel<<<64, blk256, 0, stream>>>(outb, colsum);
    colvar_kernel<<<64, blk256, 0, stream>>>(outb, colsum, ms2, colvar);
    norm_kernel<<<2048, blk256, 0, stream>>>(outb, xb_h, xb_l, colsum, colvar, g2, be2, ms2);

    // ---- head + attention matrix ----
    head_kernel<<<(BSZ + 3) / 4, blk256, 0, stream>>>(outb, idd, idc, Wout, bout, out0);
    zero_f4_kernel<<<2048, blk256, 0, stream>>>((float4*)attm, (long)NNODE * NNODE / 4);
    scatter_att_kernel<<<gE, blk256, 0, stream>>>(ei, attm);
}

// Round 8
// 736.147 us; speedup vs baseline: 1.0110x; 1.0110x over previous
//
#include <hip/hip_runtime.h>
#include <math.h>

// ---------------- problem constants ----------------
#define NDRUG 1000
#define NCELL 1000
#define NGENE 6000
#define NNODE 8000
#define H1 256
#define HD  512   // HEADS*H2 = HEADS*H3
#define E0  160000
#define ET  168000   // E0 + NNODE self loops
#define BSZ 10000
#define GKP 6016    // padded gene K
#define ZSPLIT 8    // gene split-K factor

typedef __attribute__((ext_vector_type(8))) short bf16x8;
typedef __attribute__((ext_vector_type(4))) float f32x4;

__device__ inline unsigned short f2bf(float f)
{
    unsigned u = __float_as_uint(f);
    u += 0x7fffu + ((u >> 16) & 1u);   // RNE
    return (unsigned short)(u >> 16);
}
__device__ inline float bf2f(unsigned short h)
{
    return __uint_as_float(((unsigned)h) << 16);
}

// async global->LDS, 16B per lane; LDS dest = base + lane*16 (wave-uniform base)
__device__ inline void gld16(const unsigned short* g, char* l)
{
    __builtin_amdgcn_global_load_lds(
        (const __attribute__((address_space(1))) unsigned int*)g,
        (__attribute__((address_space(3))) unsigned int*)l,
        16, 0, 0);
}

// ---------------- f32 -> (hi,lo) bf16 with [Mp][Kp] zero padding ----------------
__global__ void cvt_pad2_kernel(const float* __restrict__ in,
                                unsigned short* __restrict__ hi,
                                unsigned short* __restrict__ lo,
                                int M, int K, int Mp, int Kp)
{
    long total = (long)Mp * Kp / 8;
    int kp8 = Kp / 8;
    long stride = (long)gridDim.x * blockDim.x;
    for (long u = (long)blockIdx.x * blockDim.x + threadIdx.x; u < total; u += stride) {
        long row = u / kp8; int kc = (int)(u % kp8);
        unsigned short oh[8], ol[8];
        if (row < M && kc * 8 < K) {   // K%8==0
            const float* p = in + row * (long)K + kc * 8;
            float4 a = *(const float4*)p, b = *(const float4*)(p + 4);
            float v[8] = {a.x, a.y, a.z, a.w, b.x, b.y, b.z, b.w};
            #pragma unroll
            for (int i = 0; i < 8; ++i) {
                unsigned short h = f2bf(v[i]);
                oh[i] = h;
                ol[i] = f2bf(v[i] - bf2f(h));
            }
        } else {
            #pragma unroll
            for (int i = 0; i < 8; ++i) { oh[i] = 0; ol[i] = 0; }
        }
        *(uint4*)(hi + u * 8) = *(const uint4*)oh;
        *(uint4*)(lo + u * 8) = *(const uint4*)ol;
    }
}

// ---------------- W[K][N] f32 -> Wt_{hi,lo}[N][Kp] bf16 (transpose + split + K-pad) ----------------
__global__ __launch_bounds__(256) void transpose_cvt2_kernel(const float* __restrict__ W,
                                                             unsigned short* __restrict__ Wh,
                                                             unsigned short* __restrict__ Wl,
                                                             int K, int N, int Kp)
{
    __shared__ float t[32][33];
    int kb = blockIdx.x * 32, nb = blockIdx.y * 32;
    int tx = threadIdx.x & 31, ty = threadIdx.x >> 5;  // ty 0..7
    #pragma unroll
    for (int i = 0; i < 32; i += 8) {
        int k = kb + ty + i;
        t[ty + i][tx] = (k < K) ? W[(long)k * N + nb + tx] : 0.f;
    }
    __syncthreads();
    #pragma unroll
    for (int i = 0; i < 32; i += 8) {
        int n = nb + ty + i;
        float v = t[tx][ty + i];
        unsigned short h = f2bf(v);
        Wh[(long)n * Kp + kb + tx] = h;
        Wl[(long)n * Kp + kb + tx] = f2bf(v - bf2f(h));
    }
}

// ---------------- split-bf16 MFMA GEMM, 64x64 tile (drug/cell projections) ----------------
template<int OUTBF>
__global__ __launch_bounds__(256) void gemm_mfma2(const unsigned short* __restrict__ Ah,
                                                  const unsigned short* __restrict__ Al,
                                                  const unsigned short* __restrict__ Bh,
                                                  const unsigned short* __restrict__ Bl,
                                                  const float* __restrict__ bias,
                                                  float* __restrict__ Cf,
                                                  unsigned short* __restrict__ Cbh,
                                                  unsigned short* __restrict__ Cbl,
                                                  int M, int Kp, int N)
{
    __shared__ unsigned short AsH[64 * 64];
    __shared__ unsigned short AsL[64 * 64];
    __shared__ unsigned short BsH[64 * 64];
    __shared__ unsigned short BsL[64 * 64];
    char* AsH8 = (char*)AsH; char* AsL8 = (char*)AsL;
    char* BsH8 = (char*)BsH; char* BsL8 = (char*)BsL;
    int tid = threadIdx.x;
    int w = tid >> 6, l = tid & 63;
    int wr = w >> 1, wc = w & 1;
    int g = l >> 4, r16 = l & 15;
    int row0 = blockIdx.y * 64, col0 = blockIdx.x * 64;
    int srow = tid >> 3, skc = tid & 7;
    int B0 = srow * 128 + skc * 16;       int P0 = B0 ^ ((srow & 7) << 4);
    int r1 = srow + 32;                   int B1 = r1 * 128 + skc * 16;
    int P1 = B1 ^ ((r1 & 7) << 4);
    f32x4 acc[2][2] = {};
    for (int k0 = 0; k0 < Kp; k0 += 64) {
        long a0 = (long)(row0 + srow) * Kp + k0 + skc * 8;
        long a1 = (long)(row0 + srow + 32) * Kp + k0 + skc * 8;
        long b0 = (long)(col0 + srow) * Kp + k0 + skc * 8;
        long b1 = (long)(col0 + srow + 32) * Kp + k0 + skc * 8;
        uint4 ah0 = *(const uint4*)(Ah + a0); uint4 ah1 = *(const uint4*)(Ah + a1);
        uint4 al0 = *(const uint4*)(Al + a0); uint4 al1 = *(const uint4*)(Al + a1);
        uint4 bh0 = *(const uint4*)(Bh + b0); uint4 bh1 = *(const uint4*)(Bh + b1);
        uint4 bl0 = *(const uint4*)(Bl + b0); uint4 bl1 = *(const uint4*)(Bl + b1);
        __syncthreads();
        *(uint4*)(AsH8 + P0) = ah0; *(uint4*)(AsH8 + P1) = ah1;
        *(uint4*)(AsL8 + P0) = al0; *(uint4*)(AsL8 + P1) = al1;
        *(uint4*)(BsH8 + P0) = bh0; *(uint4*)(BsH8 + P1) = bh1;
        *(uint4*)(BsL8 + P0) = bl0; *(uint4*)(BsL8 + P1) = bl1;
        __syncthreads();
        #pragma unroll
        for (int kk = 0; kk < 2; ++kk) {
            bf16x8 afh[2], afl[2], bfh[2], bfl[2];
            #pragma unroll
            for (int m = 0; m < 2; ++m) {
                int row = wr * 32 + m * 16 + r16;
                int Bb = (row * 128 + kk * 64 + g * 16) ^ ((row & 7) << 4);
                afh[m] = *(const bf16x8*)(AsH8 + Bb);
                afl[m] = *(const bf16x8*)(AsL8 + Bb);
            }
            #pragma unroll
            for (int n = 0; n < 2; ++n) {
                int row = wc * 32 + n * 16 + r16;
                int Bb = (row * 128 + kk * 64 + g * 16) ^ ((row & 7) << 4);
                bfh[n] = *(const bf16x8*)(BsH8 + Bb);
                bfl[n] = *(const bf16x8*)(BsL8 + Bb);
            }
            #pragma unroll
            for (int m = 0; m < 2; ++m)
                #pragma unroll
                for (int n = 0; n < 2; ++n) {
                    acc[m][n] = __builtin_amdgcn_mfma_f32_16x16x32_bf16(afh[m], bfh[n], acc[m][n], 0, 0, 0);
                    acc[m][n] = __builtin_amdgcn_mfma_f32_16x16x32_bf16(afh[m], bfl[n], acc[m][n], 0, 0, 0);
                    acc[m][n] = __builtin_amdgcn_mfma_f32_16x16x32_bf16(afl[m], bfh[n], acc[m][n], 0, 0, 0);
                }
        }
    }
    #pragma unroll
    for (int m = 0; m < 2; ++m) {
        #pragma unroll
        for (int n = 0; n < 2; ++n) {
            #pragma unroll
            for (int r = 0; r < 4; ++r) {
                int rowg = row0 + wr * 32 + m * 16 + g * 4 + r;
                int colg = col0 + wc * 32 + n * 16 + r16;
                if (rowg < M) {
                    float v = acc[m][n][r] + bias[colg];
                    if (OUTBF) {
                        unsigned short h = f2bf(v);
                        Cbh[(long)rowg * N + colg] = h;
                        Cbl[(long)rowg * N + colg] = f2bf(v - bf2f(h));
                    } else {
                        Cf[(long)rowg * N + colg] = v;
                    }
                }
            }
        }
    }
}

// ---------------- 128x128 split-bf16 MFMA GEMM w/ global_load_lds (layer GEMMs) ----------------
template<int OUTBF>
__global__ __launch_bounds__(256) void gemm_mfma128(const unsigned short* __restrict__ Ah,
                                                    const unsigned short* __restrict__ Al,
                                                    const unsigned short* __restrict__ Bh,
                                                    const unsigned short* __restrict__ Bl,
                                                    const float* __restrict__ bias,
                                                    float* __restrict__ Cf,
                                                    unsigned short* __restrict__ Cbh,
                                                    unsigned short* __restrict__ Cbl,
                                                    int M, int Kp, int N)
{
    __shared__ char lds[65536];
    char* AsH = lds;          char* AsL = lds + 16384;
    char* BsH = lds + 32768;  char* BsL = lds + 49152;
    int tid = threadIdx.x;
    int w = tid >> 6, l = tid & 63;
    int wr = w >> 1, wc = w & 1;
    int g = l >> 4, r16 = l & 15;
    int row0 = blockIdx.y * 128, col0 = blockIdx.x * 128;
    int rr = l >> 3, s = l & 7;
    int swz = s ^ rr;
    f32x4 acc[4][4] = {};
    for (int k0 = 0; k0 < Kp; k0 += 64) {
        __syncthreads();
        #pragma unroll
        for (int i = 0; i < 4; ++i) {
            int rt = w * 32 + i * 8;
            long koff = (long)k0 + swz * 8;
            const unsigned short* ga  = Ah + (long)(row0 + rt + rr) * Kp + koff;
            const unsigned short* gal = Al + (long)(row0 + rt + rr) * Kp + koff;
            const unsigned short* gb  = Bh + (long)(col0 + rt + rr) * Kp + koff;
            const unsigned short* gbl = Bl + (long)(col0 + rt + rr) * Kp + koff;
            int lbase = rt * 128;
            gld16(ga,  AsH + lbase);
            gld16(gal, AsL + lbase);
            gld16(gb,  BsH + lbase);
            gld16(gbl, BsL + lbase);
        }
        __syncthreads();
        #pragma unroll
        for (int kk = 0; kk < 2; ++kk) {
            bf16x8 afh[4], afl[4], bfh[4], bfl[4];
            #pragma unroll
            for (int m = 0; m < 4; ++m) {
                int row = wr * 64 + m * 16 + r16;
                int Bb = (row * 128 + kk * 64 + g * 16) ^ ((row & 7) << 4);
                afh[m] = *(const bf16x8*)(AsH + Bb);
                afl[m] = *(const bf16x8*)(AsL + Bb);
            }
            #pragma unroll
            for (int n = 0; n < 4; ++n) {
                int row = wc * 64 + n * 16 + r16;
                int Bb = (row * 128 + kk * 64 + g * 16) ^ ((row & 7) << 4);
                bfh[n] = *(const bf16x8*)(BsH + Bb);
                bfl[n] = *(const bf16x8*)(BsL + Bb);
            }
            #pragma unroll
            for (int m = 0; m < 4; ++m)
                #pragma unroll
                for (int n = 0; n < 4; ++n) {
                    acc[m][n] = __builtin_amdgcn_mfma_f32_16x16x32_bf16(afh[m], bfh[n], acc[m][n], 0, 0, 0);
                    acc[m][n] = __builtin_amdgcn_mfma_f32_16x16x32_bf16(afh[m], bfl[n], acc[m][n], 0, 0, 0);
                    acc[m][n] = __builtin_amdgcn_mfma_f32_16x16x32_bf16(afl[m], bfh[n], acc[m][n], 0, 0, 0);
                }
        }
    }
    #pragma unroll
    for (int m = 0; m < 4; ++m) {
        #pragma unroll
        for (int n = 0; n < 4; ++n) {
            #pragma unroll
            for (int r = 0; r < 4; ++r) {
                int rowg = row0 + wr * 64 + m * 16 + g * 4 + r;
                int colg = col0 + wc * 64 + n * 16 + r16;
                if (rowg < M) {
                    float v = acc[m][n][r] + bias[colg];
                    if (OUTBF) {
                        unsigned short h = f2bf(v);
                        Cbh[(long)rowg * N + colg] = h;
                        Cbl[(long)rowg * N + colg] = f2bf(v - bf2f(h));
                    } else {
                        Cf[(long)rowg * N + colg] = v;
                    }
                }
            }
        }
    }
}

// ---------------- gene GEMM: 128x128 tile, BK=64, global_load_lds, split-K z=ZSPLIT ----------------
__global__ __launch_bounds__(256) void gemm_gene_splitk(const unsigned short* __restrict__ Ah,
                                                        const unsigned short* __restrict__ Al,
                                                        const unsigned short* __restrict__ Bh,
                                                        const unsigned short* __restrict__ Bl,
                                                        float* __restrict__ part)
{
    __shared__ char lds[65536];
    char* AsH = lds;          char* AsL = lds + 16384;
    char* BsH = lds + 32768;  char* BsL = lds + 49152;
    int tid = threadIdx.x;
    int w = tid >> 6, l = tid & 63;
    int wr = w >> 1, wc = w & 1;
    int g = l >> 4, r16 = l & 15;
    int row0 = blockIdx.y * 128, col0 = blockIdx.x * 128;
    int z = blockIdx.z;
    int kbeg = z * 768;
    int kend = kbeg + 768; if (kend > GKP) kend = GKP;
    int rr = l >> 3, s = l & 7;
    int swz = s ^ rr;
    f32x4 acc[4][4] = {};
    for (int k0 = kbeg; k0 < kend; k0 += 64) {
        __syncthreads();
        #pragma unroll
        for (int i = 0; i < 4; ++i) {
            int rt = w * 32 + i * 8;
            long koff = (long)k0 + swz * 8;
            const unsigned short* ga  = Ah + (long)(row0 + rt + rr) * GKP + koff;
            const unsigned short* gal = Al + (long)(row0 + rt + rr) * GKP + koff;
            const unsigned short* gb  = Bh + (long)(col0 + rt + rr) * GKP + koff;
            const unsigned short* gbl = Bl + (long)(col0 + rt + rr) * GKP + koff;
            int lbase = rt * 128;
            gld16(ga,  AsH + lbase);
            gld16(gal, AsL + lbase);
            gld16(gb,  BsH + lbase);
            gld16(gbl, BsL + lbase);
        }
        __syncthreads();
        #pragma unroll
        for (int kk = 0; kk < 2; ++kk) {
            bf16x8 afh[4], afl[4], bfh[4], bfl[4];
            #pragma unroll
            for (int m = 0; m < 4; ++m) {
                int row = wr * 64 + m * 16 + r16;
                int Bb = (row * 128 + kk * 64 + g * 16) ^ ((row & 7) << 4);
                afh[m] = *(const bf16x8*)(AsH + Bb);
                afl[m] = *(const bf16x8*)(AsL + Bb);
            }
            #pragma unroll
            for (int n = 0; n < 4; ++n) {
                int row = wc * 64 + n * 16 + r16;
                int Bb = (row * 128 + kk * 64 + g * 16) ^ ((row & 7) << 4);
                bfh[n] = *(const bf16x8*)(BsH + Bb);
                bfl[n] = *(const bf16x8*)(BsL + Bb);
            }
            #pragma unroll
            for (int m = 0; m < 4; ++m)
                #pragma unroll
                for (int n = 0; n < 4; ++n) {
                    acc[m][n] = __builtin_amdgcn_mfma_f32_16x16x32_bf16(afh[m], bfh[n], acc[m][n], 0, 0, 0);
                    acc[m][n] = __builtin_amdgcn_mfma_f32_16x16x32_bf16(afh[m], bfl[n], acc[m][n], 0, 0, 0);
                    acc[m][n] = __builtin_amdgcn_mfma_f32_16x16x32_bf16(afl[m], bfh[n], acc[m][n], 0, 0, 0);
                }
        }
    }
    #pragma unroll
    for (int m = 0; m < 4; ++m) {
        #pragma unroll
        for (int n = 0; n < 4; ++n) {
            #pragma unroll
            for (int r = 0; r < 4; ++r) {
                int rowg = row0 + wr * 64 + m * 16 + g * 4 + r;
                int colg = col0 + wc * 64 + n * 16 + r16;
                if (rowg < NGENE)
                    part[((long)z * NGENE + rowg) * H1 + colg] = acc[m][n][r];
            }
        }
    }
}

// ---------------- split-K reduce ----------------
__global__ __launch_bounds__(256) void reduce_splitk_kernel(const float* __restrict__ part,
                                                            const float* __restrict__ bias,
                                                            unsigned short* __restrict__ xh,
                                                            unsigned short* __restrict__ xl)
{
    const long NEL = (long)NGENE * H1;
    long stride = (long)gridDim.x * blockDim.x;
    for (long q = (long)blockIdx.x * blockDim.x + threadIdx.x; q * 4 < NEL; q += stride) {
        long e = q * 4;
        float4 sv = *(const float4*)(part + e);
        #pragma unroll
        for (int z = 1; z < ZSPLIT; ++z) {
            float4 t = *(const float4*)(part + (long)z * NEL + e);
            sv.x += t.x; sv.y += t.y; sv.z += t.z; sv.w += t.w;
        }
        int col = (int)(e & (H1 - 1));
        float4 b = *(const float4*)(bias + col);
        float v[4] = {sv.x + b.x, sv.y + b.y, sv.z + b.z, sv.w + b.w};
        unsigned short oh[4], ol[4];
        #pragma unroll
        for (int i = 0; i < 4; ++i) {
            oh[i] = f2bf(v[i]);
            ol[i] = f2bf(v[i] - bf2f(oh[i]));
        }
        long o = (long)(NDRUG + NCELL) * H1 + e;
        *(uint2*)(xh + o) = *(const uint2*)oh;
        *(uint2*)(xl + o) = *(const uint2*)ol;
    }
}

// ---------------- init kernels ----------------
__global__ void init1_kernel(float* m, int* deg, float* colsv, float* scal)
{
    int i = blockIdx.x * 256 + threadIdx.x;
    if (i < NNODE * 4) m[i] = -3.402823466e38f;
    if (i < NNODE) deg[i] = 0;
    if (i < 1024) colsv[i] = 0.f;
    if (i < 8) scal[i] = 0.f;
}

__global__ void init2_kernel(float* m, float* colsv)
{
    int i = blockIdx.x * 256 + threadIdx.x;
    if (i < NNODE * 4) m[i] = -3.402823466e38f;
    if (i < 1024) colsv[i] = 0.f;
}

// ---------------- sum(edge_attr) -> scal[0] ----------------
__global__ void reduce_sum_kernel(const float* __restrict__ x, int n, float* out)
{
    float s = 0.f;
    for (int i = blockIdx.x * blockDim.x + threadIdx.x; i < n; i += gridDim.x * blockDim.x)
        s += x[i];
    for (int off = 32; off; off >>= 1) s += __shfl_down(s, off);
    if ((threadIdx.x & 63) == 0) atomicAdd(out, s);
}

// ---------------- ce[h] ----------------
__global__ __launch_bounds__(512) void ce_kernel(const float* We1, const float* ae1,
                                                 const float* We2, const float* ae2, float* ce)
{
    __shared__ float sm[512];
    int t = threadIdx.x;
    sm[t] = We1[t] * ae1[t];
    __syncthreads();
    if (t < 4) { float s = 0.f; for (int c = 0; c < 128; ++c) s += sm[t * 128 + c]; ce[t] = s; }
    __syncthreads();
    sm[t] = We2[t] * ae2[t];
    __syncthreads();
    if (t < 4) { float s = 0.f; for (int c = 0; c < 128; ++c) s += sm[t * 128 + c]; ce[4 + t] = s; }
}

// ---------------- per-node attention coefficients ----------------
__global__ __launch_bounds__(64) void attn_coef_kernel(const float* __restrict__ xw,
                                                       const float* __restrict__ as,
                                                       const float* __restrict__ ad,
                                                       float* __restrict__ a_src,
                                                       float* __restrict__ a_dst)
{
    int n = blockIdx.x;
    int l = threadIdx.x;
    #pragma unroll
    for (int h = 0; h < 4; ++h) {
        float x1 = xw[(long)n * HD + h * 128 + l];
        float x2 = xw[(long)n * HD + h * 128 + 64 + l];
        float s = x1 * as[h * 128 + l] + x2 * as[h * 128 + 64 + l];
        float d = x1 * ad[h * 128 + l] + x2 * ad[h * 128 + 64 + l];
        for (int off = 32; off; off >>= 1) { s += __shfl_down(s, off); d += __shfl_down(d, off); }
        if (l == 0) { a_src[n * 4 + h] = s; a_dst[n * 4 + h] = d; }
    }
}

// ---------------- atomic float max ----------------
__device__ inline void atomicMaxF(float* addr, float v)
{
    if (v >= 0.f) atomicMax((int*)addr, __float_as_int(v));
    else          atomicMin((unsigned int*)addr, __float_as_uint(v));
}

// ---------------- per-edge alpha + segment max (+ degree histogram) ----------------
__global__ void alpha_max_kernel(const int* __restrict__ ei, const float* __restrict__ eattr,
                                 const float* __restrict__ scal,
                                 const float* __restrict__ a_src, const float* __restrict__ a_dst,
                                 const float* __restrict__ ce,
                                 float* __restrict__ alpha, float* __restrict__ m,
                                 int* __restrict__ deg, int do_deg)
{
    int e = blockIdx.x * blockDim.x + threadIdx.x;
    if (e >= ET) return;
    int s, d; float a;
    if (e < E0) { s = ei[e]; d = ei[E0 + e]; a = eattr[e]; }
    else        { s = d = e - E0; a = scal[0] * (1.0f / E0); }
    #pragma unroll
    for (int h = 0; h < 4; ++h) {
        float v = a_src[s * 4 + h] + a_dst[d * 4 + h] + a * ce[h];
        v = v > 0.f ? v : 0.2f * v;
        alpha[e * 4 + h] = v;
        atomicMaxF(&m[d * 4 + h], v);
    }
    if (do_deg) atomicAdd(&deg[d], 1);
}

// ---------------- exclusive scan ----------------
__global__ __launch_bounds__(1024) void scan_kernel(const int* __restrict__ deg,
                                                    int* __restrict__ row_start,
                                                    int* __restrict__ cursor)
{
    __shared__ int sm[1024];
    int t = threadIdx.x;
    int base = t * 8;
    int loc[8];
    int sum = 0;
    #pragma unroll
    for (int j = 0; j < 8; ++j) {
        int v = (base + j < NNODE) ? deg[base + j] : 0;
        loc[j] = sum; sum += v;
    }
    sm[t] = sum;
    __syncthreads();
    for (int off = 1; off < 1024; off <<= 1) {
        int v = (t >= off) ? sm[t - off] : 0;
        __syncthreads();
        sm[t] += v;
        __syncthreads();
    }
    int excl = sm[t] - sum;
    #pragma unroll
    for (int j = 0; j < 8; ++j) {
        int idx = base + j;
        if (idx < NNODE) { int v = excl + loc[j]; row_start[idx] = v; cursor[idx] = v; }
    }
    if (t == 1023) row_start[NNODE] = sm[1023];
}

// ---------------- scatter edges into CSR (by dst) ----------------
__global__ void scatter_csr_kernel(const int* __restrict__ ei, int* __restrict__ cursor,
                                   int* __restrict__ csr_src, int* __restrict__ csr_eid)
{
    int e = blockIdx.x * blockDim.x + threadIdx.x;
    if (e >= ET) return;
    int s, d;
    if (e < E0) { s = ei[e]; d = ei[E0 + e]; }
    else        { s = d = e - E0; }
    int pos = atomicAdd(&cursor[d], 1);
    csr_src[pos] = s;
    csr_eid[pos] = e;
}

// ---------------- csr-order alpha copy (sequentialize aggregate's reads) ----------------
__global__ void csr_alpha_gather_kernel(const int* __restrict__ csr_eid,
                                        const float* __restrict__ alpha,
                                        float* __restrict__ csr_alpha)
{
    int i = blockIdx.x * blockDim.x + threadIdx.x;
    if (i >= ET) return;
    *(float4*)(csr_alpha + (long)i * 4) = *(const float4*)(alpha + (long)csr_eid[i] * 4);
}

// ---------------- aggregation: one block (4 waves = 4 heads) per node ----------------
// csr_src / csr_alpha read SEQUENTIALLY; only the xw row gather is random. ILP=8.
__global__ __launch_bounds__(256) void aggregate_kernel(const float* __restrict__ xw,
                                                        const float* __restrict__ csr_alpha,
                                                        const float* __restrict__ m,
                                                        const int* __restrict__ rs,
                                                        const int* __restrict__ csr_src,
                                                        const float* __restrict__ bias,
                                                        float* __restrict__ out)
{
    int n = blockIdx.x;
    int h = threadIdx.x >> 6;   // wave index = head
    int l = threadIdx.x & 63;
    float mnh = m[n * 4 + h];
    int i0 = rs[n], i1 = rs[n + 1];
    // denominator: sequential csr_alpha reads, lane-parallel
    float den = 0.f;
    for (int i = i0 + l; i < i1; i += 64)
        den += expf(csr_alpha[(long)i * 4 + h] - mnh);
    for (int off = 32; off; off >>= 1) den += __shfl_down(den, off);
    den = __shfl(den, 0);
    float rden = 1.0f / (den + 1e-16f);
    // main loop: 8 edges in flight
    float acc0 = 0.f, acc1 = 0.f;
    int i = i0;
    for (; i + 7 < i1; i += 8) {
        int   sv[8];
        float av[8], xv0[8], xv1[8];
        #pragma unroll
        for (int j = 0; j < 8; ++j) {
            sv[j] = csr_src[i + j];
            av[j] = csr_alpha[(long)(i + j) * 4 + h];
        }
        #pragma unroll
        for (int j = 0; j < 8; ++j) {
            const float* r = xw + (long)sv[j] * HD + h * 128;
            xv0[j] = r[l]; xv1[j] = r[64 + l];
        }
        #pragma unroll
        for (int j = 0; j < 8; ++j) {
            float w = expf(av[j] - mnh);
            acc0 += w * xv0[j];
            acc1 += w * xv1[j];
        }
    }
    for (; i < i1; ++i) {
        int s = csr_src[i];
        float w = expf(csr_alpha[(long)i * 4 + h] - mnh);
        const float* xr = xw + (long)s * HD + h * 128;
        acc0 += w * xr[l];
        acc1 += w * xr[64 + l];
    }
    out[(long)n * HD + h * 128 + l]      = acc0 * rden + bias[h * 128 + l];
    out[(long)n * HD + h * 128 + 64 + l] = acc1 * rden + bias[h * 128 + 64 + l];
}

// ---------------- graph norm ----------------
__global__ __launch_bounds__(256) void colsum_kernel(const float* __restrict__ x, float* __restrict__ colsum)
{
    int t = threadIdx.x, b = blockIdx.x;
    float s0 = 0.f, s1 = 0.f;
    for (int r = b * 125; r < (b + 1) * 125; ++r) {
        s0 += x[(long)r * HD + t];
        s1 += x[(long)r * HD + t + 256];
    }
    atomicAdd(&colsum[t], s0);
    atomicAdd(&colsum[t + 256], s1);
}

__global__ __launch_bounds__(256) void colvar_kernel(const float* __restrict__ x,
                                                     const float* __restrict__ colsum,
                                                     const float* __restrict__ ms,
                                                     float* __restrict__ colvar)
{
    int t = threadIdx.x, b = blockIdx.x;
    float c0 = ms[t] * colsum[t] * (1.0f / NNODE);
    float c1 = ms[t + 256] * colsum[t + 256] * (1.0f / NNODE);
    float s0 = 0.f, s1 = 0.f;
    for (int r = b * 125; r < (b + 1) * 125; ++r) {
        float v0 = x[(long)r * HD + t] - c0;       s0 += v0 * v0;
        float v1 = x[(long)r * HD + t + 256] - c1; s1 += v1 * v1;
    }
    atomicAdd(&colvar[t], s0);
    atomicAdd(&colvar[t + 256], s1);
}

__global__ void norm_kernel(float* __restrict__ x,
                            unsigned short* __restrict__ xbh, unsigned short* __restrict__ xbl,
                            const float* __restrict__ colsum,
                            const float* __restrict__ colvar,
                            const float* __restrict__ g, const float* __restrict__ be,
                            const float* __restrict__ ms)
{
    int stride = gridDim.x * blockDim.x;
    for (int idx = blockIdx.x * blockDim.x + threadIdx.x; idx < NNODE * HD; idx += stride) {
        int j = idx & 511;
        float mu  = colsum[j] * (1.0f / NNODE);
        float var = colvar[j] * (1.0f / NNODE);
        float v = x[idx] - ms[j] * mu;
        float y = g[j] * v / sqrtf(var + 1e-5f) + be[j];
        y = y > 0.f ? y : 0.f;
        x[idx] = y;
        unsigned short h = f2bf(y);
        xbh[idx] = h;
        xbl[idx] = f2bf(y - bf2f(h));
    }
}

// ---------------- prediction head ----------------
__global__ __launch_bounds__(256) void head_kernel(const float* __restrict__ x2,
                                                   const int* __restrict__ idd,
                                                   const int* __restrict__ idc,
                                                   const float* __restrict__ Wout,
                                                   const float* __restrict__ bout,
                                                   float* __restrict__ out0)
{
    int w = threadIdx.x >> 6, l = threadIdx.x & 63;
    int b = blockIdx.x * 4 + w;
    if (b >= BSZ) return;
    int rd = idd[b], rc = idc[b];
    float s = 0.f;
    #pragma unroll
    for (int k = l; k < HD; k += 64)
        s += x2[(long)rd * HD + k] * Wout[k] + x2[(long)rc * HD + k] * Wout[HD + k];
    for (int off = 32; off; off >>= 1) s += __shfl_down(s, off);
    if (l == 0) out0[b] = s + bout[0];
}

// ---------------- all_att: zero + scatter scalar ----------------
__global__ void zero_f4_kernel(float4* __restrict__ p, long n4)
{
    long stride = (long)gridDim.x * blockDim.x;
    for (long i = (long)blockIdx.x * blockDim.x + threadIdx.x; i < n4; i += stride)
        p[i] = make_float4(0.f, 0.f, 0.f, 0.f);
}

__global__ void scatter_att_kernel(const int* __restrict__ ei, float* __restrict__ attm)
{
    int e = blockIdx.x * blockDim.x + threadIdx.x;
    if (e >= ET) return;
    int s, d;
    if (e < E0) { s = ei[e]; d = ei[E0 + e]; }
    else        { s = d = e - E0; }
    const float val = 2.0f * (float)NNODE / (float)ET;
    attm[(long)s * NNODE + d] = val;
}

// ---------------- launch ----------------
extern "C" void kernel_launch(void* const* d_in, const int* in_sizes, int n_in,
                              void* d_out, int out_size, void* d_ws, size_t ws_size,
                              hipStream_t stream)
{
    const float* drug   = (const float*)d_in[0];
    const float* cell   = (const float*)d_in[1];
    const float* gene   = (const float*)d_in[2];
    const float* eattr  = (const float*)d_in[3];
    const int*   ei     = (const int*)d_in[4];
    const int*   idd    = (const int*)d_in[5];
    const int*   idc    = (const int*)d_in[6];
    const float* Wdrug  = (const float*)d_in[7];
    const float* bdrug  = (const float*)d_in[8];
    const float* Wcell  = (const float*)d_in[9];
    const float* bcell  = (const float*)d_in[10];
    const float* Wgene  = (const float*)d_in[11];
    const float* bgene  = (const float*)d_in[12];
    const float* W1     = (const float*)d_in[13];
    const float* b1     = (const float*)d_in[14];
    const float* as1    = (const float*)d_in[15];
    const float* ad1    = (const float*)d_in[16];
    const float* We1    = (const float*)d_in[17];
    const float* ae1    = (const float*)d_in[18];
    const float* bias1  = (const float*)d_in[19];
    const float* g1     = (const float*)d_in[20];
    const float* be1    = (const float*)d_in[21];
    const float* ms1    = (const float*)d_in[22];
    const float* W2     = (const float*)d_in[23];
    const float* b2     = (const float*)d_in[24];
    const float* as2    = (const float*)d_in[25];
    const float* ad2    = (const float*)d_in[26];
    const float* We2    = (const float*)d_in[27];
    const float* ae2    = (const float*)d_in[28];
    const float* bias2  = (const float*)d_in[29];
    const float* g2     = (const float*)d_in[30];
    const float* be2    = (const float*)d_in[31];
    const float* ms2    = (const float*)d_in[32];
    const float* Wout   = (const float*)d_in[33];
    const float* bout   = (const float*)d_in[34];

    float* out0 = (float*)d_out;                 // [10000]
    float* attm = (float*)d_out + BSZ;           // [8000*8000]

    // ---- workspace layout ----
    float* ws     = (float*)d_ws;
    float* xw     = ws;                          // 8000*512
    float* outb   = xw + (long)NNODE * HD;       // 8000*512
    float* alpha  = outb + (long)NNODE * HD;     // 168000*4
    float* csr_al = alpha + (long)ET * 4;        // 168000*4
    float* a_src  = csr_al + (long)ET * 4;       // 32000
    float* a_dst  = a_src + NNODE * 4;           // 32000
    float* mbuf   = a_dst + NNODE * 4;           // 32000
    float* colsum = mbuf + NNODE * 4;            // 512
    float* colvar = colsum + 512;                // 512
    float* ce     = colvar + 512;                // 8
    float* scal   = ce + 8;                      // 8
    int* deg      = (int*)(scal + 8);            // 8000
    int* rs       = deg + NNODE;                 // 8004 (padded)
    int* cursor   = rs + NNODE + 4;              // 8000
    int* csr_src  = cursor + NNODE;              // 168000
    int* csr_eid  = csr_src + ET;                // 168000
    unsigned short* p = (unsigned short*)(csr_eid + ET);
    unsigned short* gene_h = p; p += (long)6016 * GKP;
    unsigned short* gene_l = p; p += (long)6016 * GKP;
    unsigned short* drug_h = p; p += (long)1024 * 1024;
    unsigned short* drug_l = p; p += (long)1024 * 1024;
    unsigned short* cell_h = p; p += (long)1024 * 1024;
    unsigned short* cell_l = p; p += (long)1024 * 1024;
    unsigned short* x0_h   = p; p += (long)NNODE * H1;
    unsigned short* x0_l   = p; p += (long)NNODE * H1;
    unsigned short* xb_h   = p; p += (long)NNODE * HD;
    unsigned short* xb_l   = p; p += (long)NNODE * HD;
    unsigned short* Wd_h   = p; p += 256 * 1024;
    unsigned short* Wd_l   = p; p += 256 * 1024;
    unsigned short* Wc_h   = p; p += 256 * 1024;
    unsigned short* Wc_l   = p; p += 256 * 1024;
    unsigned short* Wg_h   = p; p += 256 * GKP;
    unsigned short* Wg_l   = p; p += 256 * GKP;
    unsigned short* W1_h   = p; p += 512 * 256;
    unsigned short* W1_l   = p; p += 512 * 256;
    unsigned short* W2_h   = p; p += 512 * 512;
    unsigned short* W2_l   = p; p += 512 * 512;
    float* partsk = (float*)((((unsigned long long)p) + 15) & ~15ULL);  // ZSPLIT*NGENE*H1 f32

    dim3 blk256(256);
    int gE = (ET + 255) / 256;

    // init + small precomputes
    init1_kernel<<<125, blk256, 0, stream>>>(mbuf, deg, colsum, scal);
    reduce_sum_kernel<<<64, blk256, 0, stream>>>(eattr, E0, &scal[0]);
    ce_kernel<<<1, 512, 0, stream>>>(We1, ae1, We2, ae2, ce);

    // ---- hi/lo split conversions ----
    cvt_pad2_kernel<<<512, blk256, 0, stream>>>(drug, drug_h, drug_l, NDRUG, NDRUG, 1024, 1024);
    cvt_pad2_kernel<<<512, blk256, 0, stream>>>(cell, cell_h, cell_l, NCELL, NCELL, 1024, 1024);
    cvt_pad2_kernel<<<2048, blk256, 0, stream>>>(gene, gene_h, gene_l, NGENE, NGENE, 6016, GKP);
    transpose_cvt2_kernel<<<dim3(32, 8),  blk256, 0, stream>>>(Wdrug, Wd_h, Wd_l, NDRUG, H1, 1024);
    transpose_cvt2_kernel<<<dim3(32, 8),  blk256, 0, stream>>>(Wcell, Wc_h, Wc_l, NCELL, H1, 1024);
    transpose_cvt2_kernel<<<dim3(188, 8), blk256, 0, stream>>>(Wgene, Wg_h, Wg_l, NGENE, H1, GKP);
    transpose_cvt2_kernel<<<dim3(8, 16),  blk256, 0, stream>>>(W1, W1_h, W1_l, H1, HD, H1);
    transpose_cvt2_kernel<<<dim3(16, 16), blk256, 0, stream>>>(W2, W2_h, W2_l, HD, HD, HD);

    // ---- input projections -> x0 (hi/lo bf16) ----
    gemm_mfma2<1><<<dim3(H1 / 64, 16), blk256, 0, stream>>>(drug_h, drug_l, Wd_h, Wd_l, bdrug,
        nullptr, x0_h, x0_l, NDRUG, 1024, H1);
    gemm_mfma2<1><<<dim3(H1 / 64, 16), blk256, 0, stream>>>(cell_h, cell_l, Wc_h, Wc_l, bcell,
        nullptr, x0_h + (long)NDRUG * H1, x0_l + (long)NDRUG * H1, NCELL, 1024, H1);
    gemm_gene_splitk<<<dim3(2, 47, ZSPLIT), blk256, 0, stream>>>(gene_h, gene_l, Wg_h, Wg_l, partsk);
    reduce_splitk_kernel<<<1500, blk256, 0, stream>>>(partsk, bgene, x0_h, x0_l);

    // ---- layer 1 ----
    gemm_mfma128<0><<<dim3(HD / 128, (NNODE + 127) / 128), blk256, 0, stream>>>(x0_h, x0_l, W1_h, W1_l, b1,
        xw, nullptr, nullptr, NNODE, H1, HD);
    attn_coef_kernel<<<NNODE, 64, 0, stream>>>(xw, as1, ad1, a_src, a_dst);
    alpha_max_kernel<<<gE, blk256, 0, stream>>>(ei, eattr, scal, a_src, a_dst, ce, alpha, mbuf, deg, 1);
    scan_kernel<<<1, 1024, 0, stream>>>(deg, rs, cursor);
    scatter_csr_kernel<<<gE, blk256, 0, stream>>>(ei, cursor, csr_src, csr_eid);
    csr_alpha_gather_kernel<<<gE, blk256, 0, stream>>>(csr_eid, alpha, csr_al);
    aggregate_kernel<<<NNODE, blk256, 0, stream>>>(xw, csr_al, mbuf, rs, csr_src, bias1, outb);
    colsum_kernel<<<64, blk256, 0, stream>>>(outb, colsum);
    colvar_kernel<<<64, blk256, 0, stream>>>(outb, colsum, ms1, colvar);
    norm_kernel<<<2048, blk256, 0, stream>>>(outb, xb_h, xb_l, colsum, colvar, g1, be1, ms1);

    // ---- layer 2 ----
    gemm_mfma128<0><<<dim3(HD / 128, (NNODE + 127) / 128), blk256, 0, stream>>>(xb_h, xb_l, W2_h, W2_l, b2,
        xw, nullptr, nullptr, NNODE, HD, HD);
    attn_coef_kernel<<<NNODE, 64, 0, stream>>>(xw, as2, ad2, a_src, a_dst);
    init2_kernel<<<125, blk256, 0, stream>>>(mbuf, colsum);
    alpha_max_kernel<<<gE, blk256, 0, stream>>>(ei, eattr, scal, a_src, a_dst, ce + 4, alpha, mbuf, deg, 0);
    csr_alpha_gather_kernel<<<gE, blk256, 0, stream>>>(csr_eid, alpha, csr_al);
    aggregate_kernel<<<NNODE, blk256, 0, stream>>>(xw, csr_al, mbuf, rs, csr_src, bias2, outb);
    colsum_kernel<<<64, blk256, 0, stream>>>(outb, colsum);
    colvar_kernel<<<64, blk256, 0, stream>>>(outb, colsum, ms2, colvar);
    norm_kernel<<<2048, blk256, 0, stream>>>(outb, xb_h, xb_l, colsum, colvar, g2, be2, ms2);

    // ---- head + attention matrix ----
    head_kernel<<<(BSZ + 3) / 4, blk256, 0, stream>>>(outb, idd, idc, Wout, bout, out0);
    zero_f4_kernel<<<2048, blk256, 0, stream>>>((float4*)attm, (long)NNODE * NNODE / 4);
    scatter_att_kernel<<<gE, blk256, 0, stream>>>(ei, attm);
}

// Round 9
// 696.151 us; speedup vs baseline: 1.0691x; 1.0575x over previous
//
#include <hip/hip_runtime.h>
#include <math.h>

// ---------------- problem constants ----------------
#define NDRUG 1000
#define NCELL 1000
#define NGENE 6000
#define NNODE 8000
#define H1 256
#define HD  512   // HEADS*H2 = HEADS*H3
#define E0  160000
#define ET  168000   // E0 + NNODE self loops
#define BSZ 10000
#define GKP 6016    // padded gene K
#define ZSPLIT 8    // gene split-K factor

typedef __attribute__((ext_vector_type(8))) short bf16x8;
typedef __attribute__((ext_vector_type(4))) float f32x4;

__device__ inline unsigned short f2bf(float f)
{
    unsigned u = __float_as_uint(f);
    u += 0x7fffu + ((u >> 16) & 1u);   // RNE
    return (unsigned short)(u >> 16);
}
__device__ inline float bf2f(unsigned short h)
{
    return __uint_as_float(((unsigned)h) << 16);
}

// async global->LDS, 16B per lane; LDS dest = base + lane*16 (wave-uniform base)
__device__ inline void gld16(const unsigned short* g, char* l)
{
    __builtin_amdgcn_global_load_lds(
        (const __attribute__((address_space(1))) unsigned int*)g,
        (__attribute__((address_space(3))) unsigned int*)l,
        16, 0, 0);
}

// ---------------- f32 -> (hi,lo) bf16 with [Mp][Kp] zero padding ----------------
__global__ void cvt_pad2_kernel(const float* __restrict__ in,
                                unsigned short* __restrict__ hi,
                                unsigned short* __restrict__ lo,
                                int M, int K, int Mp, int Kp)
{
    long total = (long)Mp * Kp / 8;
    int kp8 = Kp / 8;
    long stride = (long)gridDim.x * blockDim.x;
    for (long u = (long)blockIdx.x * blockDim.x + threadIdx.x; u < total; u += stride) {
        long row = u / kp8; int kc = (int)(u % kp8);
        unsigned short oh[8], ol[8];
        if (row < M && kc * 8 < K) {   // K%8==0
            const float* p = in + row * (long)K + kc * 8;
            float4 a = *(const float4*)p, b = *(const float4*)(p + 4);
            float v[8] = {a.x, a.y, a.z, a.w, b.x, b.y, b.z, b.w};
            #pragma unroll
            for (int i = 0; i < 8; ++i) {
                unsigned short h = f2bf(v[i]);
                oh[i] = h;
                ol[i] = f2bf(v[i] - bf2f(h));
            }
        } else {
            #pragma unroll
            for (int i = 0; i < 8; ++i) { oh[i] = 0; ol[i] = 0; }
        }
        *(uint4*)(hi + u * 8) = *(const uint4*)oh;
        *(uint4*)(lo + u * 8) = *(const uint4*)ol;
    }
}

// ---------------- W[K][N] f32 -> Wt_{hi,lo}[N][Kp] bf16 ----------------
__global__ __launch_bounds__(256) void transpose_cvt2_kernel(const float* __restrict__ W,
                                                             unsigned short* __restrict__ Wh,
                                                             unsigned short* __restrict__ Wl,
                                                             int K, int N, int Kp)
{
    __shared__ float t[32][33];
    int kb = blockIdx.x * 32, nb = blockIdx.y * 32;
    int tx = threadIdx.x & 31, ty = threadIdx.x >> 5;  // ty 0..7
    #pragma unroll
    for (int i = 0; i < 32; i += 8) {
        int k = kb + ty + i;
        t[ty + i][tx] = (k < K) ? W[(long)k * N + nb + tx] : 0.f;
    }
    __syncthreads();
    #pragma unroll
    for (int i = 0; i < 32; i += 8) {
        int n = nb + ty + i;
        float v = t[tx][ty + i];
        unsigned short h = f2bf(v);
        Wh[(long)n * Kp + kb + tx] = h;
        Wl[(long)n * Kp + kb + tx] = f2bf(v - bf2f(h));
    }
}

// ---------------- split-bf16 MFMA GEMM, 64x64 tile ----------------
template<int OUTBF>
__global__ __launch_bounds__(256) void gemm_mfma2(const unsigned short* __restrict__ Ah,
                                                  const unsigned short* __restrict__ Al,
                                                  const unsigned short* __restrict__ Bh,
                                                  const unsigned short* __restrict__ Bl,
                                                  const float* __restrict__ bias,
                                                  float* __restrict__ Cf,
                                                  unsigned short* __restrict__ Cbh,
                                                  unsigned short* __restrict__ Cbl,
                                                  int M, int Kp, int N)
{
    __shared__ unsigned short AsH[64 * 64];
    __shared__ unsigned short AsL[64 * 64];
    __shared__ unsigned short BsH[64 * 64];
    __shared__ unsigned short BsL[64 * 64];
    char* AsH8 = (char*)AsH; char* AsL8 = (char*)AsL;
    char* BsH8 = (char*)BsH; char* BsL8 = (char*)BsL;
    int tid = threadIdx.x;
    int w = tid >> 6, l = tid & 63;
    int wr = w >> 1, wc = w & 1;
    int g = l >> 4, r16 = l & 15;
    int row0 = blockIdx.y * 64, col0 = blockIdx.x * 64;
    int srow = tid >> 3, skc = tid & 7;
    int B0 = srow * 128 + skc * 16;       int P0 = B0 ^ ((srow & 7) << 4);
    int r1 = srow + 32;                   int B1 = r1 * 128 + skc * 16;
    int P1 = B1 ^ ((r1 & 7) << 4);
    f32x4 acc[2][2] = {};
    for (int k0 = 0; k0 < Kp; k0 += 64) {
        long a0 = (long)(row0 + srow) * Kp + k0 + skc * 8;
        long a1 = (long)(row0 + srow + 32) * Kp + k0 + skc * 8;
        long b0 = (long)(col0 + srow) * Kp + k0 + skc * 8;
        long b1 = (long)(col0 + srow + 32) * Kp + k0 + skc * 8;
        uint4 ah0 = *(const uint4*)(Ah + a0); uint4 ah1 = *(const uint4*)(Ah + a1);
        uint4 al0 = *(const uint4*)(Al + a0); uint4 al1 = *(const uint4*)(Al + a1);
        uint4 bh0 = *(const uint4*)(Bh + b0); uint4 bh1 = *(const uint4*)(Bh + b1);
        uint4 bl0 = *(const uint4*)(Bl + b0); uint4 bl1 = *(const uint4*)(Bl + b1);
        __syncthreads();
        *(uint4*)(AsH8 + P0) = ah0; *(uint4*)(AsH8 + P1) = ah1;
        *(uint4*)(AsL8 + P0) = al0; *(uint4*)(AsL8 + P1) = al1;
        *(uint4*)(BsH8 + P0) = bh0; *(uint4*)(BsH8 + P1) = bh1;
        *(uint4*)(BsL8 + P0) = bl0; *(uint4*)(BsL8 + P1) = bl1;
        __syncthreads();
        #pragma unroll
        for (int kk = 0; kk < 2; ++kk) {
            bf16x8 afh[2], afl[2], bfh[2], bfl[2];
            #pragma unroll
            for (int m = 0; m < 2; ++m) {
                int row = wr * 32 + m * 16 + r16;
                int Bb = (row * 128 + kk * 64 + g * 16) ^ ((row & 7) << 4);
                afh[m] = *(const bf16x8*)(AsH8 + Bb);
                afl[m] = *(const bf16x8*)(AsL8 + Bb);
            }
            #pragma unroll
            for (int n = 0; n < 2; ++n) {
                int row = wc * 32 + n * 16 + r16;
                int Bb = (row * 128 + kk * 64 + g * 16) ^ ((row & 7) << 4);
                bfh[n] = *(const bf16x8*)(BsH8 + Bb);
                bfl[n] = *(const bf16x8*)(BsL8 + Bb);
            }
            #pragma unroll
            for (int m = 0; m < 2; ++m)
                #pragma unroll
                for (int n = 0; n < 2; ++n) {
                    acc[m][n] = __builtin_amdgcn_mfma_f32_16x16x32_bf16(afh[m], bfh[n], acc[m][n], 0, 0, 0);
                    acc[m][n] = __builtin_amdgcn_mfma_f32_16x16x32_bf16(afh[m], bfl[n], acc[m][n], 0, 0, 0);
                    acc[m][n] = __builtin_amdgcn_mfma_f32_16x16x32_bf16(afl[m], bfh[n], acc[m][n], 0, 0, 0);
                }
        }
    }
    #pragma unroll
    for (int m = 0; m < 2; ++m) {
        #pragma unroll
        for (int n = 0; n < 2; ++n) {
            #pragma unroll
            for (int r = 0; r < 4; ++r) {
                int rowg = row0 + wr * 32 + m * 16 + g * 4 + r;
                int colg = col0 + wc * 32 + n * 16 + r16;
                if (rowg < M) {
                    float v = acc[m][n][r] + bias[colg];
                    if (OUTBF) {
                        unsigned short h = f2bf(v);
                        Cbh[(long)rowg * N + colg] = h;
                        Cbl[(long)rowg * N + colg] = f2bf(v - bf2f(h));
                    } else {
                        Cf[(long)rowg * N + colg] = v;
                    }
                }
            }
        }
    }
}

// ---------------- gene GEMM: 128x128 tile, BK=64, global_load_lds, split-K ----------------
__global__ __launch_bounds__(256) void gemm_gene_splitk(const unsigned short* __restrict__ Ah,
                                                        const unsigned short* __restrict__ Al,
                                                        const unsigned short* __restrict__ Bh,
                                                        const unsigned short* __restrict__ Bl,
                                                        float* __restrict__ part)
{
    __shared__ char lds[65536];
    char* AsH = lds;          char* AsL = lds + 16384;
    char* BsH = lds + 32768;  char* BsL = lds + 49152;
    int tid = threadIdx.x;
    int w = tid >> 6, l = tid & 63;
    int wr = w >> 1, wc = w & 1;
    int g = l >> 4, r16 = l & 15;
    int row0 = blockIdx.y * 128, col0 = blockIdx.x * 128;
    int z = blockIdx.z;
    int kbeg = z * 768;
    int kend = kbeg + 768; if (kend > GKP) kend = GKP;
    int rr = l >> 3, s = l & 7;
    int swz = s ^ rr;
    f32x4 acc[4][4] = {};
    for (int k0 = kbeg; k0 < kend; k0 += 64) {
        __syncthreads();
        #pragma unroll
        for (int i = 0; i < 4; ++i) {
            int rt = w * 32 + i * 8;
            long koff = (long)k0 + swz * 8;
            const unsigned short* ga  = Ah + (long)(row0 + rt + rr) * GKP + koff;
            const unsigned short* gal = Al + (long)(row0 + rt + rr) * GKP + koff;
            const unsigned short* gb  = Bh + (long)(col0 + rt + rr) * GKP + koff;
            const unsigned short* gbl = Bl + (long)(col0 + rt + rr) * GKP + koff;
            int lbase = rt * 128;
            gld16(ga,  AsH + lbase);
            gld16(gal, AsL + lbase);
            gld16(gb,  BsH + lbase);
            gld16(gbl, BsL + lbase);
        }
        __syncthreads();
        #pragma unroll
        for (int kk = 0; kk < 2; ++kk) {
            bf16x8 afh[4], afl[4], bfh[4], bfl[4];
            #pragma unroll
            for (int m = 0; m < 4; ++m) {
                int row = wr * 64 + m * 16 + r16;
                int Bb = (row * 128 + kk * 64 + g * 16) ^ ((row & 7) << 4);
                afh[m] = *(const bf16x8*)(AsH + Bb);
                afl[m] = *(const bf16x8*)(AsL + Bb);
            }
            #pragma unroll
            for (int n = 0; n < 4; ++n) {
                int row = wc * 64 + n * 16 + r16;
                int Bb = (row * 128 + kk * 64 + g * 16) ^ ((row & 7) << 4);
                bfh[n] = *(const bf16x8*)(BsH + Bb);
                bfl[n] = *(const bf16x8*)(BsL + Bb);
            }
            #pragma unroll
            for (int m = 0; m < 4; ++m)
                #pragma unroll
                for (int n = 0; n < 4; ++n) {
                    acc[m][n] = __builtin_amdgcn_mfma_f32_16x16x32_bf16(afh[m], bfh[n], acc[m][n], 0, 0, 0);
                    acc[m][n] = __builtin_amdgcn_mfma_f32_16x16x32_bf16(afh[m], bfl[n], acc[m][n], 0, 0, 0);
                    acc[m][n] = __builtin_amdgcn_mfma_f32_16x16x32_bf16(afl[m], bfh[n], acc[m][n], 0, 0, 0);
                }
        }
    }
    #pragma unroll
    for (int m = 0; m < 4; ++m) {
        #pragma unroll
        for (int n = 0; n < 4; ++n) {
            #pragma unroll
            for (int r = 0; r < 4; ++r) {
                int rowg = row0 + wr * 64 + m * 16 + g * 4 + r;
                int colg = col0 + wc * 64 + n * 16 + r16;
                if (rowg < NGENE)
                    part[((long)z * NGENE + rowg) * H1 + colg] = acc[m][n][r];
            }
        }
    }
}

// ---------------- split-K reduce ----------------
__global__ __launch_bounds__(256) void reduce_splitk_kernel(const float* __restrict__ part,
                                                            const float* __restrict__ bias,
                                                            unsigned short* __restrict__ xh,
                                                            unsigned short* __restrict__ xl)
{
    const long NEL = (long)NGENE * H1;
    long stride = (long)gridDim.x * blockDim.x;
    for (long q = (long)blockIdx.x * blockDim.x + threadIdx.x; q * 4 < NEL; q += stride) {
        long e = q * 4;
        float4 sv = *(const float4*)(part + e);
        #pragma unroll
        for (int z = 1; z < ZSPLIT; ++z) {
            float4 t = *(const float4*)(part + (long)z * NEL + e);
            sv.x += t.x; sv.y += t.y; sv.z += t.z; sv.w += t.w;
        }
        int col = (int)(e & (H1 - 1));
        float4 b = *(const float4*)(bias + col);
        float v[4] = {sv.x + b.x, sv.y + b.y, sv.z + b.z, sv.w + b.w};
        unsigned short oh[4], ol[4];
        #pragma unroll
        for (int i = 0; i < 4; ++i) {
            oh[i] = f2bf(v[i]);
            ol[i] = f2bf(v[i] - bf2f(oh[i]));
        }
        long o = (long)(NDRUG + NCELL) * H1 + e;
        *(uint2*)(xh + o) = *(const uint2*)oh;
        *(uint2*)(xl + o) = *(const uint2*)ol;
    }
}

// ---------------- init kernels ----------------
__global__ void init1_kernel(float* m, int* deg, float* colstats, float* scal)
{
    int i = blockIdx.x * 256 + threadIdx.x;
    if (i < NNODE * 4) m[i] = -3.402823466e38f;
    if (i < NNODE) deg[i] = 0;
    if (i < 1024) colstats[i] = 0.f;
    if (i < 8) scal[i] = 0.f;
}

__global__ void init2_kernel(float* m, float* colstats)
{
    int i = blockIdx.x * 256 + threadIdx.x;
    if (i < NNODE * 4) m[i] = -3.402823466e38f;
    if (i < 1024) colstats[i] = 0.f;
}

// ---------------- sum(edge_attr) -> scal[0] ----------------
__global__ void reduce_sum_kernel(const float* __restrict__ x, int n, float* out)
{
    float s = 0.f;
    for (int i = blockIdx.x * blockDim.x + threadIdx.x; i < n; i += gridDim.x * blockDim.x)
        s += x[i];
    for (int off = 32; off; off >>= 1) s += __shfl_down(s, off);
    if ((threadIdx.x & 63) == 0) atomicAdd(out, s);
}

// ---------------- ce[h] ----------------
__global__ __launch_bounds__(512) void ce_kernel(const float* We1, const float* ae1,
                                                 const float* We2, const float* ae2, float* ce)
{
    __shared__ float sm[512];
    int t = threadIdx.x;
    sm[t] = We1[t] * ae1[t];
    __syncthreads();
    if (t < 4) { float s = 0.f; for (int c = 0; c < 128; ++c) s += sm[t * 128 + c]; ce[t] = s; }
    __syncthreads();
    sm[t] = We2[t] * ae2[t];
    __syncthreads();
    if (t < 4) { float s = 0.f; for (int c = 0; c < 128; ++c) s += sm[t * 128 + c]; ce[4 + t] = s; }
}

// ---------------- per-node attention coefficients (4 nodes per block) ----------------
__global__ __launch_bounds__(256) void attn_coef_kernel(const float* __restrict__ xw,
                                                        const float* __restrict__ as,
                                                        const float* __restrict__ ad,
                                                        float* __restrict__ a_src,
                                                        float* __restrict__ a_dst)
{
    int n = blockIdx.x * 4 + (threadIdx.x >> 6);
    int l = threadIdx.x & 63;
    #pragma unroll
    for (int h = 0; h < 4; ++h) {
        float x1 = xw[(long)n * HD + h * 128 + l];
        float x2 = xw[(long)n * HD + h * 128 + 64 + l];
        float s = x1 * as[h * 128 + l] + x2 * as[h * 128 + 64 + l];
        float d = x1 * ad[h * 128 + l] + x2 * ad[h * 128 + 64 + l];
        for (int off = 32; off; off >>= 1) { s += __shfl_down(s, off); d += __shfl_down(d, off); }
        if (l == 0) { a_src[n * 4 + h] = s; a_dst[n * 4 + h] = d; }
    }
}

// ---------------- atomic float max ----------------
__device__ inline void atomicMaxF(float* addr, float v)
{
    if (v >= 0.f) atomicMax((int*)addr, __float_as_int(v));
    else          atomicMin((unsigned int*)addr, __float_as_uint(v));
}

// ---------------- per-edge alpha + segment max ----------------
// MODE1 (layer 1): write alpha[e] sequentially + degree histogram.
// MODE0 (layer 2): scatter directly to csr_alpha[pos_of_e[e]] (CSR known).
__global__ void alpha_max_kernel(const int* __restrict__ ei, const float* __restrict__ eattr,
                                 const float* __restrict__ scal,
                                 const float* __restrict__ a_src, const float* __restrict__ a_dst,
                                 const float* __restrict__ ce,
                                 float* __restrict__ alpha,          // MODE1 dest
                                 float* __restrict__ csr_alpha,      // MODE0 dest
                                 const int* __restrict__ pos_of_e,   // MODE0 map
                                 float* __restrict__ m,
                                 int* __restrict__ deg, int mode1)
{
    int e = blockIdx.x * blockDim.x + threadIdx.x;
    if (e >= ET) return;
    int s, d; float a;
    if (e < E0) { s = ei[e]; d = ei[E0 + e]; a = eattr[e]; }
    else        { s = d = e - E0; a = scal[0] * (1.0f / E0); }
    float4 av;
    float* avp = (float*)&av;
    #pragma unroll
    for (int h = 0; h < 4; ++h) {
        float v = a_src[s * 4 + h] + a_dst[d * 4 + h] + a * ce[h];
        v = v > 0.f ? v : 0.2f * v;
        avp[h] = v;
        atomicMaxF(&m[d * 4 + h], v);
    }
    if (mode1) {
        *(float4*)(alpha + (long)e * 4) = av;
        atomicAdd(&deg[d], 1);
    } else {
        *(float4*)(csr_alpha + (long)pos_of_e[e] * 4) = av;
    }
}

// ---------------- exclusive scan ----------------
__global__ __launch_bounds__(1024) void scan_kernel(const int* __restrict__ deg,
                                                    int* __restrict__ row_start,
                                                    int* __restrict__ cursor)
{
    __shared__ int sm[1024];
    int t = threadIdx.x;
    int base = t * 8;
    int loc[8];
    int sum = 0;
    #pragma unroll
    for (int j = 0; j < 8; ++j) {
        int v = (base + j < NNODE) ? deg[base + j] : 0;
        loc[j] = sum; sum += v;
    }
    sm[t] = sum;
    __syncthreads();
    for (int off = 1; off < 1024; off <<= 1) {
        int v = (t >= off) ? sm[t - off] : 0;
        __syncthreads();
        sm[t] += v;
        __syncthreads();
    }
    int excl = sm[t] - sum;
    #pragma unroll
    for (int j = 0; j < 8; ++j) {
        int idx = base + j;
        if (idx < NNODE) { int v = excl + loc[j]; row_start[idx] = v; cursor[idx] = v; }
    }
    if (t == 1023) row_start[NNODE] = sm[1023];
}

// ---------------- scatter edges into CSR (by dst) + csr_alpha + pos_of_e ----------------
__global__ void scatter_csr_kernel(const int* __restrict__ ei, int* __restrict__ cursor,
                                   const float* __restrict__ alpha,
                                   int* __restrict__ csr_src, int* __restrict__ pos_of_e,
                                   float* __restrict__ csr_alpha)
{
    int e = blockIdx.x * blockDim.x + threadIdx.x;
    if (e >= ET) return;
    int s, d;
    if (e < E0) { s = ei[e]; d = ei[E0 + e]; }
    else        { s = d = e - E0; }
    int pos = atomicAdd(&cursor[d], 1);
    csr_src[pos] = s;
    pos_of_e[e] = pos;
    *(float4*)(csr_alpha + (long)pos * 4) = *(const float4*)(alpha + (long)e * 4);
}

// ---------------- aggregation: one block (4 waves = 4 heads) per node, ILP=8 ----------------
__global__ __launch_bounds__(256) void aggregate_kernel(const float* __restrict__ xw,
                                                        const float* __restrict__ csr_alpha,
                                                        const float* __restrict__ m,
                                                        const int* __restrict__ rs,
                                                        const int* __restrict__ csr_src,
                                                        const float* __restrict__ bias,
                                                        float* __restrict__ out)
{
    int n = blockIdx.x;
    int h = threadIdx.x >> 6;
    int l = threadIdx.x & 63;
    float mnh = m[n * 4 + h];
    int i0 = rs[n], i1 = rs[n + 1];
    float den = 0.f;
    for (int i = i0 + l; i < i1; i += 64)
        den += expf(csr_alpha[(long)i * 4 + h] - mnh);
    for (int off = 32; off; off >>= 1) den += __shfl_down(den, off);
    den = __shfl(den, 0);
    float rden = 1.0f / (den + 1e-16f);
    float acc0 = 0.f, acc1 = 0.f;
    int i = i0;
    for (; i + 7 < i1; i += 8) {
        int   sv[8];
        float av[8], xv0[8], xv1[8];
        #pragma unroll
        for (int j = 0; j < 8; ++j) {
            sv[j] = csr_src[i + j];
            av[j] = csr_alpha[(long)(i + j) * 4 + h];
        }
        #pragma unroll
        for (int j = 0; j < 8; ++j) {
            const float* r = xw + (long)sv[j] * HD + h * 128;
            xv0[j] = r[l]; xv1[j] = r[64 + l];
        }
        #pragma unroll
        for (int j = 0; j < 8; ++j) {
            float w = expf(av[j] - mnh);
            acc0 += w * xv0[j];
            acc1 += w * xv1[j];
        }
    }
    for (; i < i1; ++i) {
        int s = csr_src[i];
        float w = expf(csr_alpha[(long)i * 4 + h] - mnh);
        const float* xr = xw + (long)s * HD + h * 128;
        acc0 += w * xr[l];
        acc1 += w * xr[64 + l];
    }
    out[(long)n * HD + h * 128 + l]      = acc0 * rden + bias[h * 128 + l];
    out[(long)n * HD + h * 128 + 64 + l] = acc1 * rden + bias[h * 128 + 64 + l];
}

// ---------------- graph norm: fused column sum + sum-of-squares (one pass) ----------------
__global__ __launch_bounds__(256) void colstats_kernel(const float* __restrict__ x,
                                                       float* __restrict__ colsum,
                                                       float* __restrict__ colsumsq)
{
    int t = threadIdx.x, b = blockIdx.x;
    float s0 = 0.f, s1 = 0.f, q0 = 0.f, q1 = 0.f;
    for (int r = b * 125; r < (b + 1) * 125; ++r) {
        float v0 = x[(long)r * HD + t];
        float v1 = x[(long)r * HD + t + 256];
        s0 += v0; q0 += v0 * v0;
        s1 += v1; q1 += v1 * v1;
    }
    atomicAdd(&colsum[t], s0);
    atomicAdd(&colsum[t + 256], s1);
    atomicAdd(&colsumsq[t], q0);
    atomicAdd(&colsumsq[t + 256], q1);
}

// norm (+ReLU) in place; var = E[x^2] - ms*(2-ms)*mu^2 ; writes hi/lo bf16 copies
__global__ void norm_kernel(float* __restrict__ x,
                            unsigned short* __restrict__ xbh, unsigned short* __restrict__ xbl,
                            const float* __restrict__ colsum,
                            const float* __restrict__ colsumsq,
                            const float* __restrict__ g, const float* __restrict__ be,
                            const float* __restrict__ ms)
{
    int stride = gridDim.x * blockDim.x;
    for (int idx = blockIdx.x * blockDim.x + threadIdx.x; idx < NNODE * HD; idx += stride) {
        int j = idx & 511;
        float mu  = colsum[j] * (1.0f / NNODE);
        float ex2 = colsumsq[j] * (1.0f / NNODE);
        float msj = ms[j];
        float var = ex2 - msj * (2.0f - msj) * mu * mu;
        float v = x[idx] - msj * mu;
        float y = g[j] * v / sqrtf(var + 1e-5f) + be[j];
        y = y > 0.f ? y : 0.f;
        x[idx] = y;
        unsigned short h = f2bf(y);
        xbh[idx] = h;
        xbl[idx] = f2bf(y - bf2f(h));
    }
}

// ---------------- prediction head ----------------
__global__ __launch_bounds__(256) void head_kernel(const float* __restrict__ x2,
                                                   const int* __restrict__ idd,
                                                   const int* __restrict__ idc,
                                                   const float* __restrict__ Wout,
                                                   const float* __restrict__ bout,
                                                   float* __restrict__ out0)
{
    int w = threadIdx.x >> 6, l = threadIdx.x & 63;
    int b = blockIdx.x * 4 + w;
    if (b >= BSZ) return;
    int rd = idd[b], rc = idc[b];
    float s = 0.f;
    #pragma unroll
    for (int k = l; k < HD; k += 64)
        s += x2[(long)rd * HD + k] * Wout[k] + x2[(long)rc * HD + k] * Wout[HD + k];
    for (int off = 32; off; off >>= 1) s += __shfl_down(s, off);
    if (l == 0) out0[b] = s + bout[0];
}

// ---------------- all_att: zero + scatter scalar ----------------
__global__ void zero_f4_kernel(float4* __restrict__ p, long n4)
{
    long stride = (long)gridDim.x * blockDim.x;
    for (long i = (long)blockIdx.x * blockDim.x + threadIdx.x; i < n4; i += stride)
        p[i] = make_float4(0.f, 0.f, 0.f, 0.f);
}

__global__ void scatter_att_kernel(const int* __restrict__ ei, float* __restrict__ attm)
{
    int e = blockIdx.x * blockDim.x + threadIdx.x;
    if (e >= ET) return;
    int s, d;
    if (e < E0) { s = ei[e]; d = ei[E0 + e]; }
    else        { s = d = e - E0; }
    const float val = 2.0f * (float)NNODE / (float)ET;
    attm[(long)s * NNODE + d] = val;
}

// ---------------- launch ----------------
extern "C" void kernel_launch(void* const* d_in, const int* in_sizes, int n_in,
                              void* d_out, int out_size, void* d_ws, size_t ws_size,
                              hipStream_t stream)
{
    const float* drug   = (const float*)d_in[0];
    const float* cell   = (const float*)d_in[1];
    const float* gene   = (const float*)d_in[2];
    const float* eattr  = (const float*)d_in[3];
    const int*   ei     = (const int*)d_in[4];
    const int*   idd    = (const int*)d_in[5];
    const int*   idc    = (const int*)d_in[6];
    const float* Wdrug  = (const float*)d_in[7];
    const float* bdrug  = (const float*)d_in[8];
    const float* Wcell  = (const float*)d_in[9];
    const float* bcell  = (const float*)d_in[10];
    const float* Wgene  = (const float*)d_in[11];
    const float* bgene  = (const float*)d_in[12];
    const float* W1     = (const float*)d_in[13];
    const float* b1     = (const float*)d_in[14];
    const float* as1    = (const float*)d_in[15];
    const float* ad1    = (const float*)d_in[16];
    const float* We1    = (const float*)d_in[17];
    const float* ae1    = (const float*)d_in[18];
    const float* bias1  = (const float*)d_in[19];
    const float* g1     = (const float*)d_in[20];
    const float* be1    = (const float*)d_in[21];
    const float* ms1    = (const float*)d_in[22];
    const float* W2     = (const float*)d_in[23];
    const float* b2     = (const float*)d_in[24];
    const float* as2    = (const float*)d_in[25];
    const float* ad2    = (const float*)d_in[26];
    const float* We2    = (const float*)d_in[27];
    const float* ae2    = (const float*)d_in[28];
    const float* bias2  = (const float*)d_in[29];
    const float* g2     = (const float*)d_in[30];
    const float* be2    = (const float*)d_in[31];
    const float* ms2    = (const float*)d_in[32];
    const float* Wout   = (const float*)d_in[33];
    const float* bout   = (const float*)d_in[34];

    float* out0 = (float*)d_out;                 // [10000]
    float* attm = (float*)d_out + BSZ;           // [8000*8000]

    // ---- workspace layout ----
    float* ws     = (float*)d_ws;
    float* xw     = ws;                          // 8000*512
    float* outb   = xw + (long)NNODE * HD;       // 8000*512
    float* alpha  = outb + (long)NNODE * HD;     // 168000*4
    float* csr_al = alpha + (long)ET * 4;        // 168000*4
    float* a_src  = csr_al + (long)ET * 4;       // 32000
    float* a_dst  = a_src + NNODE * 4;           // 32000
    float* mbuf   = a_dst + NNODE * 4;           // 32000
    float* colsum = mbuf + NNODE * 4;            // 512
    float* colsq  = colsum + 512;                // 512
    float* ce     = colsq + 512;                 // 8
    float* scal   = ce + 8;                      // 8
    int* deg      = (int*)(scal + 8);            // 8000
    int* rs       = deg + NNODE;                 // 8004 (padded)
    int* cursor   = rs + NNODE + 4;              // 8000
    int* csr_src  = cursor + NNODE;              // 168000
    int* pos_of_e = csr_src + ET;                // 168000
    unsigned short* p = (unsigned short*)(pos_of_e + ET);
    unsigned short* gene_h = p; p += (long)6016 * GKP;
    unsigned short* gene_l = p; p += (long)6016 * GKP;
    unsigned short* drug_h = p; p += (long)1024 * 1024;
    unsigned short* drug_l = p; p += (long)1024 * 1024;
    unsigned short* cell_h = p; p += (long)1024 * 1024;
    unsigned short* cell_l = p; p += (long)1024 * 1024;
    unsigned short* x0_h   = p; p += (long)NNODE * H1;
    unsigned short* x0_l   = p; p += (long)NNODE * H1;
    unsigned short* xb_h   = p; p += (long)NNODE * HD;
    unsigned short* xb_l   = p; p += (long)NNODE * HD;
    unsigned short* Wd_h   = p; p += 256 * 1024;
    unsigned short* Wd_l   = p; p += 256 * 1024;
    unsigned short* Wc_h   = p; p += 256 * 1024;
    unsigned short* Wc_l   = p; p += 256 * 1024;
    unsigned short* Wg_h   = p; p += 256 * GKP;
    unsigned short* Wg_l   = p; p += 256 * GKP;
    unsigned short* W1_h   = p; p += 512 * 256;
    unsigned short* W1_l   = p; p += 512 * 256;
    unsigned short* W2_h   = p; p += 512 * 512;
    unsigned short* W2_l   = p; p += 512 * 512;
    float* partsk = (float*)((((unsigned long long)p) + 15) & ~15ULL);  // ZSPLIT*NGENE*H1 f32

    dim3 blk256(256);
    int gE = (ET + 255) / 256;

    // init + small precomputes
    init1_kernel<<<125, blk256, 0, stream>>>(mbuf, deg, colsum, scal);
    reduce_sum_kernel<<<64, blk256, 0, stream>>>(eattr, E0, &scal[0]);
    ce_kernel<<<1, 512, 0, stream>>>(We1, ae1, We2, ae2, ce);

    // ---- hi/lo split conversions ----
    cvt_pad2_kernel<<<512, blk256, 0, stream>>>(drug, drug_h, drug_l, NDRUG, NDRUG, 1024, 1024);
    cvt_pad2_kernel<<<512, blk256, 0, stream>>>(cell, cell_h, cell_l, NCELL, NCELL, 1024, 1024);
    cvt_pad2_kernel<<<2048, blk256, 0, stream>>>(gene, gene_h, gene_l, NGENE, NGENE, 6016, GKP);
    transpose_cvt2_kernel<<<dim3(32, 8),  blk256, 0, stream>>>(Wdrug, Wd_h, Wd_l, NDRUG, H1, 1024);
    transpose_cvt2_kernel<<<dim3(32, 8),  blk256, 0, stream>>>(Wcell, Wc_h, Wc_l, NCELL, H1, 1024);
    transpose_cvt2_kernel<<<dim3(188, 8), blk256, 0, stream>>>(Wgene, Wg_h, Wg_l, NGENE, H1, GKP);
    transpose_cvt2_kernel<<<dim3(8, 16),  blk256, 0, stream>>>(W1, W1_h, W1_l, H1, HD, H1);
    transpose_cvt2_kernel<<<dim3(16, 16), blk256, 0, stream>>>(W2, W2_h, W2_l, HD, HD, HD);

    // ---- input projections -> x0 (hi/lo bf16) ----
    gemm_mfma2<1><<<dim3(H1 / 64, 16), blk256, 0, stream>>>(drug_h, drug_l, Wd_h, Wd_l, bdrug,
        nullptr, x0_h, x0_l, NDRUG, 1024, H1);
    gemm_mfma2<1><<<dim3(H1 / 64, 16), blk256, 0, stream>>>(cell_h, cell_l, Wc_h, Wc_l, bcell,
        nullptr, x0_h + (long)NDRUG * H1, x0_l + (long)NDRUG * H1, NCELL, 1024, H1);
    gemm_gene_splitk<<<dim3(2, 47, ZSPLIT), blk256, 0, stream>>>(gene_h, gene_l, Wg_h, Wg_l, partsk);
    reduce_splitk_kernel<<<1500, blk256, 0, stream>>>(partsk, bgene, x0_h, x0_l);

    // ---- layer 1 ----
    gemm_mfma2<0><<<dim3(HD / 64, NNODE / 64), blk256, 0, stream>>>(x0_h, x0_l, W1_h, W1_l, b1,
        xw, nullptr, nullptr, NNODE, H1, HD);
    attn_coef_kernel<<<NNODE / 4, blk256, 0, stream>>>(xw, as1, ad1, a_src, a_dst);
    alpha_max_kernel<<<gE, blk256, 0, stream>>>(ei, eattr, scal, a_src, a_dst, ce,
        alpha, nullptr, nullptr, mbuf, deg, 1);
    scan_kernel<<<1, 1024, 0, stream>>>(deg, rs, cursor);
    scatter_csr_kernel<<<gE, blk256, 0, stream>>>(ei, cursor, alpha, csr_src, pos_of_e, csr_al);
    aggregate_kernel<<<NNODE, blk256, 0, stream>>>(xw, csr_al, mbuf, rs, csr_src, bias1, outb);
    colstats_kernel<<<64, blk256, 0, stream>>>(outb, colsum, colsq);
    norm_kernel<<<2048, blk256, 0, stream>>>(outb, xb_h, xb_l, colsum, colsq, g1, be1, ms1);

    // ---- layer 2 ----
    gemm_mfma2<0><<<dim3(HD / 64, NNODE / 64), blk256, 0, stream>>>(xb_h, xb_l, W2_h, W2_l, b2,
        xw, nullptr, nullptr, NNODE, HD, HD);
    attn_coef_kernel<<<NNODE / 4, blk256, 0, stream>>>(xw, as2, ad2, a_src, a_dst);
    init2_kernel<<<125, blk256, 0, stream>>>(mbuf, colsum);  // colsum zeroed here
    init2_kernel<<<125, blk256, 0, stream>>>(mbuf, colsq);   // (mbuf re-init harmless) colsq zeroed
    alpha_max_kernel<<<gE, blk256, 0, stream>>>(ei, eattr, scal, a_src, a_dst, ce + 4,
        nullptr, csr_al, pos_of_e, mbuf, deg, 0);
    aggregate_kernel<<<NNODE, blk256, 0, stream>>>(xw, csr_al, mbuf, rs, csr_src, bias2, outb);
    colstats_kernel<<<64, blk256, 0, stream>>>(outb, colsum, colsq);
    norm_kernel<<<2048, blk256, 0, stream>>>(outb, xb_h, xb_l, colsum, colsq, g2, be2, ms2);

    // ---- head + attention matrix ----
    head_kernel<<<(BSZ + 3) / 4, blk256, 0, stream>>>(outb, idd, idc, Wout, bout, out0);
    zero_f4_kernel<<<2048, blk256, 0, stream>>>((float4*)attm, (long)NNODE * NNODE / 4);
    scatter_att_kernel<<<gE, blk256, 0, stream>>>(ei, attm);
}

// Round 10
// 692.306 us; speedup vs baseline: 1.0750x; 1.0056x over previous
//
#include <hip/hip_runtime.h>
#include <math.h>

// ---------------- problem constants ----------------
#define NDRUG 1000
#define NCELL 1000
#define NGENE 6000
#define NNODE 8000
#define H1 256
#define HD  512   // HEADS*H2 = HEADS*H3
#define E0  160000
#define ET  168000   // E0 + NNODE self loops
#define BSZ 10000
#define GKP 6016    // padded gene K
#define ZSPLIT 8    // gene split-K factor

typedef __attribute__((ext_vector_type(8))) short bf16x8;
typedef __attribute__((ext_vector_type(4))) float f32x4;

__device__ inline unsigned short f2bf(float f)
{
    unsigned u = __float_as_uint(f);
    u += 0x7fffu + ((u >> 16) & 1u);   // RNE
    return (unsigned short)(u >> 16);
}
__device__ inline float bf2f(unsigned short h)
{
    return __uint_as_float(((unsigned)h) << 16);
}

// async global->LDS, 16B per lane; LDS dest = base + lane*16 (wave-uniform base)
__device__ inline void gld16(const unsigned short* g, char* l)
{
    __builtin_amdgcn_global_load_lds(
        (const __attribute__((address_space(1))) unsigned int*)g,
        (__attribute__((address_space(3))) unsigned int*)l,
        16, 0, 0);
}

// ---------------- f32 -> (hi,lo) bf16 with [Mp][Kp] zero padding ----------------
__global__ void cvt_pad2_kernel(const float* __restrict__ in,
                                unsigned short* __restrict__ hi,
                                unsigned short* __restrict__ lo,
                                int M, int K, int Mp, int Kp)
{
    long total = (long)Mp * Kp / 8;
    int kp8 = Kp / 8;
    long stride = (long)gridDim.x * blockDim.x;
    for (long u = (long)blockIdx.x * blockDim.x + threadIdx.x; u < total; u += stride) {
        long row = u / kp8; int kc = (int)(u % kp8);
        unsigned short oh[8], ol[8];
        if (row < M && kc * 8 < K) {   // K%8==0
            const float* p = in + row * (long)K + kc * 8;
            float4 a = *(const float4*)p, b = *(const float4*)(p + 4);
            float v[8] = {a.x, a.y, a.z, a.w, b.x, b.y, b.z, b.w};
            #pragma unroll
            for (int i = 0; i < 8; ++i) {
                unsigned short h = f2bf(v[i]);
                oh[i] = h;
                ol[i] = f2bf(v[i] - bf2f(h));
            }
        } else {
            #pragma unroll
            for (int i = 0; i < 8; ++i) { oh[i] = 0; ol[i] = 0; }
        }
        *(uint4*)(hi + u * 8) = *(const uint4*)oh;
        *(uint4*)(lo + u * 8) = *(const uint4*)ol;
    }
}

// ---------------- W[K][N] f32 -> Wt_{hi,lo}[N][Kp] bf16 ----------------
__global__ __launch_bounds__(256) void transpose_cvt2_kernel(const float* __restrict__ W,
                                                             unsigned short* __restrict__ Wh,
                                                             unsigned short* __restrict__ Wl,
                                                             int K, int N, int Kp)
{
    __shared__ float t[32][33];
    int kb = blockIdx.x * 32, nb = blockIdx.y * 32;
    int tx = threadIdx.x & 31, ty = threadIdx.x >> 5;  // ty 0..7
    #pragma unroll
    for (int i = 0; i < 32; i += 8) {
        int k = kb + ty + i;
        t[ty + i][tx] = (k < K) ? W[(long)k * N + nb + tx] : 0.f;
    }
    __syncthreads();
    #pragma unroll
    for (int i = 0; i < 32; i += 8) {
        int n = nb + ty + i;
        float v = t[tx][ty + i];
        unsigned short h = f2bf(v);
        Wh[(long)n * Kp + kb + tx] = h;
        Wl[(long)n * Kp + kb + tx] = f2bf(v - bf2f(h));
    }
}

// ---------------- split-bf16 MFMA GEMM, 64x64 tile ----------------
template<int OUTBF>
__global__ __launch_bounds__(256) void gemm_mfma2(const unsigned short* __restrict__ Ah,
                                                  const unsigned short* __restrict__ Al,
                                                  const unsigned short* __restrict__ Bh,
                                                  const unsigned short* __restrict__ Bl,
                                                  const float* __restrict__ bias,
                                                  float* __restrict__ Cf,
                                                  unsigned short* __restrict__ Cbh,
                                                  unsigned short* __restrict__ Cbl,
                                                  int M, int Kp, int N)
{
    __shared__ unsigned short AsH[64 * 64];
    __shared__ unsigned short AsL[64 * 64];
    __shared__ unsigned short BsH[64 * 64];
    __shared__ unsigned short BsL[64 * 64];
    char* AsH8 = (char*)AsH; char* AsL8 = (char*)AsL;
    char* BsH8 = (char*)BsH; char* BsL8 = (char*)BsL;
    int tid = threadIdx.x;
    int w = tid >> 6, l = tid & 63;
    int wr = w >> 1, wc = w & 1;
    int g = l >> 4, r16 = l & 15;
    int row0 = blockIdx.y * 64, col0 = blockIdx.x * 64;
    int srow = tid >> 3, skc = tid & 7;
    int B0 = srow * 128 + skc * 16;       int P0 = B0 ^ ((srow & 7) << 4);
    int r1 = srow + 32;                   int B1 = r1 * 128 + skc * 16;
    int P1 = B1 ^ ((r1 & 7) << 4);
    f32x4 acc[2][2] = {};
    for (int k0 = 0; k0 < Kp; k0 += 64) {
        long a0 = (long)(row0 + srow) * Kp + k0 + skc * 8;
        long a1 = (long)(row0 + srow + 32) * Kp + k0 + skc * 8;
        long b0 = (long)(col0 + srow) * Kp + k0 + skc * 8;
        long b1 = (long)(col0 + srow + 32) * Kp + k0 + skc * 8;
        uint4 ah0 = *(const uint4*)(Ah + a0); uint4 ah1 = *(const uint4*)(Ah + a1);
        uint4 al0 = *(const uint4*)(Al + a0); uint4 al1 = *(const uint4*)(Al + a1);
        uint4 bh0 = *(const uint4*)(Bh + b0); uint4 bh1 = *(const uint4*)(Bh + b1);
        uint4 bl0 = *(const uint4*)(Bl + b0); uint4 bl1 = *(const uint4*)(Bl + b1);
        __syncthreads();
        *(uint4*)(AsH8 + P0) = ah0; *(uint4*)(AsH8 + P1) = ah1;
        *(uint4*)(AsL8 + P0) = al0; *(uint4*)(AsL8 + P1) = al1;
        *(uint4*)(BsH8 + P0) = bh0; *(uint4*)(BsH8 + P1) = bh1;
        *(uint4*)(BsL8 + P0) = bl0; *(uint4*)(BsL8 + P1) = bl1;
        __syncthreads();
        #pragma unroll
        for (int kk = 0; kk < 2; ++kk) {
            bf16x8 afh[2], afl[2], bfh[2], bfl[2];
            #pragma unroll
            for (int m = 0; m < 2; ++m) {
                int row = wr * 32 + m * 16 + r16;
                int Bb = (row * 128 + kk * 64 + g * 16) ^ ((row & 7) << 4);
                afh[m] = *(const bf16x8*)(AsH8 + Bb);
                afl[m] = *(const bf16x8*)(AsL8 + Bb);
            }
            #pragma unroll
            for (int n = 0; n < 2; ++n) {
                int row = wc * 32 + n * 16 + r16;
                int Bb = (row * 128 + kk * 64 + g * 16) ^ ((row & 7) << 4);
                bfh[n] = *(const bf16x8*)(BsH8 + Bb);
                bfl[n] = *(const bf16x8*)(BsL8 + Bb);
            }
            #pragma unroll
            for (int m = 0; m < 2; ++m)
                #pragma unroll
                for (int n = 0; n < 2; ++n) {
                    acc[m][n] = __builtin_amdgcn_mfma_f32_16x16x32_bf16(afh[m], bfh[n], acc[m][n], 0, 0, 0);
                    acc[m][n] = __builtin_amdgcn_mfma_f32_16x16x32_bf16(afh[m], bfl[n], acc[m][n], 0, 0, 0);
                    acc[m][n] = __builtin_amdgcn_mfma_f32_16x16x32_bf16(afl[m], bfh[n], acc[m][n], 0, 0, 0);
                }
        }
    }
    #pragma unroll
    for (int m = 0; m < 2; ++m) {
        #pragma unroll
        for (int n = 0; n < 2; ++n) {
            #pragma unroll
            for (int r = 0; r < 4; ++r) {
                int rowg = row0 + wr * 32 + m * 16 + g * 4 + r;
                int colg = col0 + wc * 32 + n * 16 + r16;
                if (rowg < M) {
                    float v = acc[m][n][r] + bias[colg];
                    if (OUTBF) {
                        unsigned short h = f2bf(v);
                        Cbh[(long)rowg * N + colg] = h;
                        Cbl[(long)rowg * N + colg] = f2bf(v - bf2f(h));
                    } else {
                        Cf[(long)rowg * N + colg] = v;
                    }
                }
            }
        }
    }
}

// ---------------- gene GEMM: 128x128 tile, BK=32, global_load_lds, split-K, XCD-pair relabel ----
// 2-way-free LDS swizzle: t(r)=(r+(r>>2))&3; slot at LDS(row,slot) holds k-chunk slot^t(row).
// Write side: linear LDS dest (gld16) + pre-swizzled GLOBAL k-offset. Read side: slot = g ^ t(row).
__global__ __launch_bounds__(256) void gemm_gene_splitk(const unsigned short* __restrict__ Ah,
                                                        const unsigned short* __restrict__ Al,
                                                        const unsigned short* __restrict__ Bh,
                                                        const unsigned short* __restrict__ Bl,
                                                        float* __restrict__ part)
{
    __shared__ char lds[32768];
    char* AsH = lds;          char* AsL = lds + 8192;
    char* BsH = lds + 16384;  char* BsL = lds + 24576;
    int tid = threadIdx.x;
    int w = tid >> 6, l = tid & 63;
    int wr = w >> 1, wc = w & 1;
    int g = l >> 4, r16 = l & 15;
    // physical pid -> logical L: pairs (x=0/1) and a full z-chunk stay on one XCD (752 = 8*94)
    int pid = blockIdx.x;
    int L = (pid & 7) * 94 + (pid >> 3);
    int xb = L & 1;
    int yb = (L >> 1) % 47;
    int z  = L / 94;
    int row0 = yb * 128, col0 = xb * 128;
    int kbeg = z * 768;
    int kend = kbeg + 768; if (kend > GKP) kend = GKP;
    // staging: wave w stages matrix w; lane = (row-in-16, slot)
    int rr = l >> 2, s = l & 3;
    int t_rr = (rr + (rr >> 2)) & 3;
    int src_ko = (s ^ t_rr) << 3;            // pre-swizzled k-element offset (8 bf16 per slot)
    const unsigned short* gbase = (w == 0) ? Ah : (w == 1) ? Al : (w == 2) ? Bh : Bl;
    char* ldst = (w == 0) ? AsH : (w == 1) ? AsL : (w == 2) ? BsH : BsL;
    int rc0 = (w >= 2) ? col0 : row0;
    // read-side swizzle (per-lane constant)
    int tA = (r16 + (r16 >> 2)) & 3;
    int soA = (g ^ tA) << 4;                 // byte slot offset
    f32x4 acc[4][4] = {};
    for (int k0 = kbeg; k0 < kend; k0 += 32) {
        __syncthreads();   // previous iter's ds_reads done
        #pragma unroll
        for (int i = 0; i < 8; ++i) {
            int rt = i * 16;
            gld16(gbase + (long)(rc0 + rt + rr) * GKP + k0 + src_ko, ldst + rt * 64);
        }
        __syncthreads();   // staging visible (compiler drains vmcnt before barrier)
        bf16x8 afh[4], afl[4], bfh[4], bfl[4];
        #pragma unroll
        for (int m = 0; m < 4; ++m) {
            int Bb = (wr * 64 + m * 16 + r16) * 64 + soA;
            afh[m] = *(const bf16x8*)(AsH + Bb);
            afl[m] = *(const bf16x8*)(AsL + Bb);
        }
        #pragma unroll
        for (int n = 0; n < 4; ++n) {
            int Bb = (wc * 64 + n * 16 + r16) * 64 + soA;
            bfh[n] = *(const bf16x8*)(BsH + Bb);
            bfl[n] = *(const bf16x8*)(BsL + Bb);
        }
        #pragma unroll
        for (int m = 0; m < 4; ++m)
            #pragma unroll
            for (int n = 0; n < 4; ++n) {
                acc[m][n] = __builtin_amdgcn_mfma_f32_16x16x32_bf16(afh[m], bfh[n], acc[m][n], 0, 0, 0);
                acc[m][n] = __builtin_amdgcn_mfma_f32_16x16x32_bf16(afh[m], bfl[n], acc[m][n], 0, 0, 0);
                acc[m][n] = __builtin_amdgcn_mfma_f32_16x16x32_bf16(afl[m], bfh[n], acc[m][n], 0, 0, 0);
            }
    }
    #pragma unroll
    for (int m = 0; m < 4; ++m) {
        #pragma unroll
        for (int n = 0; n < 4; ++n) {
            #pragma unroll
            for (int r = 0; r < 4; ++r) {
                int rowg = row0 + wr * 64 + m * 16 + g * 4 + r;
                int colg = col0 + wc * 64 + n * 16 + r16;
                if (rowg < NGENE)
                    part[((long)z * NGENE + rowg) * H1 + colg] = acc[m][n][r];
            }
        }
    }
}

// ---------------- split-K reduce ----------------
__global__ __launch_bounds__(256) void reduce_splitk_kernel(const float* __restrict__ part,
                                                            const float* __restrict__ bias,
                                                            unsigned short* __restrict__ xh,
                                                            unsigned short* __restrict__ xl)
{
    const long NEL = (long)NGENE * H1;
    long stride = (long)gridDim.x * blockDim.x;
    for (long q = (long)blockIdx.x * blockDim.x + threadIdx.x; q * 4 < NEL; q += stride) {
        long e = q * 4;
        float4 sv = *(const float4*)(part + e);
        #pragma unroll
        for (int z = 1; z < ZSPLIT; ++z) {
            float4 t = *(const float4*)(part + (long)z * NEL + e);
            sv.x += t.x; sv.y += t.y; sv.z += t.z; sv.w += t.w;
        }
        int col = (int)(e & (H1 - 1));
        float4 b = *(const float4*)(bias + col);
        float v[4] = {sv.x + b.x, sv.y + b.y, sv.z + b.z, sv.w + b.w};
        unsigned short oh[4], ol[4];
        #pragma unroll
        for (int i = 0; i < 4; ++i) {
            oh[i] = f2bf(v[i]);
            ol[i] = f2bf(v[i] - bf2f(oh[i]));
        }
        long o = (long)(NDRUG + NCELL) * H1 + e;
        *(uint2*)(xh + o) = *(const uint2*)oh;
        *(uint2*)(xl + o) = *(const uint2*)ol;
    }
}

// ---------------- init kernels ----------------
__global__ void init1_kernel(float* m, int* deg, float* colstats, float* scal)
{
    int i = blockIdx.x * 256 + threadIdx.x;
    if (i < NNODE * 4) m[i] = -3.402823466e38f;
    if (i < NNODE) deg[i] = 0;
    if (i < 1024) colstats[i] = 0.f;
    if (i < 8) scal[i] = 0.f;
}

// zeroes mbuf (-inf) and colsum+colsq (1024 contiguous floats) — nothing else
__global__ void init2_kernel(float* m, float* colstats)
{
    int i = blockIdx.x * 256 + threadIdx.x;
    if (i < NNODE * 4) m[i] = -3.402823466e38f;
    if (i < 1024) colstats[i] = 0.f;
}

// ---------------- sum(edge_attr) -> scal[0] ----------------
__global__ void reduce_sum_kernel(const float* __restrict__ x, int n, float* out)
{
    float s = 0.f;
    for (int i = blockIdx.x * blockDim.x + threadIdx.x; i < n; i += gridDim.x * blockDim.x)
        s += x[i];
    for (int off = 32; off; off >>= 1) s += __shfl_down(s, off);
    if ((threadIdx.x & 63) == 0) atomicAdd(out, s);
}

// ---------------- ce[h] ----------------
__global__ __launch_bounds__(512) void ce_kernel(const float* We1, const float* ae1,
                                                 const float* We2, const float* ae2, float* ce)
{
    __shared__ float sm[512];
    int t = threadIdx.x;
    sm[t] = We1[t] * ae1[t];
    __syncthreads();
    if (t < 4) { float s = 0.f; for (int c = 0; c < 128; ++c) s += sm[t * 128 + c]; ce[t] = s; }
    __syncthreads();
    sm[t] = We2[t] * ae2[t];
    __syncthreads();
    if (t < 4) { float s = 0.f; for (int c = 0; c < 128; ++c) s += sm[t * 128 + c]; ce[4 + t] = s; }
}

// ---------------- per-node attention coefficients (4 nodes per block) ----------------
__global__ __launch_bounds__(256) void attn_coef_kernel(const float* __restrict__ xw,
                                                        const float* __restrict__ as,
                                                        const float* __restrict__ ad,
                                                        float* __restrict__ a_src,
                                                        float* __restrict__ a_dst)
{
    int n = blockIdx.x * 4 + (threadIdx.x >> 6);
    int l = threadIdx.x & 63;
    #pragma unroll
    for (int h = 0; h < 4; ++h) {
        float x1 = xw[(long)n * HD + h * 128 + l];
        float x2 = xw[(long)n * HD + h * 128 + 64 + l];
        float s = x1 * as[h * 128 + l] + x2 * as[h * 128 + 64 + l];
        float d = x1 * ad[h * 128 + l] + x2 * ad[h * 128 + 64 + l];
        for (int off = 32; off; off >>= 1) { s += __shfl_down(s, off); d += __shfl_down(d, off); }
        if (l == 0) { a_src[n * 4 + h] = s; a_dst[n * 4 + h] = d; }
    }
}

// ---------------- atomic float max ----------------
__device__ inline void atomicMaxF(float* addr, float v)
{
    if (v >= 0.f) atomicMax((int*)addr, __float_as_int(v));
    else          atomicMin((unsigned int*)addr, __float_as_uint(v));
}

// ---------------- per-edge alpha + segment max ----------------
__global__ void alpha_max_kernel(const int* __restrict__ ei, const float* __restrict__ eattr,
                                 const float* __restrict__ scal,
                                 const float* __restrict__ a_src, const float* __restrict__ a_dst,
                                 const float* __restrict__ ce,
                                 float* __restrict__ alpha,          // MODE1 dest
                                 float* __restrict__ csr_alpha,      // MODE0 dest
                                 const int* __restrict__ pos_of_e,   // MODE0 map
                                 float* __restrict__ m,
                                 int* __restrict__ deg, int mode1)
{
    int e = blockIdx.x * blockDim.x + threadIdx.x;
    if (e >= ET) return;
    int s, d; float a;
    if (e < E0) { s = ei[e]; d = ei[E0 + e]; a = eattr[e]; }
    else        { s = d = e - E0; a = scal[0] * (1.0f / E0); }
    float4 av;
    float* avp = (float*)&av;
    #pragma unroll
    for (int h = 0; h < 4; ++h) {
        float v = a_src[s * 4 + h] + a_dst[d * 4 + h] + a * ce[h];
        v = v > 0.f ? v : 0.2f * v;
        avp[h] = v;
        atomicMaxF(&m[d * 4 + h], v);
    }
    if (mode1) {
        *(float4*)(alpha + (long)e * 4) = av;
        atomicAdd(&deg[d], 1);
    } else {
        *(float4*)(csr_alpha + (long)pos_of_e[e] * 4) = av;
    }
}

// ---------------- exclusive scan ----------------
__global__ __launch_bounds__(1024) void scan_kernel(const int* __restrict__ deg,
                                                    int* __restrict__ row_start,
                                                    int* __restrict__ cursor)
{
    __shared__ int sm[1024];
    int t = threadIdx.x;
    int base = t * 8;
    int loc[8];
    int sum = 0;
    #pragma unroll
    for (int j = 0; j < 8; ++j) {
        int v = (base + j < NNODE) ? deg[base + j] : 0;
        loc[j] = sum; sum += v;
    }
    sm[t] = sum;
    __syncthreads();
    for (int off = 1; off < 1024; off <<= 1) {
        int v = (t >= off) ? sm[t - off] : 0;
        __syncthreads();
        sm[t] += v;
        __syncthreads();
    }
    int excl = sm[t] - sum;
    #pragma unroll
    for (int j = 0; j < 8; ++j) {
        int idx = base + j;
        if (idx < NNODE) { int v = excl + loc[j]; row_start[idx] = v; cursor[idx] = v; }
    }
    if (t == 1023) row_start[NNODE] = sm[1023];
}

// ---------------- scatter edges into CSR (by dst) + csr_alpha + pos_of_e ----------------
__global__ void scatter_csr_kernel(const int* __restrict__ ei, int* __restrict__ cursor,
                                   const float* __restrict__ alpha,
                                   int* __restrict__ csr_src, int* __restrict__ pos_of_e,
                                   float* __restrict__ csr_alpha)
{
    int e = blockIdx.x * blockDim.x + threadIdx.x;
    if (e >= ET) return;
    int s, d;
    if (e < E0) { s = ei[e]; d = ei[E0 + e]; }
    else        { s = d = e - E0; }
    int pos = atomicAdd(&cursor[d], 1);
    csr_src[pos] = s;
    pos_of_e[e] = pos;
    *(float4*)(csr_alpha + (long)pos * 4) = *(const float4*)(alpha + (long)e * 4);
}

// ---------------- aggregation: one block (4 waves = 4 heads) per node, ILP=8 ----------------
__global__ __launch_bounds__(256) void aggregate_kernel(const float* __restrict__ xw,
                                                        const float* __restrict__ csr_alpha,
                                                        const float* __restrict__ m,
                                                        const int* __restrict__ rs,
                                                        const int* __restrict__ csr_src,
                                                        const float* __restrict__ bias,
                                                        float* __restrict__ out)
{
    int n = blockIdx.x;
    int h = threadIdx.x >> 6;
    int l = threadIdx.x & 63;
    float mnh = m[n * 4 + h];
    int i0 = rs[n], i1 = rs[n + 1];
    float den = 0.f;
    for (int i = i0 + l; i < i1; i += 64)
        den += expf(csr_alpha[(long)i * 4 + h] - mnh);
    for (int off = 32; off; off >>= 1) den += __shfl_down(den, off);
    den = __shfl(den, 0);
    float rden = 1.0f / (den + 1e-16f);
    float acc0 = 0.f, acc1 = 0.f;
    int i = i0;
    for (; i + 7 < i1; i += 8) {
        int   sv[8];
        float av[8], xv0[8], xv1[8];
        #pragma unroll
        for (int j = 0; j < 8; ++j) {
            sv[j] = csr_src[i + j];
            av[j] = csr_alpha[(long)(i + j) * 4 + h];
        }
        #pragma unroll
        for (int j = 0; j < 8; ++j) {
            const float* r = xw + (long)sv[j] * HD + h * 128;
            xv0[j] = r[l]; xv1[j] = r[64 + l];
        }
        #pragma unroll
        for (int j = 0; j < 8; ++j) {
            float w = expf(av[j] - mnh);
            acc0 += w * xv0[j];
            acc1 += w * xv1[j];
        }
    }
    for (; i < i1; ++i) {
        int s = csr_src[i];
        float w = expf(csr_alpha[(long)i * 4 + h] - mnh);
        const float* xr = xw + (long)s * HD + h * 128;
        acc0 += w * xr[l];
        acc1 += w * xr[64 + l];
    }
    out[(long)n * HD + h * 128 + l]      = acc0 * rden + bias[h * 128 + l];
    out[(long)n * HD + h * 128 + 64 + l] = acc1 * rden + bias[h * 128 + 64 + l];
}

// ---------------- graph norm: fused column sum + sum-of-squares ----------------
__global__ __launch_bounds__(256) void colstats_kernel(const float* __restrict__ x,
                                                       float* __restrict__ colsum,
                                                       float* __restrict__ colsumsq)
{
    int t = threadIdx.x, b = blockIdx.x;
    float s0 = 0.f, s1 = 0.f, q0 = 0.f, q1 = 0.f;
    for (int r = b * 125; r < (b + 1) * 125; ++r) {
        float v0 = x[(long)r * HD + t];
        float v1 = x[(long)r * HD + t + 256];
        s0 += v0; q0 += v0 * v0;
        s1 += v1; q1 += v1 * v1;
    }
    atomicAdd(&colsum[t], s0);
    atomicAdd(&colsum[t + 256], s1);
    atomicAdd(&colsumsq[t], q0);
    atomicAdd(&colsumsq[t + 256], q1);
}

// norm (+ReLU) in place; var = E[x^2] - ms*(2-ms)*mu^2 ; writes hi/lo bf16 copies
__global__ void norm_kernel(float* __restrict__ x,
                            unsigned short* __restrict__ xbh, unsigned short* __restrict__ xbl,
                            const float* __restrict__ colsum,
                            const float* __restrict__ colsumsq,
                            const float* __restrict__ g, const float* __restrict__ be,
                            const float* __restrict__ ms)
{
    int stride = gridDim.x * blockDim.x;
    for (int idx = blockIdx.x * blockDim.x + threadIdx.x; idx < NNODE * HD; idx += stride) {
        int j = idx & 511;
        float mu  = colsum[j] * (1.0f / NNODE);
        float ex2 = colsumsq[j] * (1.0f / NNODE);
        float msj = ms[j];
        float var = ex2 - msj * (2.0f - msj) * mu * mu;
        float v = x[idx] - msj * mu;
        float y = g[j] * v / sqrtf(var + 1e-5f) + be[j];
        y = y > 0.f ? y : 0.f;
        x[idx] = y;
        unsigned short h = f2bf(y);
        xbh[idx] = h;
        xbl[idx] = f2bf(y - bf2f(h));
    }
}

// ---------------- prediction head ----------------
__global__ __launch_bounds__(256) void head_kernel(const float* __restrict__ x2,
                                                   const int* __restrict__ idd,
                                                   const int* __restrict__ idc,
                                                   const float* __restrict__ Wout,
                                                   const float* __restrict__ bout,
                                                   float* __restrict__ out0)
{
    int w = threadIdx.x >> 6, l = threadIdx.x & 63;
    int b = blockIdx.x * 4 + w;
    if (b >= BSZ) return;
    int rd = idd[b], rc = idc[b];
    float s = 0.f;
    #pragma unroll
    for (int k = l; k < HD; k += 64)
        s += x2[(long)rd * HD + k] * Wout[k] + x2[(long)rc * HD + k] * Wout[HD + k];
    for (int off = 32; off; off >>= 1) s += __shfl_down(s, off);
    if (l == 0) out0[b] = s + bout[0];
}

// ---------------- all_att: zero + scatter scalar ----------------
__global__ void zero_f4_kernel(float4* __restrict__ p, long n4)
{
    long stride = (long)gridDim.x * blockDim.x;
    for (long i = (long)blockIdx.x * blockDim.x + threadIdx.x; i < n4; i += stride)
        p[i] = make_float4(0.f, 0.f, 0.f, 0.f);
}

__global__ void scatter_att_kernel(const int* __restrict__ ei, float* __restrict__ attm)
{
    int e = blockIdx.x * blockDim.x + threadIdx.x;
    if (e >= ET) return;
    int s, d;
    if (e < E0) { s = ei[e]; d = ei[E0 + e]; }
    else        { s = d = e - E0; }
    const float val = 2.0f * (float)NNODE / (float)ET;
    attm[(long)s * NNODE + d] = val;
}

// ---------------- launch ----------------
extern "C" void kernel_launch(void* const* d_in, const int* in_sizes, int n_in,
                              void* d_out, int out_size, void* d_ws, size_t ws_size,
                              hipStream_t stream)
{
    const float* drug   = (const float*)d_in[0];
    const float* cell   = (const float*)d_in[1];
    const float* gene   = (const float*)d_in[2];
    const float* eattr  = (const float*)d_in[3];
    const int*   ei     = (const int*)d_in[4];
    const int*   idd    = (const int*)d_in[5];
    const int*   idc    = (const int*)d_in[6];
    const float* Wdrug  = (const float*)d_in[7];
    const float* bdrug  = (const float*)d_in[8];
    const float* Wcell  = (const float*)d_in[9];
    const float* bcell  = (const float*)d_in[10];
    const float* Wgene  = (const float*)d_in[11];
    const float* bgene  = (const float*)d_in[12];
    const float* W1     = (const float*)d_in[13];
    const float* b1     = (const float*)d_in[14];
    const float* as1    = (const float*)d_in[15];
    const float* ad1    = (const float*)d_in[16];
    const float* We1    = (const float*)d_in[17];
    const float* ae1    = (const float*)d_in[18];
    const float* bias1  = (const float*)d_in[19];
    const float* g1     = (const float*)d_in[20];
    const float* be1    = (const float*)d_in[21];
    const float* ms1    = (const float*)d_in[22];
    const float* W2     = (const float*)d_in[23];
    const float* b2     = (const float*)d_in[24];
    const float* as2    = (const float*)d_in[25];
    const float* ad2    = (const float*)d_in[26];
    const float* We2    = (const float*)d_in[27];
    const float* ae2    = (const float*)d_in[28];
    const float* bias2  = (const float*)d_in[29];
    const float* g2     = (const float*)d_in[30];
    const float* be2    = (const float*)d_in[31];
    const float* ms2    = (const float*)d_in[32];
    const float* Wout   = (const float*)d_in[33];
    const float* bout   = (const float*)d_in[34];

    float* out0 = (float*)d_out;                 // [10000]
    float* attm = (float*)d_out + BSZ;           // [8000*8000]

    // ---- workspace layout ----
    float* ws     = (float*)d_ws;
    float* xw     = ws;                          // 8000*512
    float* outb   = xw + (long)NNODE * HD;       // 8000*512
    float* alpha  = outb + (long)NNODE * HD;     // 168000*4
    float* csr_al = alpha + (long)ET * 4;        // 168000*4
    float* a_src  = csr_al + (long)ET * 4;       // 32000
    float* a_dst  = a_src + NNODE * 4;           // 32000
    float* mbuf   = a_dst + NNODE * 4;           // 32000
    float* colsum = mbuf + NNODE * 4;            // 512
    float* colsq  = colsum + 512;                // 512 (contiguous with colsum)
    float* ce     = colsq + 512;                 // 8
    float* scal   = ce + 8;                      // 8
    int* deg      = (int*)(scal + 8);            // 8000
    int* rs       = deg + NNODE;                 // 8004 (padded)
    int* cursor   = rs + NNODE + 4;              // 8000
    int* csr_src  = cursor + NNODE;              // 168000
    int* pos_of_e = csr_src + ET;                // 168000
    unsigned short* p = (unsigned short*)(pos_of_e + ET);
    unsigned short* gene_h = p; p += (long)6016 * GKP;
    unsigned short* gene_l = p; p += (long)6016 * GKP;
    unsigned short* drug_h = p; p += (long)1024 * 1024;
    unsigned short* drug_l = p; p += (long)1024 * 1024;
    unsigned short* cell_h = p; p += (long)1024 * 1024;
    unsigned short* cell_l = p; p += (long)1024 * 1024;
    unsigned short* x0_h   = p; p += (long)NNODE * H1;
    unsigned short* x0_l   = p; p += (long)NNODE * H1;
    unsigned short* xb_h   = p; p += (long)NNODE * HD;
    unsigned short* xb_l   = p; p += (long)NNODE * HD;
    unsigned short* Wd_h   = p; p += 256 * 1024;
    unsigned short* Wd_l   = p; p += 256 * 1024;
    unsigned short* Wc_h   = p; p += 256 * 1024;
    unsigned short* Wc_l   = p; p += 256 * 1024;
    unsigned short* Wg_h   = p; p += 256 * GKP;
    unsigned short* Wg_l   = p; p += 256 * GKP;
    unsigned short* W1_h   = p; p += 512 * 256;
    unsigned short* W1_l   = p; p += 512 * 256;
    unsigned short* W2_h   = p; p += 512 * 512;
    unsigned short* W2_l   = p; p += 512 * 512;
    float* partsk = (float*)((((unsigned long long)p) + 15) & ~15ULL);  // ZSPLIT*NGENE*H1 f32

    dim3 blk256(256);
    int gE = (ET + 255) / 256;

    // init + small precomputes
    init1_kernel<<<125, blk256, 0, stream>>>(mbuf, deg, colsum, scal);
    reduce_sum_kernel<<<64, blk256, 0, stream>>>(eattr, E0, &scal[0]);
    ce_kernel<<<1, 512, 0, stream>>>(We1, ae1, We2, ae2, ce);

    // ---- hi/lo split conversions ----
    cvt_pad2_kernel<<<512, blk256, 0, stream>>>(drug, drug_h, drug_l, NDRUG, NDRUG, 1024, 1024);
    cvt_pad2_kernel<<<512, blk256, 0, stream>>>(cell, cell_h, cell_l, NCELL, NCELL, 1024, 1024);
    cvt_pad2_kernel<<<2048, blk256, 0, stream>>>(gene, gene_h, gene_l, NGENE, NGENE, 6016, GKP);
    transpose_cvt2_kernel<<<dim3(32, 8),  blk256, 0, stream>>>(Wdrug, Wd_h, Wd_l, NDRUG, H1, 1024);
    transpose_cvt2_kernel<<<dim3(32, 8),  blk256, 0, stream>>>(Wcell, Wc_h, Wc_l, NCELL, H1, 1024);
    transpose_cvt2_kernel<<<dim3(188, 8), blk256, 0, stream>>>(Wgene, Wg_h, Wg_l, NGENE, H1, GKP);
    transpose_cvt2_kernel<<<dim3(8, 16),  blk256, 0, stream>>>(W1, W1_h, W1_l, H1, HD, H1);
    transpose_cvt2_kernel<<<dim3(16, 16), blk256, 0, stream>>>(W2, W2_h, W2_l, HD, HD, HD);

    // ---- input projections -> x0 (hi/lo bf16) ----
    gemm_mfma2<1><<<dim3(H1 / 64, 16), blk256, 0, stream>>>(drug_h, drug_l, Wd_h, Wd_l, bdrug,
        nullptr, x0_h, x0_l, NDRUG, 1024, H1);
    gemm_mfma2<1><<<dim3(H1 / 64, 16), blk256, 0, stream>>>(cell_h, cell_l, Wc_h, Wc_l, bcell,
        nullptr, x0_h + (long)NDRUG * H1, x0_l + (long)NDRUG * H1, NCELL, 1024, H1);
    gemm_gene_splitk<<<752, blk256, 0, stream>>>(gene_h, gene_l, Wg_h, Wg_l, partsk);
    reduce_splitk_kernel<<<1500, blk256, 0, stream>>>(partsk, bgene, x0_h, x0_l);

    // ---- layer 1 ----
    gemm_mfma2<0><<<dim3(HD / 64, NNODE / 64), blk256, 0, stream>>>(x0_h, x0_l, W1_h, W1_l, b1,
        xw, nullptr, nullptr, NNODE, H1, HD);
    attn_coef_kernel<<<NNODE / 4, blk256, 0, stream>>>(xw, as1, ad1, a_src, a_dst);
    alpha_max_kernel<<<gE, blk256, 0, stream>>>(ei, eattr, scal, a_src, a_dst, ce,
        alpha, nullptr, nullptr, mbuf, deg, 1);
    scan_kernel<<<1, 1024, 0, stream>>>(deg, rs, cursor);
    scatter_csr_kernel<<<gE, blk256, 0, stream>>>(ei, cursor, alpha, csr_src, pos_of_e, csr_al);
    aggregate_kernel<<<NNODE, blk256, 0, stream>>>(xw, csr_al, mbuf, rs, csr_src, bias1, outb);
    colstats_kernel<<<64, blk256, 0, stream>>>(outb, colsum, colsq);
    norm_kernel<<<2048, blk256, 0, stream>>>(outb, xb_h, xb_l, colsum, colsq, g1, be1, ms1);

    // ---- layer 2 ----
    gemm_mfma2<0><<<dim3(HD / 64, NNODE / 64), blk256, 0, stream>>>(xb_h, xb_l, W2_h, W2_l, b2,
        xw, nullptr, nullptr, NNODE, HD, HD);
    attn_coef_kernel<<<NNODE / 4, blk256, 0, stream>>>(xw, as2, ad2, a_src, a_dst);
    init2_kernel<<<125, blk256, 0, stream>>>(mbuf, colsum);  // zeroes mbuf + colsum+colsq (1024)
    alpha_max_kernel<<<gE, blk256, 0, stream>>>(ei, eattr, scal, a_src, a_dst, ce + 4,
        nullptr, csr_al, pos_of_e, mbuf, deg, 0);
    aggregate_kernel<<<NNODE, blk256, 0, stream>>>(xw, csr_al, mbuf, rs, csr_src, bias2, outb);
    colstats_kernel<<<64, blk256, 0, stream>>>(outb, colsum, colsq);
    norm_kernel<<<2048, blk256, 0, stream>>>(outb, xb_h, xb_l, colsum, colsq, g2, be2, ms2);

    // ---- head + attention matrix ----
    head_kernel<<<(BSZ + 3) / 4, blk256, 0, stream>>>(outb, idd, idc, Wout, bout, out0);
    zero_f4_kernel<<<2048, blk256, 0, stream>>>((float4*)attm, (long)NNODE * NNODE / 4);
    scatter_att_kernel<<<gE, blk256, 0, stream>>>(ei, attm);
}

// Round 11
// 600.304 us; speedup vs baseline: 1.2398x; 1.1533x over previous
//
#include <hip/hip_runtime.h>
#include <math.h>

// ---------------- problem constants ----------------
#define NDRUG 1000
#define NCELL 1000
#define NGENE 6000
#define NNODE 8000
#define H1 256
#define HD  512   // HEADS*H2 = HEADS*H3
#define E0  160000
#define ET  168000   // E0 + NNODE self loops
#define BSZ 10000
#define GKP 6016    // padded gene K (weights only)
#define ZSPLIT 8    // gene split-K factor
#define ZCH 768     // k-elements per z chunk

typedef __attribute__((ext_vector_type(8))) short bf16x8;
typedef __attribute__((ext_vector_type(4))) float f32x4;

__device__ inline unsigned short f2bf(float f)
{
    unsigned u = __float_as_uint(f);
    u += 0x7fffu + ((u >> 16) & 1u);   // RNE
    return (unsigned short)(u >> 16);
}
__device__ inline float bf2f(unsigned short h)
{
    return __uint_as_float(((unsigned)h) << 16);
}

// ---------------- f32 -> (hi,lo) bf16 with [Mp][Kp] zero padding (drug/cell only) ----------------
__global__ void cvt_pad2_kernel(const float* __restrict__ in,
                                unsigned short* __restrict__ hi,
                                unsigned short* __restrict__ lo,
                                int M, int K, int Mp, int Kp)
{
    long total = (long)Mp * Kp / 8;
    int kp8 = Kp / 8;
    long stride = (long)gridDim.x * blockDim.x;
    for (long u = (long)blockIdx.x * blockDim.x + threadIdx.x; u < total; u += stride) {
        long row = u / kp8; int kc = (int)(u % kp8);
        unsigned short oh[8], ol[8];
        if (row < M && kc * 8 < K) {   // K%8==0
            const float* p = in + row * (long)K + kc * 8;
            float4 a = *(const float4*)p, b = *(const float4*)(p + 4);
            float v[8] = {a.x, a.y, a.z, a.w, b.x, b.y, b.z, b.w};
            #pragma unroll
            for (int i = 0; i < 8; ++i) {
                unsigned short h = f2bf(v[i]);
                oh[i] = h;
                ol[i] = f2bf(v[i] - bf2f(h));
            }
        } else {
            #pragma unroll
            for (int i = 0; i < 8; ++i) { oh[i] = 0; ol[i] = 0; }
        }
        *(uint4*)(hi + u * 8) = *(const uint4*)oh;
        *(uint4*)(lo + u * 8) = *(const uint4*)ol;
    }
}

// ---------------- W[K][N] f32 -> Wt_{hi,lo}[N][Kp] bf16 ----------------
__global__ __launch_bounds__(256) void transpose_cvt2_kernel(const float* __restrict__ W,
                                                             unsigned short* __restrict__ Wh,
                                                             unsigned short* __restrict__ Wl,
                                                             int K, int N, int Kp)
{
    __shared__ float t[32][33];
    int kb = blockIdx.x * 32, nb = blockIdx.y * 32;
    int tx = threadIdx.x & 31, ty = threadIdx.x >> 5;  // ty 0..7
    #pragma unroll
    for (int i = 0; i < 32; i += 8) {
        int k = kb + ty + i;
        t[ty + i][tx] = (k < K) ? W[(long)k * N + nb + tx] : 0.f;
    }
    __syncthreads();
    #pragma unroll
    for (int i = 0; i < 32; i += 8) {
        int n = nb + ty + i;
        float v = t[tx][ty + i];
        unsigned short h = f2bf(v);
        Wh[(long)n * Kp + kb + tx] = h;
        Wl[(long)n * Kp + kb + tx] = f2bf(v - bf2f(h));
    }
}

// ---------------- split-bf16 MFMA GEMM, 64x64 tile ----------------
template<int OUTBF>
__global__ __launch_bounds__(256) void gemm_mfma2(const unsigned short* __restrict__ Ah,
                                                  const unsigned short* __restrict__ Al,
                                                  const unsigned short* __restrict__ Bh,
                                                  const unsigned short* __restrict__ Bl,
                                                  const float* __restrict__ bias,
                                                  float* __restrict__ Cf,
                                                  unsigned short* __restrict__ Cbh,
                                                  unsigned short* __restrict__ Cbl,
                                                  int M, int Kp, int N)
{
    __shared__ unsigned short AsH[64 * 64];
    __shared__ unsigned short AsL[64 * 64];
    __shared__ unsigned short BsH[64 * 64];
    __shared__ unsigned short BsL[64 * 64];
    char* AsH8 = (char*)AsH; char* AsL8 = (char*)AsL;
    char* BsH8 = (char*)BsH; char* BsL8 = (char*)BsL;
    int tid = threadIdx.x;
    int w = tid >> 6, l = tid & 63;
    int wr = w >> 1, wc = w & 1;
    int g = l >> 4, r16 = l & 15;
    int row0 = blockIdx.y * 64, col0 = blockIdx.x * 64;
    int srow = tid >> 3, skc = tid & 7;
    int B0 = srow * 128 + skc * 16;       int P0 = B0 ^ ((srow & 7) << 4);
    int r1 = srow + 32;                   int B1 = r1 * 128 + skc * 16;
    int P1 = B1 ^ ((r1 & 7) << 4);
    f32x4 acc[2][2] = {};
    for (int k0 = 0; k0 < Kp; k0 += 64) {
        long a0 = (long)(row0 + srow) * Kp + k0 + skc * 8;
        long a1 = (long)(row0 + srow + 32) * Kp + k0 + skc * 8;
        long b0 = (long)(col0 + srow) * Kp + k0 + skc * 8;
        long b1 = (long)(col0 + srow + 32) * Kp + k0 + skc * 8;
        uint4 ah0 = *(const uint4*)(Ah + a0); uint4 ah1 = *(const uint4*)(Ah + a1);
        uint4 al0 = *(const uint4*)(Al + a0); uint4 al1 = *(const uint4*)(Al + a1);
        uint4 bh0 = *(const uint4*)(Bh + b0); uint4 bh1 = *(const uint4*)(Bh + b1);
        uint4 bl0 = *(const uint4*)(Bl + b0); uint4 bl1 = *(const uint4*)(Bl + b1);
        __syncthreads();
        *(uint4*)(AsH8 + P0) = ah0; *(uint4*)(AsH8 + P1) = ah1;
        *(uint4*)(AsL8 + P0) = al0; *(uint4*)(AsL8 + P1) = al1;
        *(uint4*)(BsH8 + P0) = bh0; *(uint4*)(BsH8 + P1) = bh1;
        *(uint4*)(BsL8 + P0) = bl0; *(uint4*)(BsL8 + P1) = bl1;
        __syncthreads();
        #pragma unroll
        for (int kk = 0; kk < 2; ++kk) {
            bf16x8 afh[2], afl[2], bfh[2], bfl[2];
            #pragma unroll
            for (int m = 0; m < 2; ++m) {
                int row = wr * 32 + m * 16 + r16;
                int Bb = (row * 128 + kk * 64 + g * 16) ^ ((row & 7) << 4);
                afh[m] = *(const bf16x8*)(AsH8 + Bb);
                afl[m] = *(const bf16x8*)(AsL8 + Bb);
            }
            #pragma unroll
            for (int n = 0; n < 2; ++n) {
                int row = wc * 32 + n * 16 + r16;
                int Bb = (row * 128 + kk * 64 + g * 16) ^ ((row & 7) << 4);
                bfh[n] = *(const bf16x8*)(BsH8 + Bb);
                bfl[n] = *(const bf16x8*)(BsL8 + Bb);
            }
            #pragma unroll
            for (int m = 0; m < 2; ++m)
                #pragma unroll
                for (int n = 0; n < 2; ++n) {
                    acc[m][n] = __builtin_amdgcn_mfma_f32_16x16x32_bf16(afh[m], bfh[n], acc[m][n], 0, 0, 0);
                    acc[m][n] = __builtin_amdgcn_mfma_f32_16x16x32_bf16(afh[m], bfl[n], acc[m][n], 0, 0, 0);
                    acc[m][n] = __builtin_amdgcn_mfma_f32_16x16x32_bf16(afl[m], bfh[n], acc[m][n], 0, 0, 0);
                }
        }
    }
    #pragma unroll
    for (int m = 0; m < 2; ++m) {
        #pragma unroll
        for (int n = 0; n < 2; ++n) {
            #pragma unroll
            for (int r = 0; r < 4; ++r) {
                int rowg = row0 + wr * 32 + m * 16 + g * 4 + r;
                int colg = col0 + wc * 32 + n * 16 + r16;
                if (rowg < M) {
                    float v = acc[m][n][r] + bias[colg];
                    if (OUTBF) {
                        unsigned short h = f2bf(v);
                        Cbh[(long)rowg * N + colg] = h;
                        Cbl[(long)rowg * N + colg] = f2bf(v - bf2f(h));
                    } else {
                        Cf[(long)rowg * N + colg] = v;
                    }
                }
            }
        }
    }
}

// ---------------- gene GEMM: f32 A staged in-kernel to hi/lo LDS; 128x128, BK=32, split-K ------
// A = raw gene f32 [6000][6000]; B = Wg hi/lo bf16 [256][GKP]. Swizzle t(r)=(r+(r>>2))&3 applied
// on BOTH ds_write slot and read slot (same involution).
__global__ __launch_bounds__(256) void gemm_gene_f32(const float* __restrict__ A,
                                                     const unsigned short* __restrict__ Bh,
                                                     const unsigned short* __restrict__ Bl,
                                                     float* __restrict__ part)
{
    __shared__ char lds[32768];
    char* AsH = lds;          char* AsL = lds + 8192;
    char* BsH = lds + 16384;  char* BsL = lds + 24576;
    int tid = threadIdx.x;
    int w = tid >> 6, l = tid & 63;
    int wr = w >> 1, wc = w & 1;
    int g = l >> 4, r16 = l & 15;
    // XCD-pair relabel (752 = 8*94): pairs (xb) and a z-chunk stay on one XCD
    int pid = blockIdx.x;
    int L = (pid & 7) * 94 + (pid >> 3);
    int xb = L & 1;
    int yb = (L >> 1) % 47;
    int z  = L / 94;
    int row0 = yb * 128, col0 = xb * 128;
    int kbeg = z * ZCH;
    int kend = kbeg + ZCH; if (kend > GKP) kend = GKP;
    // staging mapping: thread -> row arow = tid>>1 (0..127), k-half akp = (tid&1)*16
    int arow = tid >> 1, akp = (tid & 1) * 16;
    int t_ar = (arow + (arow >> 2)) & 3;
    int s0 = akp >> 3;                       // slots s0, s0+1
    int wb0 = arow * 64 + ((s0 ^ t_ar) << 4);
    int wb1 = arow * 64 + (((s0 + 1) ^ t_ar) << 4);
    // read-side swizzle (row-dependent part reduces to r16 since row bases are multiples of 16)
    int tA = (r16 + (r16 >> 2)) & 3;
    int soA = (g ^ tA) << 4;
    f32x4 acc[4][4] = {};
    for (int k0 = kbeg; k0 < kend; k0 += 32) {
        // ---- load to registers (before barrier) ----
        int gr = row0 + arow;
        int gk = k0 + akp;
        float av[16];
        #pragma unroll
        for (int j = 0; j < 16; j += 4) {
            float4 v = (gr < NGENE && gk + j < NGENE)
                     ? *(const float4*)(A + (long)gr * NGENE + gk + j)
                     : make_float4(0.f, 0.f, 0.f, 0.f);
            av[j] = v.x; av[j + 1] = v.y; av[j + 2] = v.z; av[j + 3] = v.w;
        }
        unsigned short ah[16], alr[16];
        #pragma unroll
        for (int j = 0; j < 16; ++j) {
            ah[j]  = f2bf(av[j]);
            alr[j] = f2bf(av[j] - bf2f(ah[j]));
        }
        const unsigned short* bsh = Bh + (long)(col0 + arow) * GKP + gk;
        const unsigned short* bsl = Bl + (long)(col0 + arow) * GKP + gk;
        uint4 bh0 = *(const uint4*)bsh, bh1 = *(const uint4*)(bsh + 8);
        uint4 bl0 = *(const uint4*)bsl, bl1 = *(const uint4*)(bsl + 8);
        __syncthreads();   // previous iter's LDS reads done
        *(uint4*)(AsH + wb0) = *(const uint4*)&ah[0];
        *(uint4*)(AsH + wb1) = *(const uint4*)&ah[8];
        *(uint4*)(AsL + wb0) = *(const uint4*)&alr[0];
        *(uint4*)(AsL + wb1) = *(const uint4*)&alr[8];
        *(uint4*)(BsH + wb0) = bh0; *(uint4*)(BsH + wb1) = bh1;
        *(uint4*)(BsL + wb0) = bl0; *(uint4*)(BsL + wb1) = bl1;
        __syncthreads();   // staging visible
        bf16x8 afh[4], afl[4], bfh[4], bfl[4];
        #pragma unroll
        for (int m = 0; m < 4; ++m) {
            int Bb = (wr * 64 + m * 16 + r16) * 64 + soA;
            afh[m] = *(const bf16x8*)(AsH + Bb);
            afl[m] = *(const bf16x8*)(AsL + Bb);
        }
        #pragma unroll
        for (int n = 0; n < 4; ++n) {
            int Bb = (wc * 64 + n * 16 + r16) * 64 + soA;
            bfh[n] = *(const bf16x8*)(BsH + Bb);
            bfl[n] = *(const bf16x8*)(BsL + Bb);
        }
        #pragma unroll
        for (int m = 0; m < 4; ++m)
            #pragma unroll
            for (int n = 0; n < 4; ++n) {
                acc[m][n] = __builtin_amdgcn_mfma_f32_16x16x32_bf16(afh[m], bfh[n], acc[m][n], 0, 0, 0);
                acc[m][n] = __builtin_amdgcn_mfma_f32_16x16x32_bf16(afh[m], bfl[n], acc[m][n], 0, 0, 0);
                acc[m][n] = __builtin_amdgcn_mfma_f32_16x16x32_bf16(afl[m], bfh[n], acc[m][n], 0, 0, 0);
            }
    }
    #pragma unroll
    for (int m = 0; m < 4; ++m) {
        #pragma unroll
        for (int n = 0; n < 4; ++n) {
            #pragma unroll
            for (int r = 0; r < 4; ++r) {
                int rowg = row0 + wr * 64 + m * 16 + g * 4 + r;
                int colg = col0 + wc * 64 + n * 16 + r16;
                if (rowg < NGENE)
                    part[((long)z * NGENE + rowg) * H1 + colg] = acc[m][n][r];
            }
        }
    }
}

// ---------------- split-K reduce ----------------
__global__ __launch_bounds__(256) void reduce_splitk_kernel(const float* __restrict__ part,
                                                            const float* __restrict__ bias,
                                                            unsigned short* __restrict__ xh,
                                                            unsigned short* __restrict__ xl)
{
    const long NEL = (long)NGENE * H1;
    long stride = (long)gridDim.x * blockDim.x;
    for (long q = (long)blockIdx.x * blockDim.x + threadIdx.x; q * 4 < NEL; q += stride) {
        long e = q * 4;
        float4 sv = *(const float4*)(part + e);
        #pragma unroll
        for (int z = 1; z < ZSPLIT; ++z) {
            float4 t = *(const float4*)(part + (long)z * NEL + e);
            sv.x += t.x; sv.y += t.y; sv.z += t.z; sv.w += t.w;
        }
        int col = (int)(e & (H1 - 1));
        float4 b = *(const float4*)(bias + col);
        float v[4] = {sv.x + b.x, sv.y + b.y, sv.z + b.z, sv.w + b.w};
        unsigned short oh[4], ol[4];
        #pragma unroll
        for (int i = 0; i < 4; ++i) {
            oh[i] = f2bf(v[i]);
            ol[i] = f2bf(v[i] - bf2f(oh[i]));
        }
        long o = (long)(NDRUG + NCELL) * H1 + e;
        *(uint2*)(xh + o) = *(const uint2*)oh;
        *(uint2*)(xl + o) = *(const uint2*)ol;
    }
}

// ---------------- init kernels ----------------
__global__ void init1_kernel(float* m, int* deg, float* colstats, float* scal)
{
    int i = blockIdx.x * 256 + threadIdx.x;
    if (i < NNODE * 4) m[i] = -3.402823466e38f;
    if (i < NNODE) deg[i] = 0;
    if (i < 1024) colstats[i] = 0.f;
    if (i < 8) scal[i] = 0.f;
}

// zeroes mbuf (-inf) and colsum+colsq (1024 contiguous floats) — nothing else
__global__ void init2_kernel(float* m, float* colstats)
{
    int i = blockIdx.x * 256 + threadIdx.x;
    if (i < NNODE * 4) m[i] = -3.402823466e38f;
    if (i < 1024) colstats[i] = 0.f;
}

// ---------------- sum(edge_attr) -> scal[0] ----------------
__global__ void reduce_sum_kernel(const float* __restrict__ x, int n, float* out)
{
    float s = 0.f;
    for (int i = blockIdx.x * blockDim.x + threadIdx.x; i < n; i += gridDim.x * blockDim.x)
        s += x[i];
    for (int off = 32; off; off >>= 1) s += __shfl_down(s, off);
    if ((threadIdx.x & 63) == 0) atomicAdd(out, s);
}

// ---------------- ce[h] ----------------
__global__ __launch_bounds__(512) void ce_kernel(const float* We1, const float* ae1,
                                                 const float* We2, const float* ae2, float* ce)
{
    __shared__ float sm[512];
    int t = threadIdx.x;
    sm[t] = We1[t] * ae1[t];
    __syncthreads();
    if (t < 4) { float s = 0.f; for (int c = 0; c < 128; ++c) s += sm[t * 128 + c]; ce[t] = s; }
    __syncthreads();
    sm[t] = We2[t] * ae2[t];
    __syncthreads();
    if (t < 4) { float s = 0.f; for (int c = 0; c < 128; ++c) s += sm[t * 128 + c]; ce[4 + t] = s; }
}

// ---------------- degree histogram from edge_index only (data-independent) ----------------
__global__ void deg_kernel(const int* __restrict__ ei, int* __restrict__ deg)
{
    int e = blockIdx.x * blockDim.x + threadIdx.x;
    if (e >= ET) return;
    int d = (e < E0) ? ei[E0 + e] : (e - E0);
    atomicAdd(&deg[d], 1);
}

// ---------------- exclusive scan ----------------
__global__ __launch_bounds__(1024) void scan_kernel(const int* __restrict__ deg,
                                                    int* __restrict__ row_start,
                                                    int* __restrict__ cursor)
{
    __shared__ int sm[1024];
    int t = threadIdx.x;
    int base = t * 8;
    int loc[8];
    int sum = 0;
    #pragma unroll
    for (int j = 0; j < 8; ++j) {
        int v = (base + j < NNODE) ? deg[base + j] : 0;
        loc[j] = sum; sum += v;
    }
    sm[t] = sum;
    __syncthreads();
    for (int off = 1; off < 1024; off <<= 1) {
        int v = (t >= off) ? sm[t - off] : 0;
        __syncthreads();
        sm[t] += v;
        __syncthreads();
    }
    int excl = sm[t] - sum;
    #pragma unroll
    for (int j = 0; j < 8; ++j) {
        int idx = base + j;
        if (idx < NNODE) { int v = excl + loc[j]; row_start[idx] = v; cursor[idx] = v; }
    }
    if (t == 1023) row_start[NNODE] = sm[1023];
}

// ---------------- scatter edge structure into CSR (by dst): csr_src + pos_of_e ----------------
__global__ void scatter_csr_kernel(const int* __restrict__ ei, int* __restrict__ cursor,
                                   int* __restrict__ csr_src, int* __restrict__ pos_of_e)
{
    int e = blockIdx.x * blockDim.x + threadIdx.x;
    if (e >= ET) return;
    int s, d;
    if (e < E0) { s = ei[e]; d = ei[E0 + e]; }
    else        { s = d = e - E0; }
    int pos = atomicAdd(&cursor[d], 1);
    csr_src[pos] = s;
    pos_of_e[e] = pos;
}

// ---------------- per-node attention coefficients (4 nodes per block) ----------------
__global__ __launch_bounds__(256) void attn_coef_kernel(const float* __restrict__ xw,
                                                        const float* __restrict__ as,
                                                        const float* __restrict__ ad,
                                                        float* __restrict__ a_src,
                                                        float* __restrict__ a_dst)
{
    int n = blockIdx.x * 4 + (threadIdx.x >> 6);
    int l = threadIdx.x & 63;
    #pragma unroll
    for (int h = 0; h < 4; ++h) {
        float x1 = xw[(long)n * HD + h * 128 + l];
        float x2 = xw[(long)n * HD + h * 128 + 64 + l];
        float s = x1 * as[h * 128 + l] + x2 * as[h * 128 + 64 + l];
        float d = x1 * ad[h * 128 + l] + x2 * ad[h * 128 + 64 + l];
        for (int off = 32; off; off >>= 1) { s += __shfl_down(s, off); d += __shfl_down(d, off); }
        if (l == 0) { a_src[n * 4 + h] = s; a_dst[n * 4 + h] = d; }
    }
}

// ---------------- atomic float max ----------------
__device__ inline void atomicMaxF(float* addr, float v)
{
    if (v >= 0.f) atomicMax((int*)addr, __float_as_int(v));
    else          atomicMin((unsigned int*)addr, __float_as_uint(v));
}

// ---------------- per-edge alpha (scatter to CSR order) + segment max ----------------
__global__ void alpha_max_kernel(const int* __restrict__ ei, const float* __restrict__ eattr,
                                 const float* __restrict__ scal,
                                 const float* __restrict__ a_src, const float* __restrict__ a_dst,
                                 const float* __restrict__ ce,
                                 float* __restrict__ csr_alpha,
                                 const int* __restrict__ pos_of_e,
                                 float* __restrict__ m)
{
    int e = blockIdx.x * blockDim.x + threadIdx.x;
    if (e >= ET) return;
    int s, d; float a;
    if (e < E0) { s = ei[e]; d = ei[E0 + e]; a = eattr[e]; }
    else        { s = d = e - E0; a = scal[0] * (1.0f / E0); }
    float4 av;
    float* avp = (float*)&av;
    #pragma unroll
    for (int h = 0; h < 4; ++h) {
        float v = a_src[s * 4 + h] + a_dst[d * 4 + h] + a * ce[h];
        v = v > 0.f ? v : 0.2f * v;
        avp[h] = v;
        atomicMaxF(&m[d * 4 + h], v);
    }
    *(float4*)(csr_alpha + (long)pos_of_e[e] * 4) = av;
}

// ---------------- aggregation: one block (4 waves = 4 heads) per node, ILP=8 ----------------
__global__ __launch_bounds__(256) void aggregate_kernel(const float* __restrict__ xw,
                                                        const float* __restrict__ csr_alpha,
                                                        const float* __restrict__ m,
                                                        const int* __restrict__ rs,
                                                        const int* __restrict__ csr_src,
                                                        const float* __restrict__ bias,
                                                        float* __restrict__ out)
{
    int n = blockIdx.x;
    int h = threadIdx.x >> 6;
    int l = threadIdx.x & 63;
    float mnh = m[n * 4 + h];
    int i0 = rs[n], i1 = rs[n + 1];
    float den = 0.f;
    for (int i = i0 + l; i < i1; i += 64)
        den += expf(csr_alpha[(long)i * 4 + h] - mnh);
    for (int off = 32; off; off >>= 1) den += __shfl_down(den, off);
    den = __shfl(den, 0);
    float rden = 1.0f / (den + 1e-16f);
    float acc0 = 0.f, acc1 = 0.f;
    int i = i0;
    for (; i + 7 < i1; i += 8) {
        int   sv[8];
        float av[8], xv0[8], xv1[8];
        #pragma unroll
        for (int j = 0; j < 8; ++j) {
            sv[j] = csr_src[i + j];
            av[j] = csr_alpha[(long)(i + j) * 4 + h];
        }
        #pragma unroll
        for (int j = 0; j < 8; ++j) {
            const float* r = xw + (long)sv[j] * HD + h * 128;
            xv0[j] = r[l]; xv1[j] = r[64 + l];
        }
        #pragma unroll
        for (int j = 0; j < 8; ++j) {
            float w = expf(av[j] - mnh);
            acc0 += w * xv0[j];
            acc1 += w * xv1[j];
        }
    }
    for (; i < i1; ++i) {
        int s = csr_src[i];
        float w = expf(csr_alpha[(long)i * 4 + h] - mnh);
        const float* xr = xw + (long)s * HD + h * 128;
        acc0 += w * xr[l];
        acc1 += w * xr[64 + l];
    }
    out[(long)n * HD + h * 128 + l]      = acc0 * rden + bias[h * 128 + l];
    out[(long)n * HD + h * 128 + 64 + l] = acc1 * rden + bias[h * 128 + 64 + l];
}

// ---------------- graph norm: fused column sum + sum-of-squares ----------------
__global__ __launch_bounds__(256) void colstats_kernel(const float* __restrict__ x,
                                                       float* __restrict__ colsum,
                                                       float* __restrict__ colsumsq)
{
    int t = threadIdx.x, b = blockIdx.x;
    float s0 = 0.f, s1 = 0.f, q0 = 0.f, q1 = 0.f;
    for (int r = b * 125; r < (b + 1) * 125; ++r) {
        float v0 = x[(long)r * HD + t];
        float v1 = x[(long)r * HD + t + 256];
        s0 += v0; q0 += v0 * v0;
        s1 += v1; q1 += v1 * v1;
    }
    atomicAdd(&colsum[t], s0);
    atomicAdd(&colsum[t + 256], s1);
    atomicAdd(&colsumsq[t], q0);
    atomicAdd(&colsumsq[t + 256], q1);
}

// norm (+ReLU) in place; var = E[x^2] - ms*(2-ms)*mu^2 ; writes hi/lo bf16 copies
__global__ void norm_kernel(float* __restrict__ x,
                            unsigned short* __restrict__ xbh, unsigned short* __restrict__ xbl,
                            const float* __restrict__ colsum,
                            const float* __restrict__ colsumsq,
                            const float* __restrict__ g, const float* __restrict__ be,
                            const float* __restrict__ ms)
{
    int stride = gridDim.x * blockDim.x;
    for (int idx = blockIdx.x * blockDim.x + threadIdx.x; idx < NNODE * HD; idx += stride) {
        int j = idx & 511;
        float mu  = colsum[j] * (1.0f / NNODE);
        float ex2 = colsumsq[j] * (1.0f / NNODE);
        float msj = ms[j];
        float var = ex2 - msj * (2.0f - msj) * mu * mu;
        float v = x[idx] - msj * mu;
        float y = g[j] * v / sqrtf(var + 1e-5f) + be[j];
        y = y > 0.f ? y : 0.f;
        x[idx] = y;
        unsigned short h = f2bf(y);
        xbh[idx] = h;
        xbl[idx] = f2bf(y - bf2f(h));
    }
}

// ---------------- prediction head ----------------
__global__ __launch_bounds__(256) void head_kernel(const float* __restrict__ x2,
                                                   const int* __restrict__ idd,
                                                   const int* __restrict__ idc,
                                                   const float* __restrict__ Wout,
                                                   const float* __restrict__ bout,
                                                   float* __restrict__ out0)
{
    int w = threadIdx.x >> 6, l = threadIdx.x & 63;
    int b = blockIdx.x * 4 + w;
    if (b >= BSZ) return;
    int rd = idd[b], rc = idc[b];
    float s = 0.f;
    #pragma unroll
    for (int k = l; k < HD; k += 64)
        s += x2[(long)rd * HD + k] * Wout[k] + x2[(long)rc * HD + k] * Wout[HD + k];
    for (int off = 32; off; off >>= 1) s += __shfl_down(s, off);
    if (l == 0) out0[b] = s + bout[0];
}

// ---------------- all_att: zero + scatter scalar ----------------
__global__ void zero_f4_kernel(float4* __restrict__ p, long n4)
{
    long stride = (long)gridDim.x * blockDim.x;
    for (long i = (long)blockIdx.x * blockDim.x + threadIdx.x; i < n4; i += stride)
        p[i] = make_float4(0.f, 0.f, 0.f, 0.f);
}

__global__ void scatter_att_kernel(const int* __restrict__ ei, float* __restrict__ attm)
{
    int e = blockIdx.x * blockDim.x + threadIdx.x;
    if (e >= ET) return;
    int s, d;
    if (e < E0) { s = ei[e]; d = ei[E0 + e]; }
    else        { s = d = e - E0; }
    const float val = 2.0f * (float)NNODE / (float)ET;
    attm[(long)s * NNODE + d] = val;
}

// ---------------- launch ----------------
extern "C" void kernel_launch(void* const* d_in, const int* in_sizes, int n_in,
                              void* d_out, int out_size, void* d_ws, size_t ws_size,
                              hipStream_t stream)
{
    const float* drug   = (const float*)d_in[0];
    const float* cell   = (const float*)d_in[1];
    const float* gene   = (const float*)d_in[2];
    const float* eattr  = (const float*)d_in[3];
    const int*   ei     = (const int*)d_in[4];
    const int*   idd    = (const int*)d_in[5];
    const int*   idc    = (const int*)d_in[6];
    const float* Wdrug  = (const float*)d_in[7];
    const float* bdrug  = (const float*)d_in[8];
    const float* Wcell  = (const float*)d_in[9];
    const float* bcell  = (const float*)d_in[10];
    const float* Wgene  = (const float*)d_in[11];
    const float* bgene  = (const float*)d_in[12];
    const float* W1     = (const float*)d_in[13];
    const float* b1     = (const float*)d_in[14];
    const float* as1    = (const float*)d_in[15];
    const float* ad1    = (const float*)d_in[16];
    const float* We1    = (const float*)d_in[17];
    const float* ae1    = (const float*)d_in[18];
    const float* bias1  = (const float*)d_in[19];
    const float* g1     = (const float*)d_in[20];
    const float* be1    = (const float*)d_in[21];
    const float* ms1    = (const float*)d_in[22];
    const float* W2     = (const float*)d_in[23];
    const float* b2     = (const float*)d_in[24];
    const float* as2    = (const float*)d_in[25];
    const float* ad2    = (const float*)d_in[26];
    const float* We2    = (const float*)d_in[27];
    const float* ae2    = (const float*)d_in[28];
    const float* bias2  = (const float*)d_in[29];
    const float* g2     = (const float*)d_in[30];
    const float* be2    = (const float*)d_in[31];
    const float* ms2    = (const float*)d_in[32];
    const float* Wout   = (const float*)d_in[33];
    const float* bout   = (const float*)d_in[34];

    float* out0 = (float*)d_out;                 // [10000]
    float* attm = (float*)d_out + BSZ;           // [8000*8000]

    // ---- workspace layout ----
    float* ws     = (float*)d_ws;
    float* xw     = ws;                          // 8000*512
    float* outb   = xw + (long)NNODE * HD;       // 8000*512
    float* csr_al = outb + (long)NNODE * HD;     // 168000*4
    float* a_src  = csr_al + (long)ET * 4;       // 32000
    float* a_dst  = a_src + NNODE * 4;           // 32000
    float* mbuf   = a_dst + NNODE * 4;           // 32000
    float* colsum = mbuf + NNODE * 4;            // 512
    float* colsq  = colsum + 512;                // 512 (contiguous with colsum)
    float* ce     = colsq + 512;                 // 8
    float* scal   = ce + 8;                      // 8
    int* deg      = (int*)(scal + 8);            // 8000
    int* rs       = deg + NNODE;                 // 8004 (padded)
    int* cursor   = rs + NNODE + 4;              // 8000
    int* csr_src  = cursor + NNODE;              // 168000
    int* pos_of_e = csr_src + ET;                // 168000
    unsigned short* p = (unsigned short*)(pos_of_e + ET);
    unsigned short* drug_h = p; p += (long)1024 * 1024;
    unsigned short* drug_l = p; p += (long)1024 * 1024;
    unsigned short* cell_h = p; p += (long)1024 * 1024;
    unsigned short* cell_l = p; p += (long)1024 * 1024;
    unsigned short* x0_h   = p; p += (long)NNODE * H1;
    unsigned short* x0_l   = p; p += (long)NNODE * H1;
    unsigned short* xb_h   = p; p += (long)NNODE * HD;
    unsigned short* xb_l   = p; p += (long)NNODE * HD;
    unsigned short* Wd_h   = p; p += 256 * 1024;
    unsigned short* Wd_l   = p; p += 256 * 1024;
    unsigned short* Wc_h   = p; p += 256 * 1024;
    unsigned short* Wc_l   = p; p += 256 * 1024;
    unsigned short* Wg_h   = p; p += 256 * GKP;
    unsigned short* Wg_l   = p; p += 256 * GKP;
    unsigned short* W1_h   = p; p += 512 * 256;
    unsigned short* W1_l   = p; p += 512 * 256;
    unsigned short* W2_h   = p; p += 512 * 512;
    unsigned short* W2_l   = p; p += 512 * 512;
    float* partsk = (float*)((((unsigned long long)p) + 15) & ~15ULL);  // ZSPLIT*NGENE*H1 f32

    dim3 blk256(256);
    int gE = (ET + 255) / 256;

    // init + small precomputes + data-independent CSR build
    init1_kernel<<<125, blk256, 0, stream>>>(mbuf, deg, colsum, scal);
    deg_kernel<<<gE, blk256, 0, stream>>>(ei, deg);
    scan_kernel<<<1, 1024, 0, stream>>>(deg, rs, cursor);
    scatter_csr_kernel<<<gE, blk256, 0, stream>>>(ei, cursor, csr_src, pos_of_e);
    reduce_sum_kernel<<<64, blk256, 0, stream>>>(eattr, E0, &scal[0]);
    ce_kernel<<<1, 512, 0, stream>>>(We1, ae1, We2, ae2, ce);

    // ---- hi/lo split conversions (drug/cell inputs + all weights) ----
    cvt_pad2_kernel<<<512, blk256, 0, stream>>>(drug, drug_h, drug_l, NDRUG, NDRUG, 1024, 1024);
    cvt_pad2_kernel<<<512, blk256, 0, stream>>>(cell, cell_h, cell_l, NCELL, NCELL, 1024, 1024);
    transpose_cvt2_kernel<<<dim3(32, 8),  blk256, 0, stream>>>(Wdrug, Wd_h, Wd_l, NDRUG, H1, 1024);
    transpose_cvt2_kernel<<<dim3(32, 8),  blk256, 0, stream>>>(Wcell, Wc_h, Wc_l, NCELL, H1, 1024);
    transpose_cvt2_kernel<<<dim3(188, 8), blk256, 0, stream>>>(Wgene, Wg_h, Wg_l, NGENE, H1, GKP);
    transpose_cvt2_kernel<<<dim3(8, 16),  blk256, 0, stream>>>(W1, W1_h, W1_l, H1, HD, H1);
    transpose_cvt2_kernel<<<dim3(16, 16), blk256, 0, stream>>>(W2, W2_h, W2_l, HD, HD, HD);

    // ---- input projections -> x0 (hi/lo bf16) ----
    gemm_mfma2<1><<<dim3(H1 / 64, 16), blk256, 0, stream>>>(drug_h, drug_l, Wd_h, Wd_l, bdrug,
        nullptr, x0_h, x0_l, NDRUG, 1024, H1);
    gemm_mfma2<1><<<dim3(H1 / 64, 16), blk256, 0, stream>>>(cell_h, cell_l, Wc_h, Wc_l, bcell,
        nullptr, x0_h + (long)NDRUG * H1, x0_l + (long)NDRUG * H1, NCELL, 1024, H1);
    gemm_gene_f32<<<752, blk256, 0, stream>>>(gene, Wg_h, Wg_l, partsk);
    reduce_splitk_kernel<<<1500, blk256, 0, stream>>>(partsk, bgene, x0_h, x0_l);

    // ---- layer 1 ----
    gemm_mfma2<0><<<dim3(HD / 64, NNODE / 64), blk256, 0, stream>>>(x0_h, x0_l, W1_h, W1_l, b1,
        xw, nullptr, nullptr, NNODE, H1, HD);
    attn_coef_kernel<<<NNODE / 4, blk256, 0, stream>>>(xw, as1, ad1, a_src, a_dst);
    alpha_max_kernel<<<gE, blk256, 0, stream>>>(ei, eattr, scal, a_src, a_dst, ce,
        csr_al, pos_of_e, mbuf);
    aggregate_kernel<<<NNODE, blk256, 0, stream>>>(xw, csr_al, mbuf, rs, csr_src, bias1, outb);
    colstats_kernel<<<64, blk256, 0, stream>>>(outb, colsum, colsq);
    norm_kernel<<<2048, blk256, 0, stream>>>(outb, xb_h, xb_l, colsum, colsq, g1, be1, ms1);

    // ---- layer 2 ----
    gemm_mfma2<0><<<dim3(HD / 64, NNODE / 64), blk256, 0, stream>>>(xb_h, xb_l, W2_h, W2_l, b2,
        xw, nullptr, nullptr, NNODE, HD, HD);
    attn_coef_kernel<<<NNODE / 4, blk256, 0, stream>>>(xw, as2, ad2, a_src, a_dst);
    init2_kernel<<<125, blk256, 0, stream>>>(mbuf, colsum);  // zeroes mbuf + colsum+colsq (1024)
    alpha_max_kernel<<<gE, blk256, 0, stream>>>(ei, eattr, scal, a_src, a_dst, ce + 4,
        csr_al, pos_of_e, mbuf);
    aggregate_kernel<<<NNODE, blk256, 0, stream>>>(xw, csr_al, mbuf, rs, csr_src, bias2, outb);
    colstats_kernel<<<64, blk256, 0, stream>>>(outb, colsum, colsq);
    norm_kernel<<<2048, blk256, 0, stream>>>(outb, xb_h, xb_l, colsum, colsq, g2, be2, ms2);

    // ---- head + attention matrix ----
    head_kernel<<<(BSZ + 3) / 4, blk256, 0, stream>>>(outb, idd, idc, Wout, bout, out0);
    zero_f4_kernel<<<2048, blk256, 0, stream>>>((float4*)attm, (long)NNODE * NNODE / 4);
    scatter_att_kernel<<<gE, blk256, 0, stream>>>(ei, attm);
}

// Round 12
// 598.777 us; speedup vs baseline: 1.2429x; 1.0025x over previous
//
#include <hip/hip_runtime.h>
#include <math.h>

// ---------------- problem constants ----------------
#define NDRUG 1000
#define NCELL 1000
#define NGENE 6000
#define NNODE 8000
#define H1 256
#define HD  512   // HEADS*H2 = HEADS*H3
#define E0  160000
#define ET  168000   // E0 + NNODE self loops
#define BSZ 10000
#define GKP 6016    // padded gene K (weights only)
#define ZSPLIT 8    // gene split-K factor
#define ZCH 768     // k-elements per z chunk

typedef __attribute__((ext_vector_type(8))) short bf16x8;
typedef __attribute__((ext_vector_type(4))) float f32x4;

__device__ inline unsigned short f2bf(float f)
{
    unsigned u = __float_as_uint(f);
    u += 0x7fffu + ((u >> 16) & 1u);   // RNE
    return (unsigned short)(u >> 16);
}
__device__ inline float bf2f(unsigned short h)
{
    return __uint_as_float(((unsigned)h) << 16);
}

// ---------------- f32 -> (hi,lo) bf16 with [Mp][Kp] zero padding (drug/cell only) ----------------
__global__ void cvt_pad2_kernel(const float* __restrict__ in,
                                unsigned short* __restrict__ hi,
                                unsigned short* __restrict__ lo,
                                int M, int K, int Mp, int Kp)
{
    long total = (long)Mp * Kp / 8;
    int kp8 = Kp / 8;
    long stride = (long)gridDim.x * blockDim.x;
    for (long u = (long)blockIdx.x * blockDim.x + threadIdx.x; u < total; u += stride) {
        long row = u / kp8; int kc = (int)(u % kp8);
        unsigned short oh[8], ol[8];
        if (row < M && kc * 8 < K) {   // K%8==0
            const float* p = in + row * (long)K + kc * 8;
            float4 a = *(const float4*)p, b = *(const float4*)(p + 4);
            float v[8] = {a.x, a.y, a.z, a.w, b.x, b.y, b.z, b.w};
            #pragma unroll
            for (int i = 0; i < 8; ++i) {
                unsigned short h = f2bf(v[i]);
                oh[i] = h;
                ol[i] = f2bf(v[i] - bf2f(h));
            }
        } else {
            #pragma unroll
            for (int i = 0; i < 8; ++i) { oh[i] = 0; ol[i] = 0; }
        }
        *(uint4*)(hi + u * 8) = *(const uint4*)oh;
        *(uint4*)(lo + u * 8) = *(const uint4*)ol;
    }
}

// ---------------- W[K][N] f32 -> Wt_{hi,lo}[N][Kp] bf16 ----------------
__global__ __launch_bounds__(256) void transpose_cvt2_kernel(const float* __restrict__ W,
                                                             unsigned short* __restrict__ Wh,
                                                             unsigned short* __restrict__ Wl,
                                                             int K, int N, int Kp)
{
    __shared__ float t[32][33];
    int kb = blockIdx.x * 32, nb = blockIdx.y * 32;
    int tx = threadIdx.x & 31, ty = threadIdx.x >> 5;  // ty 0..7
    #pragma unroll
    for (int i = 0; i < 32; i += 8) {
        int k = kb + ty + i;
        t[ty + i][tx] = (k < K) ? W[(long)k * N + nb + tx] : 0.f;
    }
    __syncthreads();
    #pragma unroll
    for (int i = 0; i < 32; i += 8) {
        int n = nb + ty + i;
        float v = t[tx][ty + i];
        unsigned short h = f2bf(v);
        Wh[(long)n * Kp + kb + tx] = h;
        Wl[(long)n * Kp + kb + tx] = f2bf(v - bf2f(h));
    }
}

// ---------------- split-bf16 MFMA GEMM, 64x64 tile ----------------
template<int OUTBF>
__global__ __launch_bounds__(256) void gemm_mfma2(const unsigned short* __restrict__ Ah,
                                                  const unsigned short* __restrict__ Al,
                                                  const unsigned short* __restrict__ Bh,
                                                  const unsigned short* __restrict__ Bl,
                                                  const float* __restrict__ bias,
                                                  float* __restrict__ Cf,
                                                  unsigned short* __restrict__ Cbh,
                                                  unsigned short* __restrict__ Cbl,
                                                  int M, int Kp, int N)
{
    __shared__ unsigned short AsH[64 * 64];
    __shared__ unsigned short AsL[64 * 64];
    __shared__ unsigned short BsH[64 * 64];
    __shared__ unsigned short BsL[64 * 64];
    char* AsH8 = (char*)AsH; char* AsL8 = (char*)AsL;
    char* BsH8 = (char*)BsH; char* BsL8 = (char*)BsL;
    int tid = threadIdx.x;
    int w = tid >> 6, l = tid & 63;
    int wr = w >> 1, wc = w & 1;
    int g = l >> 4, r16 = l & 15;
    int row0 = blockIdx.y * 64, col0 = blockIdx.x * 64;
    int srow = tid >> 3, skc = tid & 7;
    int B0 = srow * 128 + skc * 16;       int P0 = B0 ^ ((srow & 7) << 4);
    int r1 = srow + 32;                   int B1 = r1 * 128 + skc * 16;
    int P1 = B1 ^ ((r1 & 7) << 4);
    f32x4 acc[2][2] = {};
    for (int k0 = 0; k0 < Kp; k0 += 64) {
        long a0 = (long)(row0 + srow) * Kp + k0 + skc * 8;
        long a1 = (long)(row0 + srow + 32) * Kp + k0 + skc * 8;
        long b0 = (long)(col0 + srow) * Kp + k0 + skc * 8;
        long b1 = (long)(col0 + srow + 32) * Kp + k0 + skc * 8;
        uint4 ah0 = *(const uint4*)(Ah + a0); uint4 ah1 = *(const uint4*)(Ah + a1);
        uint4 al0 = *(const uint4*)(Al + a0); uint4 al1 = *(const uint4*)(Al + a1);
        uint4 bh0 = *(const uint4*)(Bh + b0); uint4 bh1 = *(const uint4*)(Bh + b1);
        uint4 bl0 = *(const uint4*)(Bl + b0); uint4 bl1 = *(const uint4*)(Bl + b1);
        __syncthreads();
        *(uint4*)(AsH8 + P0) = ah0; *(uint4*)(AsH8 + P1) = ah1;
        *(uint4*)(AsL8 + P0) = al0; *(uint4*)(AsL8 + P1) = al1;
        *(uint4*)(BsH8 + P0) = bh0; *(uint4*)(BsH8 + P1) = bh1;
        *(uint4*)(BsL8 + P0) = bl0; *(uint4*)(BsL8 + P1) = bl1;
        __syncthreads();
        #pragma unroll
        for (int kk = 0; kk < 2; ++kk) {
            bf16x8 afh[2], afl[2], bfh[2], bfl[2];
            #pragma unroll
            for (int m = 0; m < 2; ++m) {
                int row = wr * 32 + m * 16 + r16;
                int Bb = (row * 128 + kk * 64 + g * 16) ^ ((row & 7) << 4);
                afh[m] = *(const bf16x8*)(AsH8 + Bb);
                afl[m] = *(const bf16x8*)(AsL8 + Bb);
            }
            #pragma unroll
            for (int n = 0; n < 2; ++n) {
                int row = wc * 32 + n * 16 + r16;
                int Bb = (row * 128 + kk * 64 + g * 16) ^ ((row & 7) << 4);
                bfh[n] = *(const bf16x8*)(BsH8 + Bb);
                bfl[n] = *(const bf16x8*)(BsL8 + Bb);
            }
            #pragma unroll
            for (int m = 0; m < 2; ++m)
                #pragma unroll
                for (int n = 0; n < 2; ++n) {
                    acc[m][n] = __builtin_amdgcn_mfma_f32_16x16x32_bf16(afh[m], bfh[n], acc[m][n], 0, 0, 0);
                    acc[m][n] = __builtin_amdgcn_mfma_f32_16x16x32_bf16(afh[m], bfl[n], acc[m][n], 0, 0, 0);
                    acc[m][n] = __builtin_amdgcn_mfma_f32_16x16x32_bf16(afl[m], bfh[n], acc[m][n], 0, 0, 0);
                }
        }
    }
    #pragma unroll
    for (int m = 0; m < 2; ++m) {
        #pragma unroll
        for (int n = 0; n < 2; ++n) {
            #pragma unroll
            for (int r = 0; r < 4; ++r) {
                int rowg = row0 + wr * 32 + m * 16 + g * 4 + r;
                int colg = col0 + wc * 32 + n * 16 + r16;
                if (rowg < M) {
                    float v = acc[m][n][r] + bias[colg];
                    if (OUTBF) {
                        unsigned short h = f2bf(v);
                        Cbh[(long)rowg * N + colg] = h;
                        Cbl[(long)rowg * N + colg] = f2bf(v - bf2f(h));
                    } else {
                        Cf[(long)rowg * N + colg] = v;
                    }
                }
            }
        }
    }
}

// ---------------- gene GEMM: f32 A staged in-kernel to hi/lo LDS; 128x128, BK=32, split-K ------
// A = raw gene f32 [6000][6000]; B = Wg hi/lo bf16 [256][GKP]. Swizzle t(r)=(r+(r>>2))&3 applied
// on BOTH ds_write slot and read slot (same involution).
__global__ __launch_bounds__(256) void gemm_gene_f32(const float* __restrict__ A,
                                                     const unsigned short* __restrict__ Bh,
                                                     const unsigned short* __restrict__ Bl,
                                                     float* __restrict__ part)
{
    __shared__ char lds[32768];
    char* AsH = lds;          char* AsL = lds + 8192;
    char* BsH = lds + 16384;  char* BsL = lds + 24576;
    int tid = threadIdx.x;
    int w = tid >> 6, l = tid & 63;
    int wr = w >> 1, wc = w & 1;
    int g = l >> 4, r16 = l & 15;
    // XCD-pair relabel (752 = 8*94): pairs (xb) and a z-chunk stay on one XCD
    int pid = blockIdx.x;
    int L = (pid & 7) * 94 + (pid >> 3);
    int xb = L & 1;
    int yb = (L >> 1) % 47;
    int z  = L / 94;
    int row0 = yb * 128, col0 = xb * 128;
    int kbeg = z * ZCH;
    int kend = kbeg + ZCH; if (kend > GKP) kend = GKP;
    // staging mapping: thread -> row arow = tid>>1 (0..127), k-half akp = (tid&1)*16
    int arow = tid >> 1, akp = (tid & 1) * 16;
    int t_ar = (arow + (arow >> 2)) & 3;
    int s0 = akp >> 3;                       // slots s0, s0+1
    int wb0 = arow * 64 + ((s0 ^ t_ar) << 4);
    int wb1 = arow * 64 + (((s0 + 1) ^ t_ar) << 4);
    // read-side swizzle (row-dependent part reduces to r16 since row bases are multiples of 16)
    int tA = (r16 + (r16 >> 2)) & 3;
    int soA = (g ^ tA) << 4;
    f32x4 acc[4][4] = {};
    for (int k0 = kbeg; k0 < kend; k0 += 32) {
        // ---- load to registers (before barrier) ----
        int gr = row0 + arow;
        int gk = k0 + akp;
        float av[16];
        #pragma unroll
        for (int j = 0; j < 16; j += 4) {
            float4 v = (gr < NGENE && gk + j < NGENE)
                     ? *(const float4*)(A + (long)gr * NGENE + gk + j)
                     : make_float4(0.f, 0.f, 0.f, 0.f);
            av[j] = v.x; av[j + 1] = v.y; av[j + 2] = v.z; av[j + 3] = v.w;
        }
        unsigned short ah[16], alr[16];
        #pragma unroll
        for (int j = 0; j < 16; ++j) {
            ah[j]  = f2bf(av[j]);
            alr[j] = f2bf(av[j] - bf2f(ah[j]));
        }
        const unsigned short* bsh = Bh + (long)(col0 + arow) * GKP + gk;
        const unsigned short* bsl = Bl + (long)(col0 + arow) * GKP + gk;
        uint4 bh0 = *(const uint4*)bsh, bh1 = *(const uint4*)(bsh + 8);
        uint4 bl0 = *(const uint4*)bsl, bl1 = *(const uint4*)(bsl + 8);
        __syncthreads();   // previous iter's LDS reads done
        *(uint4*)(AsH + wb0) = *(const uint4*)&ah[0];
        *(uint4*)(AsH + wb1) = *(const uint4*)&ah[8];
        *(uint4*)(AsL + wb0) = *(const uint4*)&alr[0];
        *(uint4*)(AsL + wb1) = *(const uint4*)&alr[8];
        *(uint4*)(BsH + wb0) = bh0; *(uint4*)(BsH + wb1) = bh1;
        *(uint4*)(BsL + wb0) = bl0; *(uint4*)(BsL + wb1) = bl1;
        __syncthreads();   // staging visible
        bf16x8 afh[4], afl[4], bfh[4], bfl[4];
        #pragma unroll
        for (int m = 0; m < 4; ++m) {
            int Bb = (wr * 64 + m * 16 + r16) * 64 + soA;
            afh[m] = *(const bf16x8*)(AsH + Bb);
            afl[m] = *(const bf16x8*)(AsL + Bb);
        }
        #pragma unroll
        for (int n = 0; n < 4; ++n) {
            int Bb = (wc * 64 + n * 16 + r16) * 64 + soA;
            bfh[n] = *(const bf16x8*)(BsH + Bb);
            bfl[n] = *(const bf16x8*)(BsL + Bb);
        }
        #pragma unroll
        for (int m = 0; m < 4; ++m)
            #pragma unroll
            for (int n = 0; n < 4; ++n) {
                acc[m][n] = __builtin_amdgcn_mfma_f32_16x16x32_bf16(afh[m], bfh[n], acc[m][n], 0, 0, 0);
                acc[m][n] = __builtin_amdgcn_mfma_f32_16x16x32_bf16(afh[m], bfl[n], acc[m][n], 0, 0, 0);
                acc[m][n] = __builtin_amdgcn_mfma_f32_16x16x32_bf16(afl[m], bfh[n], acc[m][n], 0, 0, 0);
            }
    }
    #pragma unroll
    for (int m = 0; m < 4; ++m) {
        #pragma unroll
        for (int n = 0; n < 4; ++n) {
            #pragma unroll
            for (int r = 0; r < 4; ++r) {
                int rowg = row0 + wr * 64 + m * 16 + g * 4 + r;
                int colg = col0 + wc * 64 + n * 16 + r16;
                if (rowg < NGENE)
                    part[((long)z * NGENE + rowg) * H1 + colg] = acc[m][n][r];
            }
        }
    }
}

// ---------------- split-K reduce ----------------
__global__ __launch_bounds__(256) void reduce_splitk_kernel(const float* __restrict__ part,
                                                            const float* __restrict__ bias,
                                                            unsigned short* __restrict__ xh,
                                                            unsigned short* __restrict__ xl)
{
    const long NEL = (long)NGENE * H1;
    long stride = (long)gridDim.x * blockDim.x;
    for (long q = (long)blockIdx.x * blockDim.x + threadIdx.x; q * 4 < NEL; q += stride) {
        long e = q * 4;
        float4 sv = *(const float4*)(part + e);
        #pragma unroll
        for (int z = 1; z < ZSPLIT; ++z) {
            float4 t = *(const float4*)(part + (long)z * NEL + e);
            sv.x += t.x; sv.y += t.y; sv.z += t.z; sv.w += t.w;
        }
        int col = (int)(e & (H1 - 1));
        float4 b = *(const float4*)(bias + col);
        float v[4] = {sv.x + b.x, sv.y + b.y, sv.z + b.z, sv.w + b.w};
        unsigned short oh[4], ol[4];
        #pragma unroll
        for (int i = 0; i < 4; ++i) {
            oh[i] = f2bf(v[i]);
            ol[i] = f2bf(v[i] - bf2f(oh[i]));
        }
        long o = (long)(NDRUG + NCELL) * H1 + e;
        *(uint2*)(xh + o) = *(const uint2*)oh;
        *(uint2*)(xl + o) = *(const uint2*)ol;
    }
}

// ---------------- init kernels ----------------
__global__ void init1_kernel(float* m, int* deg, float* colstats, float* scal)
{
    int i = blockIdx.x * 256 + threadIdx.x;
    if (i < NNODE * 4) m[i] = -3.402823466e38f;
    if (i < NNODE) deg[i] = 0;
    if (i < 1024) colstats[i] = 0.f;
    if (i < 8) scal[i] = 0.f;
}

// zeroes mbuf (-inf) and colsum+colsq (1024 contiguous floats) — nothing else
__global__ void init2_kernel(float* m, float* colstats)
{
    int i = blockIdx.x * 256 + threadIdx.x;
    if (i < NNODE * 4) m[i] = -3.402823466e38f;
    if (i < 1024) colstats[i] = 0.f;
}

// ---------------- sum(edge_attr) -> scal[0] ----------------
__global__ void reduce_sum_kernel(const float* __restrict__ x, int n, float* out)
{
    float s = 0.f;
    for (int i = blockIdx.x * blockDim.x + threadIdx.x; i < n; i += gridDim.x * blockDim.x)
        s += x[i];
    for (int off = 32; off; off >>= 1) s += __shfl_down(s, off);
    if ((threadIdx.x & 63) == 0) atomicAdd(out, s);
}

// ---------------- ce[h] ----------------
__global__ __launch_bounds__(512) void ce_kernel(const float* We1, const float* ae1,
                                                 const float* We2, const float* ae2, float* ce)
{
    __shared__ float sm[512];
    int t = threadIdx.x;
    sm[t] = We1[t] * ae1[t];
    __syncthreads();
    if (t < 4) { float s = 0.f; for (int c = 0; c < 128; ++c) s += sm[t * 128 + c]; ce[t] = s; }
    __syncthreads();
    sm[t] = We2[t] * ae2[t];
    __syncthreads();
    if (t < 4) { float s = 0.f; for (int c = 0; c < 128; ++c) s += sm[t * 128 + c]; ce[4 + t] = s; }
}

// ---------------- degree histogram from edge_index only (data-independent) ----------------
__global__ void deg_kernel(const int* __restrict__ ei, int* __restrict__ deg)
{
    int e = blockIdx.x * blockDim.x + threadIdx.x;
    if (e >= ET) return;
    int d = (e < E0) ? ei[E0 + e] : (e - E0);
    atomicAdd(&deg[d], 1);
}

// ---------------- exclusive scan ----------------
__global__ __launch_bounds__(1024) void scan_kernel(const int* __restrict__ deg,
                                                    int* __restrict__ row_start,
                                                    int* __restrict__ cursor)
{
    __shared__ int sm[1024];
    int t = threadIdx.x;
    int base = t * 8;
    int loc[8];
    int sum = 0;
    #pragma unroll
    for (int j = 0; j < 8; ++j) {
        int v = (base + j < NNODE) ? deg[base + j] : 0;
        loc[j] = sum; sum += v;
    }
    sm[t] = sum;
    __syncthreads();
    for (int off = 1; off < 1024; off <<= 1) {
        int v = (t >= off) ? sm[t - off] : 0;
        __syncthreads();
        sm[t] += v;
        __syncthreads();
    }
    int excl = sm[t] - sum;
    #pragma unroll
    for (int j = 0; j < 8; ++j) {
        int idx = base + j;
        if (idx < NNODE) { int v = excl + loc[j]; row_start[idx] = v; cursor[idx] = v; }
    }
    if (t == 1023) row_start[NNODE] = sm[1023];
}

// ---------------- scatter edge structure into CSR (by dst): csr_src + pos_of_e ----------------
__global__ void scatter_csr_kernel(const int* __restrict__ ei, int* __restrict__ cursor,
                                   int* __restrict__ csr_src, int* __restrict__ pos_of_e)
{
    int e = blockIdx.x * blockDim.x + threadIdx.x;
    if (e >= ET) return;
    int s, d;
    if (e < E0) { s = ei[e]; d = ei[E0 + e]; }
    else        { s = d = e - E0; }
    int pos = atomicAdd(&cursor[d], 1);
    csr_src[pos] = s;
    pos_of_e[e] = pos;
}

// ---------------- per-node attention coefficients (4 nodes per block) ----------------
__global__ __launch_bounds__(256) void attn_coef_kernel(const float* __restrict__ xw,
                                                        const float* __restrict__ as,
                                                        const float* __restrict__ ad,
                                                        float* __restrict__ a_src,
                                                        float* __restrict__ a_dst)
{
    int n = blockIdx.x * 4 + (threadIdx.x >> 6);
    int l = threadIdx.x & 63;
    #pragma unroll
    for (int h = 0; h < 4; ++h) {
        float x1 = xw[(long)n * HD + h * 128 + l];
        float x2 = xw[(long)n * HD + h * 128 + 64 + l];
        float s = x1 * as[h * 128 + l] + x2 * as[h * 128 + 64 + l];
        float d = x1 * ad[h * 128 + l] + x2 * ad[h * 128 + 64 + l];
        for (int off = 32; off; off >>= 1) { s += __shfl_down(s, off); d += __shfl_down(d, off); }
        if (l == 0) { a_src[n * 4 + h] = s; a_dst[n * 4 + h] = d; }
    }
}

// ---------------- atomic float max ----------------
__device__ inline void atomicMaxF(float* addr, float v)
{
    if (v >= 0.f) atomicMax((int*)addr, __float_as_int(v));
    else          atomicMin((unsigned int*)addr, __float_as_uint(v));
}

// ---------------- per-edge alpha (scatter to CSR order) + segment max ----------------
__global__ void alpha_max_kernel(const int* __restrict__ ei, const float* __restrict__ eattr,
                                 const float* __restrict__ scal,
                                 const float* __restrict__ a_src, const float* __restrict__ a_dst,
                                 const float* __restrict__ ce,
                                 float* __restrict__ csr_alpha,
                                 const int* __restrict__ pos_of_e,
                                 float* __restrict__ m)
{
    int e = blockIdx.x * blockDim.x + threadIdx.x;
    if (e >= ET) return;
    int s, d; float a;
    if (e < E0) { s = ei[e]; d = ei[E0 + e]; a = eattr[e]; }
    else        { s = d = e - E0; a = scal[0] * (1.0f / E0); }
    float4 av;
    float* avp = (float*)&av;
    #pragma unroll
    for (int h = 0; h < 4; ++h) {
        float v = a_src[s * 4 + h] + a_dst[d * 4 + h] + a * ce[h];
        v = v > 0.f ? v : 0.2f * v;
        avp[h] = v;
        atomicMaxF(&m[d * 4 + h], v);
    }
    *(float4*)(csr_alpha + (long)pos_of_e[e] * 4) = av;
}

// ---------------- aggregation: one block (4 waves = 4 heads) per node, ILP=8 ----------------
__global__ __launch_bounds__(256) void aggregate_kernel(const float* __restrict__ xw,
                                                        const float* __restrict__ csr_alpha,
                                                        const float* __restrict__ m,
                                                        const int* __restrict__ rs,
                                                        const int* __restrict__ csr_src,
                                                        const float* __restrict__ bias,
                                                        float* __restrict__ out)
{
    int n = blockIdx.x;
    int h = threadIdx.x >> 6;
    int l = threadIdx.x & 63;
    float mnh = m[n * 4 + h];
    int i0 = rs[n], i1 = rs[n + 1];
    float den = 0.f;
    for (int i = i0 + l; i < i1; i += 64)
        den += expf(csr_alpha[(long)i * 4 + h] - mnh);
    for (int off = 32; off; off >>= 1) den += __shfl_down(den, off);
    den = __shfl(den, 0);
    float rden = 1.0f / (den + 1e-16f);
    float acc0 = 0.f, acc1 = 0.f;
    int i = i0;
    for (; i + 7 < i1; i += 8) {
        int   sv[8];
        float av[8], xv0[8], xv1[8];
        #pragma unroll
        for (int j = 0; j < 8; ++j) {
            sv[j] = csr_src[i + j];
            av[j] = csr_alpha[(long)(i + j) * 4 + h];
        }
        #pragma unroll
        for (int j = 0; j < 8; ++j) {
            const float* r = xw + (long)sv[j] * HD + h * 128;
            xv0[j] = r[l]; xv1[j] = r[64 + l];
        }
        #pragma unroll
        for (int j = 0; j < 8; ++j) {
            float w = expf(av[j] - mnh);
            acc0 += w * xv0[j];
            acc1 += w * xv1[j];
        }
    }
    for (; i < i1; ++i) {
        int s = csr_src[i];
        float w = expf(csr_alpha[(long)i * 4 + h] - mnh);
        const float* xr = xw + (long)s * HD + h * 128;
        acc0 += w * xr[l];
        acc1 += w * xr[64 + l];
    }
    out[(long)n * HD + h * 128 + l]      = acc0 * rden + bias[h * 128 + l];
    out[(long)n * HD + h * 128 + 64 + l] = acc1 * rden + bias[h * 128 + 64 + l];
}

// ---------------- graph norm: fused column sum + sum-of-squares ----------------
__global__ __launch_bounds__(256) void colstats_kernel(const float* __restrict__ x,
                                                       float* __restrict__ colsum,
                                                       float* __restrict__ colsumsq)
{
    int t = threadIdx.x, b = blockIdx.x;
    float s0 = 0.f, s1 = 0.f, q0 = 0.f, q1 = 0.f;
    for (int r = b * 125; r < (b + 1) * 125; ++r) {
        float v0 = x[(long)r * HD + t];
        float v1 = x[(long)r * HD + t + 256];
        s0 += v0; q0 += v0 * v0;
        s1 += v1; q1 += v1 * v1;
    }
    atomicAdd(&colsum[t], s0);
    atomicAdd(&colsum[t + 256], s1);
    atomicAdd(&colsumsq[t], q0);
    atomicAdd(&colsumsq[t + 256], q1);
}

// norm (+ReLU) in place; var = E[x^2] - ms*(2-ms)*mu^2 ; writes hi/lo bf16 copies
__global__ void norm_kernel(float* __restrict__ x,
                            unsigned short* __restrict__ xbh, unsigned short* __restrict__ xbl,
                            const float* __restrict__ colsum,
                            const float* __restrict__ colsumsq,
                            const float* __restrict__ g, const float* __restrict__ be,
                            const float* __restrict__ ms)
{
    int stride = gridDim.x * blockDim.x;
    for (int idx = blockIdx.x * blockDim.x + threadIdx.x; idx < NNODE * HD; idx += stride) {
        int j = idx & 511;
        float mu  = colsum[j] * (1.0f / NNODE);
        float ex2 = colsumsq[j] * (1.0f / NNODE);
        float msj = ms[j];
        float var = ex2 - msj * (2.0f - msj) * mu * mu;
        float v = x[idx] - msj * mu;
        float y = g[j] * v / sqrtf(var + 1e-5f) + be[j];
        y = y > 0.f ? y : 0.f;
        x[idx] = y;
        unsigned short h = f2bf(y);
        xbh[idx] = h;
        xbl[idx] = f2bf(y - bf2f(h));
    }
}

// ---------------- prediction head ----------------
__global__ __launch_bounds__(256) void head_kernel(const float* __restrict__ x2,
                                                   const int* __restrict__ idd,
                                                   const int* __restrict__ idc,
                                                   const float* __restrict__ Wout,
                                                   const float* __restrict__ bout,
                                                   float* __restrict__ out0)
{
    int w = threadIdx.x >> 6, l = threadIdx.x & 63;
    int b = blockIdx.x * 4 + w;
    if (b >= BSZ) return;
    int rd = idd[b], rc = idc[b];
    float s = 0.f;
    #pragma unroll
    for (int k = l; k < HD; k += 64)
        s += x2[(long)rd * HD + k] * Wout[k] + x2[(long)rc * HD + k] * Wout[HD + k];
    for (int off = 32; off; off >>= 1) s += __shfl_down(s, off);
    if (l == 0) out0[b] = s + bout[0];
}

// ---------------- all_att: zero + scatter scalar ----------------
__global__ void zero_f4_kernel(float4* __restrict__ p, long n4)
{
    long stride = (long)gridDim.x * blockDim.x;
    for (long i = (long)blockIdx.x * blockDim.x + threadIdx.x; i < n4; i += stride)
        p[i] = make_float4(0.f, 0.f, 0.f, 0.f);
}

__global__ void scatter_att_kernel(const int* __restrict__ ei, float* __restrict__ attm)
{
    int e = blockIdx.x * blockDim.x + threadIdx.x;
    if (e >= ET) return;
    int s, d;
    if (e < E0) { s = ei[e]; d = ei[E0 + e]; }
    else        { s = d = e - E0; }
    const float val = 2.0f * (float)NNODE / (float)ET;
    attm[(long)s * NNODE + d] = val;
}

// ---------------- launch ----------------
extern "C" void kernel_launch(void* const* d_in, const int* in_sizes, int n_in,
                              void* d_out, int out_size, void* d_ws, size_t ws_size,
                              hipStream_t stream)
{
    const float* drug   = (const float*)d_in[0];
    const float* cell   = (const float*)d_in[1];
    const float* gene   = (const float*)d_in[2];
    const float* eattr  = (const float*)d_in[3];
    const int*   ei     = (const int*)d_in[4];
    const int*   idd    = (const int*)d_in[5];
    const int*   idc    = (const int*)d_in[6];
    const float* Wdrug  = (const float*)d_in[7];
    const float* bdrug  = (const float*)d_in[8];
    const float* Wcell  = (const float*)d_in[9];
    const float* bcell  = (const float*)d_in[10];
    const float* Wgene  = (const float*)d_in[11];
    const float* bgene  = (const float*)d_in[12];
    const float* W1     = (const float*)d_in[13];
    const float* b1     = (const float*)d_in[14];
    const float* as1    = (const float*)d_in[15];
    const float* ad1    = (const float*)d_in[16];
    const float* We1    = (const float*)d_in[17];
    const float* ae1    = (const float*)d_in[18];
    const float* bias1  = (const float*)d_in[19];
    const float* g1     = (const float*)d_in[20];
    const float* be1    = (const float*)d_in[21];
    const float* ms1    = (const float*)d_in[22];
    const float* W2     = (const float*)d_in[23];
    const float* b2     = (const float*)d_in[24];
    const float* as2    = (const float*)d_in[25];
    const float* ad2    = (const float*)d_in[26];
    const float* We2    = (const float*)d_in[27];
    const float* ae2    = (const float*)d_in[28];
    const float* bias2  = (const float*)d_in[29];
    const float* g2     = (const float*)d_in[30];
    const float* be2    = (const float*)d_in[31];
    const float* ms2    = (const float*)d_in[32];
    const float* Wout   = (const float*)d_in[33];
    const float* bout   = (const float*)d_in[34];

    float* out0 = (float*)d_out;                 // [10000]
    float* attm = (float*)d_out + BSZ;           // [8000*8000]

    // ---- workspace layout ----
    float* ws     = (float*)d_ws;
    float* xw     = ws;                          // 8000*512
    float* outb   = xw + (long)NNODE * HD;       // 8000*512
    float* csr_al = outb + (long)NNODE * HD;     // 168000*4
    float* a_src  = csr_al + (long)ET * 4;       // 32000
    float* a_dst  = a_src + NNODE * 4;           // 32000
    float* mbuf   = a_dst + NNODE * 4;           // 32000
    float* colsum = mbuf + NNODE * 4;            // 512
    float* colsq  = colsum + 512;                // 512 (contiguous with colsum)
    float* ce     = colsq + 512;                 // 8
    float* scal   = ce + 8;                      // 8
    int* deg      = (int*)(scal + 8);            // 8000
    int* rs       = deg + NNODE;                 // 8004 (padded)
    int* cursor   = rs + NNODE + 4;              // 8000
    int* csr_src  = cursor + NNODE;              // 168000
    int* pos_of_e = csr_src + ET;                // 168000
    unsigned short* p = (unsigned short*)(pos_of_e + ET);
    unsigned short* drug_h = p; p += (long)1024 * 1024;
    unsigned short* drug_l = p; p += (long)1024 * 1024;
    unsigned short* cell_h = p; p += (long)1024 * 1024;
    unsigned short* cell_l = p; p += (long)1024 * 1024;
    unsigned short* x0_h   = p; p += (long)NNODE * H1;
    unsigned short* x0_l   = p; p += (long)NNODE * H1;
    unsigned short* xb_h   = p; p += (long)NNODE * HD;
    unsigned short* xb_l   = p; p += (long)NNODE * HD;
    unsigned short* Wd_h   = p; p += 256 * 1024;
    unsigned short* Wd_l   = p; p += 256 * 1024;
    unsigned short* Wc_h   = p; p += 256 * 1024;
    unsigned short* Wc_l   = p; p += 256 * 1024;
    unsigned short* Wg_h   = p; p += 256 * GKP;
    unsigned short* Wg_l   = p; p += 256 * GKP;
    unsigned short* W1_h   = p; p += 512 * 256;
    unsigned short* W1_l   = p; p += 512 * 256;
    unsigned short* W2_h   = p; p += 512 * 512;
    unsigned short* W2_l   = p; p += 512 * 512;
    float* partsk = (float*)((((unsigned long long)p) + 15) & ~15ULL);  // ZSPLIT*NGENE*H1 f32

    dim3 blk256(256);
    int gE = (ET + 255) / 256;

    // init + small precomputes + data-independent CSR build
    init1_kernel<<<125, blk256, 0, stream>>>(mbuf, deg, colsum, scal);
    deg_kernel<<<gE, blk256, 0, stream>>>(ei, deg);
    scan_kernel<<<1, 1024, 0, stream>>>(deg, rs, cursor);
    scatter_csr_kernel<<<gE, blk256, 0, stream>>>(ei, cursor, csr_src, pos_of_e);
    reduce_sum_kernel<<<64, blk256, 0, stream>>>(eattr, E0, &scal[0]);
    ce_kernel<<<1, 512, 0, stream>>>(We1, ae1, We2, ae2, ce);

    // ---- hi/lo split conversions (drug/cell inputs + all weights) ----
    cvt_pad2_kernel<<<512, blk256, 0, stream>>>(drug, drug_h, drug_l, NDRUG, NDRUG, 1024, 1024);
    cvt_pad2_kernel<<<512, blk256, 0, stream>>>(cell, cell_h, cell_l, NCELL, NCELL, 1024, 1024);
    transpose_cvt2_kernel<<<dim3(32, 8),  blk256, 0, stream>>>(Wdrug, Wd_h, Wd_l, NDRUG, H1, 1024);
    transpose_cvt2_kernel<<<dim3(32, 8),  blk256, 0, stream>>>(Wcell, Wc_h, Wc_l, NCELL, H1, 1024);
    transpose_cvt2_kernel<<<dim3(188, 8), blk256, 0, stream>>>(Wgene, Wg_h, Wg_l, NGENE, H1, GKP);
    transpose_cvt2_kernel<<<dim3(8, 16),  blk256, 0, stream>>>(W1, W1_h, W1_l, H1, HD, H1);
    transpose_cvt2_kernel<<<dim3(16, 16), blk256, 0, stream>>>(W2, W2_h, W2_l, HD, HD, HD);

    // ---- input projections -> x0 (hi/lo bf16) ----
    gemm_mfma2<1><<<dim3(H1 / 64, 16), blk256, 0, stream>>>(drug_h, drug_l, Wd_h, Wd_l, bdrug,
        nullptr, x0_h, x0_l, NDRUG, 1024, H1);
    gemm_mfma2<1><<<dim3(H1 / 64, 16), blk256, 0, stream>>>(cell_h, cell_l, Wc_h, Wc_l, bcell,
        nullptr, x0_h + (long)NDRUG * H1, x0_l + (long)NDRUG * H1, NCELL, 1024, H1);
    gemm_gene_f32<<<752, blk256, 0, stream>>>(gene, Wg_h, Wg_l, partsk);
    reduce_splitk_kernel<<<1500, blk256, 0, stream>>>(partsk, bgene, x0_h, x0_l);

    // ---- layer 1 ----
    gemm_mfma2<0><<<dim3(HD / 64, NNODE / 64), blk256, 0, stream>>>(x0_h, x0_l, W1_h, W1_l, b1,
        xw, nullptr, nullptr, NNODE, H1, HD);
    attn_coef_kernel<<<NNODE / 4, blk256, 0, stream>>>(xw, as1, ad1, a_src, a_dst);
    alpha_max_kernel<<<gE, blk256, 0, stream>>>(ei, eattr, scal, a_src, a_dst, ce,
        csr_al, pos_of_e, mbuf);
    aggregate_kernel<<<NNODE, blk256, 0, stream>>>(xw, csr_al, mbuf, rs, csr_src, bias1, outb);
    colstats_kernel<<<64, blk256, 0, stream>>>(outb, colsum, colsq);
    norm_kernel<<<2048, blk256, 0, stream>>>(outb, xb_h, xb_l, colsum, colsq, g1, be1, ms1);

    // ---- layer 2 ----
    gemm_mfma2<0><<<dim3(HD / 64, NNODE / 64), blk256, 0, stream>>>(xb_h, xb_l, W2_h, W2_l, b2,
        xw, nullptr, nullptr, NNODE, HD, HD);
    attn_coef_kernel<<<NNODE / 4, blk256, 0, stream>>>(xw, as2, ad2, a_src, a_dst);
    init2_kernel<<<125, blk256, 0, stream>>>(mbuf, colsum);  // zeroes mbuf + colsum+colsq (1024)
    alpha_max_kernel<<<gE, blk256, 0, stream>>>(ei, eattr, scal, a_src, a_dst, ce + 4,
        csr_al, pos_of_e, mbuf);
    aggregate_kernel<<<NNODE, blk256, 0, stream>>>(xw, csr_al, mbuf, rs, csr_src, bias2, outb);
    colstats_kernel<<<64, blk256, 0, stream>>>(outb, colsum, colsq);
    norm_kernel<<<2048, blk256, 0, stream>>>(outb, xb_h, xb_l, colsum, colsq, g2, be2, ms2);

    // ---- head + attention matrix ----
    head_kernel<<<(BSZ + 3) / 4, blk256, 0, stream>>>(outb, idd, idc, Wout, bout, out0);
    zero_f4_kernel<<<2048, blk256, 0, stream>>>((float4*)attm, (long)NNODE * NNODE / 4);
    scatter_att_kernel<<<gE, blk256, 0, stream>>>(ei, attm);
}